// Round 5
// baseline (1526.993 us; speedup 1.0000x reference)
//
#include <hip/hip_runtime.h>
#include <cstdint>
#include <cstddef>

typedef uint32_t u32;
typedef uint64_t u64;

#define NB 16
#define NC 4000
#define NCPAD 4096
#define POSTN 1000
#define PREN 1000
#define NCHUNK 63   // ceil(NC/64)
#define TIECAP 8192

__constant__ int c_N[4]    = {120000, 30000, 7500, 1875};
__constant__ int c_OFF[4]  = {0, 120000, 150000, 157500};
__constant__ int c_HW[4]   = {40000, 10000, 2500, 625};
__constant__ int c_W[4]    = {200, 100, 50, 25};
__constant__ int c_BASE[4] = {0, 1000, 2000, 3000};
__constant__ int c_KOFF[4] = {0, 1920000, 2400000, 2520000};

__device__ __forceinline__ u32 ord_bits(float f) {
  u32 u = __float_as_uint(f);
  return (u & 0x80000000u) ? ~u : (u | 0x80000000u);
}
__device__ __forceinline__ float inv_ord(u32 o) {
  u32 bits = (o & 0x80000000u) ? (o ^ 0x80000000u) : ~o;
  return __uint_as_float(bits);
}

// 192-block slice map: 8 blocks/task lvl0, 2/task lvl1, 1/task lvl2+3
__device__ __forceinline__ void slice_map(int bid, int& lvl, int& b, int& e0,
                                          int& nsl) {
  if (bid < 128)      { lvl = 0; b = bid >> 3; e0 = (bid & 7) * 15000; nsl = 15000; }
  else if (bid < 160) { lvl = 1; int t = bid - 128; b = t >> 1; e0 = (t & 1) * 15000; nsl = 15000; }
  else if (bid < 176) { lvl = 2; b = bid - 160; e0 = 0; nsl = 7500; }
  else                { lvl = 3; b = bid - 176; e0 = 0; nsl = 1875; }
}

struct DecBox { float x1, y1, x2, y2; int lvl; bool valid; };

__device__ DecBox decode_box(u32 gid, int b,
    const float* __restrict__ reg0, const float* __restrict__ reg1,
    const float* __restrict__ reg2, const float* __restrict__ reg3,
    const float* __restrict__ anchors) {
  int lvl = (gid < 120000u) ? 0 : (gid < 150000u) ? 1 : (gid < 157500u) ? 2 : 3;
  int local = (int)gid - c_OFF[lvl];
  int a = local % 3;
  int cell = local / 3;
  int w = c_W[lvl];
  int hw = c_HW[lvl];
  int y = cell / w;
  int x = cell - y * w;
  const float* reg = (lvl == 0) ? reg0 : (lvl == 1) ? reg1 : (lvl == 2) ? reg2 : reg3;
  size_t base = ((size_t)(b * 12 + a * 4) * (size_t)w + (size_t)y) * (size_t)w + (size_t)x;
  const float CLIPV = 4.135166556742356f; // log(1000/16) as f32
  float dx = reg[base];
  float dy = reg[base + (size_t)hw];
  float dwv = fminf(reg[base + 2 * (size_t)hw], CLIPV);
  float dhv = fminf(reg[base + 3 * (size_t)hw], CLIPV);
  float a0 = anchors[(size_t)gid * 4 + 0];
  float a1 = anchors[(size_t)gid * 4 + 1];
  float a2 = anchors[(size_t)gid * 4 + 2];
  float a3 = anchors[(size_t)gid * 4 + 3];
  float wa = __fsub_rn(a2, a0);
  float ha = __fsub_rn(a3, a1);
  float cxa = __fadd_rn(a0, __fmul_rn(0.5f, wa));
  float cya = __fadd_rn(a1, __fmul_rn(0.5f, ha));
  float pcx = __fadd_rn(__fmul_rn(dx, wa), cxa);
  float pcy = __fadd_rn(__fmul_rn(dy, ha), cya);
  float pw = __fmul_rn(expf(dwv), wa);
  float ph = __fmul_rn(expf(dhv), ha);
  float x1 = __fsub_rn(pcx, __fmul_rn(0.5f, pw));
  float y1 = __fsub_rn(pcy, __fmul_rn(0.5f, ph));
  float x2 = __fadd_rn(pcx, __fmul_rn(0.5f, pw));
  float y2 = __fadd_rn(pcy, __fmul_rn(0.5f, ph));
  x1 = fminf(fmaxf(x1, 0.0f), 800.0f);
  y1 = fminf(fmaxf(y1, 0.0f), 800.0f);
  x2 = fminf(fmaxf(x2, 0.0f), 800.0f);
  y2 = fminf(fmaxf(y2, 0.0f), 800.0f);
  DecBox r;
  r.x1 = x1; r.y1 = y1; r.x2 = x2; r.y2 = y2; r.lvl = lvl;
  r.valid = (__fsub_rn(x2, x1) >= 1.0f) && (__fsub_rn(y2, y1) >= 1.0f);
  return r;
}

// ---------------- K0: zero state ----------------------------------------------
__global__ void k_zero(float* __restrict__ out, u32* __restrict__ counters,
                       u64* __restrict__ cand_key, u32* __restrict__ hist1,
                       u32* __restrict__ hist2, u32* __restrict__ hist3,
                       u32* __restrict__ tiecnt, u32* __restrict__ resolvedf,
                       u32* __restrict__ state_known,
                       u32* __restrict__ state_kneed) {
  int i = blockIdx.x * blockDim.x + threadIdx.x;
  if (i < NB * POSTN * 5) out[i] = 0.0f;
  if (i < NB * NCPAD) cand_key[i] = 0ull;
  if (i < 64 * 2048) { hist1[i] = 0u; hist2[i] = 0u; hist3[i] = 0u; }
  if (i < 64) {
    counters[i] = 0u; tiecnt[i] = 0u; resolvedf[i] = 0u;
    state_known[i] = 0u; state_kneed[i] = (u32)PREN;
  }
}

// ---------------- K1: ord keys + pass-1 histogram (full chip) -----------------
__global__ __launch_bounds__(1024) void k_keys(
    const float* __restrict__ cls0, const float* __restrict__ cls1,
    const float* __restrict__ cls2, const float* __restrict__ cls3,
    u32* __restrict__ keybuf, u32* __restrict__ hist1) {
  int lvl, b, e0, nsl;
  slice_map(blockIdx.x, lvl, b, e0, nsl);
  const float* cls = (lvl == 0) ? cls0 : (lvl == 1) ? cls1 : (lvl == 2) ? cls2 : cls3;
  int n = c_N[lvl];
  const float* cp = cls + (size_t)b * n;
  u32* kb = keybuf + c_KOFF[lvl] + b * n;
  int tid = threadIdx.x;
  __shared__ u32 h[2048];
  for (int t = tid; t < 2048; t += 1024) h[t] = 0u;
  __syncthreads();
  for (int e = e0 + tid; e < e0 + nsl; e += 1024) {
    u32 o = ord_bits(cp[e]);
    kb[e] = o;
    atomicAdd(&h[o >> 21], 1u);
  }
  __syncthreads();
  int task = lvl * 16 + b;
  for (int t = tid; t < 2048; t += 1024) {
    u32 v = h[t];
    if (v) atomicAdd(&hist1[task * 2048 + t], v);
  }
}

// ---------------- K2/K3: filtered histogram passes -----------------------------
__global__ __launch_bounds__(1024) void k_hist(
    const u32* __restrict__ keybuf, const u32* __restrict__ state_known,
    u32* __restrict__ hist, int shift, u32 fmask, u32 dmask) {
  int lvl, b, e0, nsl;
  slice_map(blockIdx.x, lvl, b, e0, nsl);
  int task = lvl * 16 + b;
  u32 known = state_known[task];
  const u32* kb = keybuf + c_KOFF[lvl] + b * c_N[lvl];
  int tid = threadIdx.x;
  __shared__ u32 h[2048];
  for (int t = tid; t <= (int)dmask; t += 1024) h[t] = 0u;
  __syncthreads();
  for (int e = e0 + tid; e < e0 + nsl; e += 1024) {
    u32 o = kb[e];
    if ((o & fmask) == known) atomicAdd(&h[(o >> shift) & dmask], 1u);
  }
  __syncthreads();
  for (int t = tid; t <= (int)dmask; t += 1024) {
    u32 v = h[t];
    if (v) atomicAdd(&hist[task * 2048 + t], v);
  }
}

// ---------------- K pick: suffix-scan histogram, choose digit ------------------
__global__ __launch_bounds__(1024) void k_pick(
    const u32* __restrict__ hist, u32* __restrict__ state_known,
    u32* __restrict__ state_kneed, u32* __restrict__ resolvedf,
    u64* __restrict__ kth, int nb, int shift, int final_pass) {
  int task = blockIdx.x;
  int tid = threadIdx.x;
  __shared__ u32 A[2048], Bb[2048];
  __shared__ int sh_t;
  __shared__ u32 sh_above;
  u32 kneed = state_kneed[task];
  for (int t = tid; t < nb; t += 1024) A[t] = hist[task * 2048 + t];
  __syncthreads();
  u32* cur = A;
  u32* nxt = Bb;
  for (int off2 = 1; off2 < nb; off2 <<= 1) {
    for (int t = tid; t < nb; t += 1024)
      nxt[t] = cur[t] + ((t + off2 < nb) ? cur[t + off2] : 0u);
    __syncthreads();
    u32* tmp = cur; cur = nxt; nxt = tmp;
  }
  // cur[t] = count of elements with digit >= t
  for (int t = tid; t < nb; t += 1024) {
    u32 s = cur[t];
    u32 above = (t + 1 < nb) ? cur[t + 1] : 0u;
    if (s >= kneed && above < kneed) { sh_t = t; sh_above = above; }
  }
  __syncthreads();
  if (tid == 0) {
    u32 known = state_known[task] | ((u32)sh_t << shift);
    u32 kneed2 = kneed - sh_above;
    state_known[task] = known;
    state_kneed[task] = kneed2;
    if (final_pass) {
      u32 c = cur[sh_t] - sh_above;   // count equal to kth value
      if (kneed2 == c) {
        resolvedf[task] = 1u;
        kth[task] = ((u64)known) << 32;   // take all value-equals
      } else {
        resolvedf[task] = 0u;             // gid tie-break needed
      }
    }
  }
}

// ---------------- K tie: collect gids of value-equal elements ------------------
__global__ __launch_bounds__(1024) void k_tie(
    const u32* __restrict__ keybuf, const u32* __restrict__ state_known,
    const u32* __restrict__ resolvedf, u32* __restrict__ tiecnt,
    u32* __restrict__ tiebuf) {
  int lvl, b, e0, nsl;
  slice_map(blockIdx.x, lvl, b, e0, nsl);
  int task = lvl * 16 + b;
  if (resolvedf[task]) return;
  u32 pval = state_known[task];
  const u32* kb = keybuf + c_KOFF[lvl] + b * c_N[lvl];
  int hw = c_HW[lvl], off = c_OFF[lvl];
  for (int e = e0 + threadIdx.x; e < e0 + nsl; e += 1024) {
    if (kb[e] == pval) {
      int a = e / hw;
      int cell = e - a * hw;
      u32 gid = (u32)(off + cell * 3 + a);
      u32 idx = atomicAdd(&tiecnt[task], 1u);
      if (idx < (u32)TIECAP) tiebuf[task * TIECAP + idx] = gid;
    }
  }
}

// ---------------- K tiepick: kneed-th smallest gid among equals ----------------
__global__ __launch_bounds__(1024) void k_tiepick(
    const u32* __restrict__ tiecnt, const u32* __restrict__ tiebuf,
    const u32* __restrict__ state_known, const u32* __restrict__ state_kneed,
    const u32* __restrict__ resolvedf, u64* __restrict__ kth) {
  int task = blockIdx.x;
  if (resolvedf[task]) return;
  int tid = threadIdx.x;
  __shared__ u32 G[TIECAP];
  __shared__ u32 h[256];
  __shared__ u32 sh_known, sh_kneed;
  u32 c2 = min(tiecnt[task], (u32)TIECAP);
  for (u32 i = tid; i < c2; i += 1024) G[i] = tiebuf[task * TIECAP + i];
  if (tid == 0) { sh_known = 0u; sh_kneed = state_kneed[task]; }
  u32 pmask = 0u;
  __syncthreads();
  for (int pass = 2; pass >= 0; --pass) {  // gid < 2^18 < 2^24
    int shift = pass * 8;
    if (tid < 256) h[tid] = 0u;
    __syncthreads();
    u32 known = sh_known;
    for (u32 i = tid; i < c2; i += 1024) {
      u32 g = G[i];
      if ((g & pmask) == known) atomicAdd(&h[(g >> shift) & 255u], 1u);
    }
    __syncthreads();
    if (tid == 0) {
      u32 kneed = sh_kneed;
      u32 cum = 0;
      for (int t = 0; t < 256; ++t) {   // ascending: kneed-th SMALLEST gid
        u32 v = h[t];
        if (cum + v >= kneed) {
          sh_known = known | ((u32)t << shift);
          sh_kneed = kneed - cum;
          break;
        }
        cum += v;
      }
    }
    pmask |= (0xFFu << shift);
    __syncthreads();
  }
  if (tid == 0)
    kth[task] = (((u64)state_known[task]) << 32) | (u32)(~sh_known);
}

// ---------------- K gather: threshold test + decode + slot write ---------------
__global__ __launch_bounds__(1024) void k_gather(
    const u32* __restrict__ keybuf, const u64* __restrict__ kth,
    const float* __restrict__ reg0, const float* __restrict__ reg1,
    const float* __restrict__ reg2, const float* __restrict__ reg3,
    const float* __restrict__ anchors, u32* __restrict__ counters,
    u64* __restrict__ cand_key) {
  int lvl, b, e0, nsl;
  slice_map(blockIdx.x, lvl, b, e0, nsl);
  int task = lvl * 16 + b;
  u64 kt = kth[task];
  u32 hi = (u32)(kt >> 32);
  const u32* kb = keybuf + c_KOFF[lvl] + b * c_N[lvl];
  int hw = c_HW[lvl], off = c_OFF[lvl];
  for (int e = e0 + threadIdx.x; e < e0 + nsl; e += 1024) {
    u32 o = kb[e];
    if (o < hi) continue;
    int a = e / hw;
    int cell = e - a * hw;
    u32 gid = (u32)(off + cell * 3 + a);
    u64 key = ((u64)o << 32) | (u32)(~gid);
    if (key < kt) continue;
    DecBox bx = decode_box(gid, b, reg0, reg1, reg2, reg3, anchors);
    u64 skey = bx.valid ? key : (key & 0xFFFFFFFFull);
    u32 slot = atomicAdd(&counters[task], 1u);
    if (slot < (u32)PREN)
      cand_key[(size_t)b * NCPAD + (size_t)(c_BASE[lvl] + (int)slot)] = skey;
  }
}

// ---------------- K sort: per-image bitonic sort (desc) of 4096 keys -----------
__global__ __launch_bounds__(1024) void k_sort(u64* __restrict__ cand_key) {
  int b = blockIdx.x;
  int tid = threadIdx.x;
  __shared__ u64 sk[NCPAD];
  for (int p = tid; p < NCPAD; p += 1024) sk[p] = cand_key[(size_t)b * NCPAD + p];
  __syncthreads();
  for (u32 k = 2; k <= NCPAD; k <<= 1) {
    for (u32 j = k >> 1; j > 0; j >>= 1) {
      for (u32 t = tid; t < NCPAD / 2; t += 1024) {
        u32 i = 2u * t - (t & (j - 1u));
        u32 l2 = i | j;
        u64 av = sk[i], bv = sk[l2];
        bool up = ((i & k) == 0u);
        if (up ? (av < bv) : (av > bv)) { sk[i] = bv; sk[l2] = av; }
      }
      __syncthreads();
    }
  }
  for (int p = tid; p < NCPAD; p += 1024) cand_key[(size_t)b * NCPAD + p] = sk[p];
}

// ---------------- K decode: payloads for sorted candidates (full grid) ---------
__global__ __launch_bounds__(1024) void k_decode(
    const u64* __restrict__ cand_key,
    const float* __restrict__ reg0, const float* __restrict__ reg1,
    const float* __restrict__ reg2, const float* __restrict__ reg3,
    const float* __restrict__ anchors,
    float4* __restrict__ sbox, float4* __restrict__ boffA,
    float* __restrict__ area, float* __restrict__ score,
    u64* __restrict__ validmask) {
  int bid = blockIdx.x;
  int b = bid >> 2;
  int p = ((bid & 3) << 10) | threadIdx.x;
  u64 key = cand_key[(size_t)b * NCPAD + p];
  float4 bx4 = make_float4(0.f, 0.f, 0.f, 0.f);
  float4 bo4 = make_float4(0.f, 0.f, 0.f, 0.f);
  float ar = 0.f, sc = 0.f;
  bool vflag = false;
  if (key != 0ull) {
    u32 gid = ~((u32)key);
    vflag = (key >> 32) != 0ull;
    DecBox bx = decode_box(gid, b, reg0, reg1, reg2, reg3, anchors);
    bx4 = make_float4(bx.x1, bx.y1, bx.x2, bx.y2);
    float offv = __fmul_rn((float)bx.lvl, 801.0f);
    bo4 = make_float4(__fadd_rn(bx.x1, offv), __fadd_rn(bx.y1, offv),
                      __fadd_rn(bx.x2, offv), __fadd_rn(bx.y2, offv));
    ar = __fmul_rn(__fsub_rn(bo4.z, bo4.x), __fsub_rn(bo4.w, bo4.y));
    if (vflag) {
      float logit = inv_ord((u32)(key >> 32));
      sc = 1.0f / (1.0f + expf(-logit));
    }
  }
  size_t gi = (size_t)b * NCPAD + (size_t)p;
  sbox[gi] = bx4;
  boffA[gi] = bo4;
  area[gi] = ar;
  score[gi] = sc;
  u64 bal = __ballot(vflag ? 1 : 0);
  if ((threadIdx.x & 63) == 0) validmask[b * 64 + (p >> 6)] = bal;
}

// ---------------- K mask: IoU suppression bitmask matrix -----------------------
#define RPB 16
__global__ __launch_bounds__(256) void k_mask(
    const float4* __restrict__ boffA, const float* __restrict__ area,
    u64* __restrict__ mask) {
  int bg = blockIdx.x;
  int b = bg / 250;
  int g = bg - b * 250;
  int row0 = g * RPB;
  int tid = threadIdx.x;
  int wave = tid >> 6;
  int lane = tid & 63;
  __shared__ float4 rb[RPB];
  __shared__ float ra[RPB];
  if (tid < RPB) {
    int rr = row0 + tid;
    int rc = (rr < NCPAD) ? rr : (NCPAD - 1);
    rb[tid] = boffA[(size_t)b * NCPAD + rc];
    ra[tid] = area[(size_t)b * NCPAD + rc];
  }
  __syncthreads();
  u64* M = mask + (size_t)b * NC * 64;
  for (int chunk = 0; chunk < 16; ++chunk) {
    int wword = chunk * 4 + wave;
    int wmaxj = chunk * 256 + wave * 64 + 63;   // this wave's max column
    if (wmaxj <= row0) {
      // whole 16-row group below the diagonal for this wave: all zero
      if (lane == 0) {
#pragma unroll
        for (int rr = 0; rr < RPB; ++rr) {
          int i = row0 + rr;
          if (i < NC) M[(size_t)i * 64 + wword] = 0ull;
        }
      }
      continue;
    }
    int j = chunk * 256 + tid;
    float4 cb = boffA[(size_t)b * NCPAD + j];
    float ca = area[(size_t)b * NCPAD + j];
#pragma unroll
    for (int rr = 0; rr < RPB; ++rr) {
      int i = row0 + rr;
      if (wmaxj <= i) {   // wave entirely j<=i: zero word, skip IoU
        if (lane == 0 && i < NC) M[(size_t)i * 64 + wword] = 0ull;
        continue;
      }
      float4 rbb = rb[rr];
      float ria = ra[rr];
      float ix1 = fmaxf(cb.x, rbb.x);
      float iy1 = fmaxf(cb.y, rbb.y);
      float ix2 = fminf(cb.z, rbb.z);
      float iy2 = fminf(cb.w, rbb.w);
      float inter = __fmul_rn(fmaxf(__fsub_rn(ix2, ix1), 0.0f),
                              fmaxf(__fsub_rn(iy2, iy1), 0.0f));
      float uni = __fsub_rn(__fadd_rn(ca, ria), inter);
      float iou = __fdiv_rn(inter, (uni > 0.0f) ? uni : 1.0f);
      bool pred = (j > i) && (iou > 0.7f);
      u64 bal = __ballot(pred ? 1 : 0);
      if (lane == 0 && i < NC) M[(size_t)i * 64 + wword] = bal;
    }
  }
}

// ---------------- K nms: greedy NMS, single wave per image (barrier-free) ------
__global__ __launch_bounds__(64) void k_nms(
    const u64* __restrict__ mask, const u64* __restrict__ validmask,
    const float4* __restrict__ sbox, const float* __restrict__ score,
    float* __restrict__ out) {
  int b = blockIdx.x;
  int lane = threadIdx.x;
  const u64* M = mask + (size_t)b * NC * 64;
  u64 supp = 0ull;      // lane L holds suppression word L
  u64 keep = 0ull;      // lane L holds keep word L
  u64 valid = validmask[b * 64 + lane];
  // diagonal block of chunk 0: lane q holds row q's word 0
  u64 dch = M[(size_t)lane * 64 + 0];
  for (int W = 0; W < NCHUNK; ++W) {
    int c0 = W << 6;
    u64 s = __shfl(supp, W);
    u64 v = __shfl(valid, W);
    // prefetch next chunk's diagonal block (hides under resolve+apply)
    u64 dnext = 0ull;
    if (W + 1 < NCHUNK) {
      int row = c0 + 64 + lane;
      if (row < NC) dnext = M[(size_t)row * 64 + (W + 1)];
    }
    // greedy resolve within chunk (identical in all lanes)
    u64 pending = v & ~s;
    u64 kw = 0ull;
    while (pending) {
      int q = __builtin_ctzll(pending);
      kw |= (1ull << q);
      u64 supq = __shfl(dch, q);   // row q only sets bits > q
      pending &= ~supq & ~(1ull << q);
    }
    // apply kept rows to this lane's supp word (rows' words < W are zero)
    if (lane >= W) {
      u64 kk = kw;
      while (kk) {
        int q = __builtin_ctzll(kk);
        kk &= kk - 1ull;
        supp |= M[(size_t)(c0 + q) * 64 + lane];
      }
    }
    if (lane == W) keep = kw;
    dch = dnext;
  }
  // rank = exclusive prefix of popcounts across lanes
  int pc = __popcll(keep);
  int incl = pc;
  for (int d = 1; d < 64; d <<= 1) {
    int t = __shfl_up(incl, d);
    if (lane >= d) incl += t;
  }
  int r = incl - pc;
  u64 kk = keep;
  while (kk) {
    int bit = __builtin_ctzll(kk);
    kk &= kk - 1ull;
    if (r < POSTN) {
      int p = lane * 64 + bit;
      float4 bx = sbox[(size_t)b * NCPAD + p];
      size_t ob = ((size_t)b * POSTN + (size_t)r) * 4;
      out[ob + 0] = bx.x;
      out[ob + 1] = bx.y;
      out[ob + 2] = bx.z;
      out[ob + 3] = bx.w;
      out[(size_t)NB * POSTN * 4 + (size_t)b * POSTN + (size_t)r] =
          score[(size_t)b * NCPAD + p];
    }
    ++r;
  }
}

extern "C" void kernel_launch(void* const* d_in, const int* in_sizes, int n_in,
                              void* d_out, int out_size, void* d_ws, size_t ws_size,
                              hipStream_t stream) {
  // setup_inputs dict order: cls0, reg0, cls1, reg1, cls2, reg2, cls3, reg3, anchors
  const float* cls0 = (const float*)d_in[0];
  const float* reg0 = (const float*)d_in[1];
  const float* cls1 = (const float*)d_in[2];
  const float* reg1 = (const float*)d_in[3];
  const float* cls2 = (const float*)d_in[4];
  const float* reg2 = (const float*)d_in[5];
  const float* cls3 = (const float*)d_in[6];
  const float* reg3 = (const float*)d_in[7];
  const float* anchors = (const float*)d_in[8];
  float* out = (float*)d_out;

  char* ws = (char*)d_ws;
  size_t off = 0;
  auto take = [&](size_t bytes) -> void* {
    off = (off + 255) & ~(size_t)255;
    void* p = ws + off;
    off += bytes;
    return p;
  };
  u64* mask      = (u64*)take((size_t)NB * NC * 64 * 8);   // 32.8 MB
  // keybuf (10.2 MB) and tiebuf (2 MB) alias the mask region: they are
  // dead before k_mask writes it (stream-ordered).
  u32* keybuf    = (u32*)mask;
  u32* tiebuf    = (u32*)((char*)mask + (20u << 20));
  u64* cand_key  = (u64*)take((size_t)NB * NCPAD * 8);
  float4* sbox   = (float4*)take((size_t)NB * NCPAD * 16);
  float4* boffA  = (float4*)take((size_t)NB * NCPAD * 16);
  float* area    = (float*)take((size_t)NB * NCPAD * 4);
  float* score   = (float*)take((size_t)NB * NCPAD * 4);
  u64* validmask = (u64*)take((size_t)NB * 64 * 8);
  u32* hist1     = (u32*)take((size_t)64 * 2048 * 4);
  u32* hist2     = (u32*)take((size_t)64 * 2048 * 4);
  u32* hist3     = (u32*)take((size_t)64 * 2048 * 4);
  u64* kth       = (u64*)take((size_t)64 * 8);
  u32* counters  = (u32*)take((size_t)64 * 4);
  u32* tiecnt    = (u32*)take((size_t)64 * 4);
  u32* resolvedf = (u32*)take((size_t)64 * 4);
  u32* state_known = (u32*)take((size_t)64 * 4);
  u32* state_kneed = (u32*)take((size_t)64 * 4);
  (void)ws_size; (void)in_sizes; (void)n_in; (void)out_size;

  k_zero<<<512, 256, 0, stream>>>(out, counters, cand_key, hist1, hist2, hist3,
                                  tiecnt, resolvedf, state_known, state_kneed);
  k_keys<<<192, 1024, 0, stream>>>(cls0, cls1, cls2, cls3, keybuf, hist1);
  k_pick<<<64, 1024, 0, stream>>>(hist1, state_known, state_kneed, resolvedf,
                                  kth, 2048, 21, 0);
  k_hist<<<192, 1024, 0, stream>>>(keybuf, state_known, hist2, 10, 0xFFE00000u,
                                   0x7FFu);
  k_pick<<<64, 1024, 0, stream>>>(hist2, state_known, state_kneed, resolvedf,
                                  kth, 2048, 10, 0);
  k_hist<<<192, 1024, 0, stream>>>(keybuf, state_known, hist3, 0, 0xFFFFFC00u,
                                   0x3FFu);
  k_pick<<<64, 1024, 0, stream>>>(hist3, state_known, state_kneed, resolvedf,
                                  kth, 1024, 0, 1);
  k_tie<<<192, 1024, 0, stream>>>(keybuf, state_known, resolvedf, tiecnt,
                                  tiebuf);
  k_tiepick<<<64, 1024, 0, stream>>>(tiecnt, tiebuf, state_known, state_kneed,
                                     resolvedf, kth);
  k_gather<<<192, 1024, 0, stream>>>(keybuf, kth, reg0, reg1, reg2, reg3,
                                     anchors, counters, cand_key);
  k_sort<<<NB, 1024, 0, stream>>>(cand_key);
  k_decode<<<NB * 4, 1024, 0, stream>>>(cand_key, reg0, reg1, reg2, reg3,
                                        anchors, sbox, boffA, area, score,
                                        validmask);
  k_mask<<<NB * 250, 256, 0, stream>>>(boffA, area, mask);
  k_nms<<<NB, 64, 0, stream>>>(mask, validmask, sbox, score, out);
}

// Round 6
// 518.369 us; speedup vs baseline: 2.9458x; 2.9458x over previous
//
#include <hip/hip_runtime.h>
#include <cstdint>
#include <cstddef>

typedef uint32_t u32;
typedef uint64_t u64;

#define NB 16
#define NC 4000
#define NCPAD 4096
#define POSTN 1000
#define PREN 1000
#define NCHUNK 63   // ceil(NC/64)
#define TIECAP 8192

__constant__ int c_N[4]    = {120000, 30000, 7500, 1875};
__constant__ int c_OFF[4]  = {0, 120000, 150000, 157500};
__constant__ int c_HW[4]   = {40000, 10000, 2500, 625};
__constant__ int c_W[4]    = {200, 100, 50, 25};
__constant__ int c_BASE[4] = {0, 1000, 2000, 3000};
__constant__ int c_KOFF[4] = {0, 1920000, 2400000, 2520000};

__device__ __forceinline__ u32 ord_bits(float f) {
  u32 u = __float_as_uint(f);
  return (u & 0x80000000u) ? ~u : (u | 0x80000000u);
}
__device__ __forceinline__ float inv_ord(u32 o) {
  u32 bits = (o & 0x80000000u) ? (o ^ 0x80000000u) : ~o;
  return __uint_as_float(bits);
}
__device__ __forceinline__ u64 readlane_u64(u64 v, int l) {
  u32 lo = (u32)__builtin_amdgcn_readlane((int)(u32)v, l);
  u32 hi = (u32)__builtin_amdgcn_readlane((int)(u32)(v >> 32), l);
  return (((u64)hi) << 32) | (u64)lo;
}

// 192-block slice map: 8 blocks/task lvl0, 2/task lvl1, 1/task lvl2+3
__device__ __forceinline__ void slice_map(int bid, int& lvl, int& b, int& e0,
                                          int& nsl) {
  if (bid < 128)      { lvl = 0; b = bid >> 3; e0 = (bid & 7) * 15000; nsl = 15000; }
  else if (bid < 160) { lvl = 1; int t = bid - 128; b = t >> 1; e0 = (t & 1) * 15000; nsl = 15000; }
  else if (bid < 176) { lvl = 2; b = bid - 160; e0 = 0; nsl = 7500; }
  else                { lvl = 3; b = bid - 176; e0 = 0; nsl = 1875; }
}

struct DecBox { float x1, y1, x2, y2; int lvl; bool valid; };

__device__ DecBox decode_box(u32 gid, int b,
    const float* __restrict__ reg0, const float* __restrict__ reg1,
    const float* __restrict__ reg2, const float* __restrict__ reg3,
    const float* __restrict__ anchors) {
  int lvl = (gid < 120000u) ? 0 : (gid < 150000u) ? 1 : (gid < 157500u) ? 2 : 3;
  int local = (int)gid - c_OFF[lvl];
  int a = local % 3;
  int cell = local / 3;
  int w = c_W[lvl];
  int hw = c_HW[lvl];
  int y = cell / w;
  int x = cell - y * w;
  const float* reg = (lvl == 0) ? reg0 : (lvl == 1) ? reg1 : (lvl == 2) ? reg2 : reg3;
  size_t base = ((size_t)(b * 12 + a * 4) * (size_t)w + (size_t)y) * (size_t)w + (size_t)x;
  const float CLIPV = 4.135166556742356f; // log(1000/16) as f32
  float dx = reg[base];
  float dy = reg[base + (size_t)hw];
  float dwv = fminf(reg[base + 2 * (size_t)hw], CLIPV);
  float dhv = fminf(reg[base + 3 * (size_t)hw], CLIPV);
  float a0 = anchors[(size_t)gid * 4 + 0];
  float a1 = anchors[(size_t)gid * 4 + 1];
  float a2 = anchors[(size_t)gid * 4 + 2];
  float a3 = anchors[(size_t)gid * 4 + 3];
  float wa = __fsub_rn(a2, a0);
  float ha = __fsub_rn(a3, a1);
  float cxa = __fadd_rn(a0, __fmul_rn(0.5f, wa));
  float cya = __fadd_rn(a1, __fmul_rn(0.5f, ha));
  float pcx = __fadd_rn(__fmul_rn(dx, wa), cxa);
  float pcy = __fadd_rn(__fmul_rn(dy, ha), cya);
  float pw = __fmul_rn(expf(dwv), wa);
  float ph = __fmul_rn(expf(dhv), ha);
  float x1 = __fsub_rn(pcx, __fmul_rn(0.5f, pw));
  float y1 = __fsub_rn(pcy, __fmul_rn(0.5f, ph));
  float x2 = __fadd_rn(pcx, __fmul_rn(0.5f, pw));
  float y2 = __fadd_rn(pcy, __fmul_rn(0.5f, ph));
  x1 = fminf(fmaxf(x1, 0.0f), 800.0f);
  y1 = fminf(fmaxf(y1, 0.0f), 800.0f);
  x2 = fminf(fmaxf(x2, 0.0f), 800.0f);
  y2 = fminf(fmaxf(y2, 0.0f), 800.0f);
  DecBox r;
  r.x1 = x1; r.y1 = y1; r.x2 = x2; r.y2 = y2; r.lvl = lvl;
  r.valid = (__fsub_rn(x2, x1) >= 1.0f) && (__fsub_rn(y2, y1) >= 1.0f);
  return r;
}

// ---------------- K0: zero state ----------------------------------------------
__global__ void k_zero(float* __restrict__ out, u32* __restrict__ counters,
                       u64* __restrict__ cand_key, u32* __restrict__ hist1,
                       u32* __restrict__ hist2, u32* __restrict__ hist3,
                       u32* __restrict__ tiecnt, u32* __restrict__ resolvedf,
                       u32* __restrict__ state_known,
                       u32* __restrict__ state_kneed,
                       u64* __restrict__ rowmask) {
  int i = blockIdx.x * blockDim.x + threadIdx.x;
  if (i < NB * POSTN * 5) out[i] = 0.0f;
  if (i < NB * NCPAD) { cand_key[i] = 0ull; rowmask[i] = 0ull; }
  if (i < 64 * 2048) { hist1[i] = 0u; hist2[i] = 0u; hist3[i] = 0u; }
  if (i < 64) {
    counters[i] = 0u; tiecnt[i] = 0u; resolvedf[i] = 0u;
    state_known[i] = 0u; state_kneed[i] = (u32)PREN;
  }
}

// ---------------- K1: ord keys + pass-1 histogram (full chip) -----------------
__global__ __launch_bounds__(1024) void k_keys(
    const float* __restrict__ cls0, const float* __restrict__ cls1,
    const float* __restrict__ cls2, const float* __restrict__ cls3,
    u32* __restrict__ keybuf, u32* __restrict__ hist1) {
  int lvl, b, e0, nsl;
  slice_map(blockIdx.x, lvl, b, e0, nsl);
  const float* cls = (lvl == 0) ? cls0 : (lvl == 1) ? cls1 : (lvl == 2) ? cls2 : cls3;
  int n = c_N[lvl];
  const float* cp = cls + (size_t)b * n;
  u32* kb = keybuf + c_KOFF[lvl] + b * n;
  int tid = threadIdx.x;
  __shared__ u32 h[2048];
  for (int t = tid; t < 2048; t += 1024) h[t] = 0u;
  __syncthreads();
  for (int e = e0 + tid; e < e0 + nsl; e += 1024) {
    u32 o = ord_bits(cp[e]);
    kb[e] = o;
    atomicAdd(&h[o >> 21], 1u);
  }
  __syncthreads();
  int task = lvl * 16 + b;
  for (int t = tid; t < 2048; t += 1024) {
    u32 v = h[t];
    if (v) atomicAdd(&hist1[task * 2048 + t], v);
  }
}

// ---------------- K2/K3: filtered histogram passes -----------------------------
__global__ __launch_bounds__(1024) void k_hist(
    const u32* __restrict__ keybuf, const u32* __restrict__ state_known,
    u32* __restrict__ hist, int shift, u32 fmask, u32 dmask) {
  int lvl, b, e0, nsl;
  slice_map(blockIdx.x, lvl, b, e0, nsl);
  int task = lvl * 16 + b;
  u32 known = state_known[task];
  const u32* kb = keybuf + c_KOFF[lvl] + b * c_N[lvl];
  int tid = threadIdx.x;
  __shared__ u32 h[2048];
  for (int t = tid; t <= (int)dmask; t += 1024) h[t] = 0u;
  __syncthreads();
  for (int e = e0 + tid; e < e0 + nsl; e += 1024) {
    u32 o = kb[e];
    if ((o & fmask) == known) atomicAdd(&h[(o >> shift) & dmask], 1u);
  }
  __syncthreads();
  for (int t = tid; t <= (int)dmask; t += 1024) {
    u32 v = h[t];
    if (v) atomicAdd(&hist[task * 2048 + t], v);
  }
}

// ---------------- K pick: suffix-scan histogram, choose digit ------------------
__global__ __launch_bounds__(1024) void k_pick(
    const u32* __restrict__ hist, u32* __restrict__ state_known,
    u32* __restrict__ state_kneed, u32* __restrict__ resolvedf,
    u64* __restrict__ kth, int nb, int shift, int final_pass) {
  int task = blockIdx.x;
  int tid = threadIdx.x;
  __shared__ u32 A[2048], Bb[2048];
  __shared__ int sh_t;
  __shared__ u32 sh_above;
  u32 kneed = state_kneed[task];
  for (int t = tid; t < nb; t += 1024) A[t] = hist[task * 2048 + t];
  __syncthreads();
  u32* cur = A;
  u32* nxt = Bb;
  for (int off2 = 1; off2 < nb; off2 <<= 1) {
    for (int t = tid; t < nb; t += 1024)
      nxt[t] = cur[t] + ((t + off2 < nb) ? cur[t + off2] : 0u);
    __syncthreads();
    u32* tmp = cur; cur = nxt; nxt = tmp;
  }
  // cur[t] = count of elements with digit >= t
  for (int t = tid; t < nb; t += 1024) {
    u32 s = cur[t];
    u32 above = (t + 1 < nb) ? cur[t + 1] : 0u;
    if (s >= kneed && above < kneed) { sh_t = t; sh_above = above; }
  }
  __syncthreads();
  if (tid == 0) {
    u32 known = state_known[task] | ((u32)sh_t << shift);
    u32 kneed2 = kneed - sh_above;
    state_known[task] = known;
    state_kneed[task] = kneed2;
    if (final_pass) {
      u32 c = cur[sh_t] - sh_above;   // count equal to kth value
      if (kneed2 == c) {
        resolvedf[task] = 1u;
        kth[task] = ((u64)known) << 32;   // take all value-equals
      } else {
        resolvedf[task] = 0u;             // gid tie-break needed
      }
    }
  }
}

// ---------------- K tie: collect gids of value-equal elements ------------------
__global__ __launch_bounds__(1024) void k_tie(
    const u32* __restrict__ keybuf, const u32* __restrict__ state_known,
    const u32* __restrict__ resolvedf, u32* __restrict__ tiecnt,
    u32* __restrict__ tiebuf) {
  int lvl, b, e0, nsl;
  slice_map(blockIdx.x, lvl, b, e0, nsl);
  int task = lvl * 16 + b;
  if (resolvedf[task]) return;
  u32 pval = state_known[task];
  const u32* kb = keybuf + c_KOFF[lvl] + b * c_N[lvl];
  int hw = c_HW[lvl], off = c_OFF[lvl];
  for (int e = e0 + threadIdx.x; e < e0 + nsl; e += 1024) {
    if (kb[e] == pval) {
      int a = e / hw;
      int cell = e - a * hw;
      u32 gid = (u32)(off + cell * 3 + a);
      u32 idx = atomicAdd(&tiecnt[task], 1u);
      if (idx < (u32)TIECAP) tiebuf[task * TIECAP + idx] = gid;
    }
  }
}

// ---------------- K tiepick: kneed-th smallest gid among equals ----------------
__global__ __launch_bounds__(1024) void k_tiepick(
    const u32* __restrict__ tiecnt, const u32* __restrict__ tiebuf,
    const u32* __restrict__ state_known, const u32* __restrict__ state_kneed,
    const u32* __restrict__ resolvedf, u64* __restrict__ kth) {
  int task = blockIdx.x;
  if (resolvedf[task]) return;
  int tid = threadIdx.x;
  __shared__ u32 G[TIECAP];
  __shared__ u32 h[256];
  __shared__ u32 sh_known, sh_kneed;
  u32 c2 = min(tiecnt[task], (u32)TIECAP);
  for (u32 i = tid; i < c2; i += 1024) G[i] = tiebuf[task * TIECAP + i];
  if (tid == 0) { sh_known = 0u; sh_kneed = state_kneed[task]; }
  u32 pmask = 0u;
  __syncthreads();
  for (int pass = 2; pass >= 0; --pass) {  // gid < 2^18 < 2^24
    int shift = pass * 8;
    if (tid < 256) h[tid] = 0u;
    __syncthreads();
    u32 known = sh_known;
    for (u32 i = tid; i < c2; i += 1024) {
      u32 g = G[i];
      if ((g & pmask) == known) atomicAdd(&h[(g >> shift) & 255u], 1u);
    }
    __syncthreads();
    if (tid == 0) {
      u32 kneed = sh_kneed;
      u32 cum = 0;
      for (int t = 0; t < 256; ++t) {   // ascending: kneed-th SMALLEST gid
        u32 v = h[t];
        if (cum + v >= kneed) {
          sh_known = known | ((u32)t << shift);
          sh_kneed = kneed - cum;
          break;
        }
        cum += v;
      }
    }
    pmask |= (0xFFu << shift);
    __syncthreads();
  }
  if (tid == 0)
    kth[task] = (((u64)state_known[task]) << 32) | (u32)(~sh_known);
}

// ---------------- K gather: threshold test + decode + slot write ---------------
__global__ __launch_bounds__(1024) void k_gather(
    const u32* __restrict__ keybuf, const u64* __restrict__ kth,
    const float* __restrict__ reg0, const float* __restrict__ reg1,
    const float* __restrict__ reg2, const float* __restrict__ reg3,
    const float* __restrict__ anchors, u32* __restrict__ counters,
    u64* __restrict__ cand_key) {
  int lvl, b, e0, nsl;
  slice_map(blockIdx.x, lvl, b, e0, nsl);
  int task = lvl * 16 + b;
  u64 kt = kth[task];
  u32 hi = (u32)(kt >> 32);
  const u32* kb = keybuf + c_KOFF[lvl] + b * c_N[lvl];
  int hw = c_HW[lvl], off = c_OFF[lvl];
  for (int e = e0 + threadIdx.x; e < e0 + nsl; e += 1024) {
    u32 o = kb[e];
    if (o < hi) continue;
    int a = e / hw;
    int cell = e - a * hw;
    u32 gid = (u32)(off + cell * 3 + a);
    u64 key = ((u64)o << 32) | (u32)(~gid);
    if (key < kt) continue;
    DecBox bx = decode_box(gid, b, reg0, reg1, reg2, reg3, anchors);
    u64 skey = bx.valid ? key : (key & 0xFFFFFFFFull);
    u32 slot = atomicAdd(&counters[task], 1u);
    if (slot < (u32)PREN)
      cand_key[(size_t)b * NCPAD + (size_t)(c_BASE[lvl] + (int)slot)] = skey;
  }
}

// ---------------- K sort: per-image bitonic sort (desc) of 4096 keys -----------
__global__ __launch_bounds__(1024) void k_sort(u64* __restrict__ cand_key) {
  int b = blockIdx.x;
  int tid = threadIdx.x;
  __shared__ u64 sk[NCPAD];
  for (int p = tid; p < NCPAD; p += 1024) sk[p] = cand_key[(size_t)b * NCPAD + p];
  __syncthreads();
  for (u32 k = 2; k <= NCPAD; k <<= 1) {
    for (u32 j = k >> 1; j > 0; j >>= 1) {
      for (u32 t = tid; t < NCPAD / 2; t += 1024) {
        u32 i = 2u * t - (t & (j - 1u));
        u32 l2 = i | j;
        u64 av = sk[i], bv = sk[l2];
        bool up = ((i & k) == 0u);
        if (up ? (av < bv) : (av > bv)) { sk[i] = bv; sk[l2] = av; }
      }
      __syncthreads();
    }
  }
  for (int p = tid; p < NCPAD; p += 1024) cand_key[(size_t)b * NCPAD + p] = sk[p];
}

// ---------------- K decode: payloads for sorted candidates (full grid) ---------
__global__ __launch_bounds__(1024) void k_decode(
    const u64* __restrict__ cand_key,
    const float* __restrict__ reg0, const float* __restrict__ reg1,
    const float* __restrict__ reg2, const float* __restrict__ reg3,
    const float* __restrict__ anchors,
    float4* __restrict__ sbox, float4* __restrict__ boffA,
    float* __restrict__ area, float* __restrict__ score,
    u64* __restrict__ validmask) {
  int bid = blockIdx.x;
  int b = bid >> 2;
  int p = ((bid & 3) << 10) | threadIdx.x;
  u64 key = cand_key[(size_t)b * NCPAD + p];
  float4 bx4 = make_float4(0.f, 0.f, 0.f, 0.f);
  float4 bo4 = make_float4(0.f, 0.f, 0.f, 0.f);
  float ar = 0.f, sc = 0.f;
  bool vflag = false;
  if (key != 0ull) {
    u32 gid = ~((u32)key);
    vflag = (key >> 32) != 0ull;
    DecBox bx = decode_box(gid, b, reg0, reg1, reg2, reg3, anchors);
    bx4 = make_float4(bx.x1, bx.y1, bx.x2, bx.y2);
    float offv = __fmul_rn((float)bx.lvl, 801.0f);
    bo4 = make_float4(__fadd_rn(bx.x1, offv), __fadd_rn(bx.y1, offv),
                      __fadd_rn(bx.x2, offv), __fadd_rn(bx.y2, offv));
    ar = __fmul_rn(__fsub_rn(bo4.z, bo4.x), __fsub_rn(bo4.w, bo4.y));
    if (vflag) {
      float logit = inv_ord((u32)(key >> 32));
      sc = 1.0f / (1.0f + expf(-logit));
    }
  }
  size_t gi = (size_t)b * NCPAD + (size_t)p;
  sbox[gi] = bx4;
  boffA[gi] = bo4;
  area[gi] = ar;
  score[gi] = sc;
  u64 bal = __ballot(vflag ? 1 : 0);
  if ((threadIdx.x & 63) == 0) validmask[b * 64 + (p >> 6)] = bal;
}

// ---------------- K mask: IoU suppression bitmask matrix + row-nonzero bitmap --
#define RPB 16
__global__ __launch_bounds__(256) void k_mask(
    const float4* __restrict__ boffA, const float* __restrict__ area,
    u64* __restrict__ mask, u64* __restrict__ rowmask) {
  int bg = blockIdx.x;
  int b = bg / 250;
  int g = bg - b * 250;
  int row0 = g * RPB;
  int tid = threadIdx.x;
  int wave = tid >> 6;
  int lane = tid & 63;
  __shared__ float4 rb[RPB];
  __shared__ float ra[RPB];
  if (tid < RPB) {
    int rr = row0 + tid;
    int rc = (rr < NCPAD) ? rr : (NCPAD - 1);
    rb[tid] = boffA[(size_t)b * NCPAD + rc];
    ra[tid] = area[(size_t)b * NCPAD + rc];
  }
  __syncthreads();
  u64* M = mask + (size_t)b * NC * 64;
  u64* RM = rowmask + (size_t)b * NCPAD;
  for (int chunk = 0; chunk < 16; ++chunk) {
    int wword = chunk * 4 + wave;
    int wmaxj = chunk * 256 + wave * 64 + 63;   // this wave's max column
    if (wmaxj <= row0) {
      // whole 16-row group below the diagonal for this wave: all zero
      if (lane == 0) {
#pragma unroll
        for (int rr = 0; rr < RPB; ++rr) {
          int i = row0 + rr;
          if (i < NC) M[(size_t)i * 64 + wword] = 0ull;
        }
      }
      continue;
    }
    int j = chunk * 256 + tid;
    float4 cb = boffA[(size_t)b * NCPAD + j];
    float ca = area[(size_t)b * NCPAD + j];
#pragma unroll
    for (int rr = 0; rr < RPB; ++rr) {
      int i = row0 + rr;
      if (wmaxj <= i) {   // wave entirely j<=i: zero word, skip IoU
        if (lane == 0 && i < NC) M[(size_t)i * 64 + wword] = 0ull;
        continue;
      }
      float4 rbb = rb[rr];
      float ria = ra[rr];
      float ix1 = fmaxf(cb.x, rbb.x);
      float iy1 = fmaxf(cb.y, rbb.y);
      float ix2 = fminf(cb.z, rbb.z);
      float iy2 = fminf(cb.w, rbb.w);
      float inter = __fmul_rn(fmaxf(__fsub_rn(ix2, ix1), 0.0f),
                              fmaxf(__fsub_rn(iy2, iy1), 0.0f));
      float uni = __fsub_rn(__fadd_rn(ca, ria), inter);
      float iou = __fdiv_rn(inter, (uni > 0.0f) ? uni : 1.0f);
      bool pred = (j > i) && (iou > 0.7f);
      u64 bal = __ballot(pred ? 1 : 0);
      if (lane == 0 && i < NC) {
        M[(size_t)i * 64 + wword] = bal;
        if (bal)   // sparse: record that row i has a nonzero word wword
          atomicOr((unsigned long long*)&RM[i], 1ull << wword);
      }
    }
  }
}

// ---------------- K nms: greedy NMS — single wave, scalar resolve, sparse apply
__global__ __launch_bounds__(64) void k_nms(
    const u64* __restrict__ mask, const u64* __restrict__ rowmask,
    const u64* __restrict__ validmask,
    const float4* __restrict__ sbox, const float* __restrict__ score,
    float* __restrict__ out) {
  int b = blockIdx.x;
  int lane = threadIdx.x;
  const u64* M = mask + (size_t)b * NC * 64;
  const u64* RM = rowmask + (size_t)b * NCPAD;
  u64 supp = 0ull;      // lane L holds suppression word L
  u64 keep = 0ull;      // lane L holds keep word L
  u64 valid = validmask[b * 64 + lane];
  // chunk 0 diagonal: lane q holds row q's word 0; rnz: row q's nonzero map
  u64 dch = M[(size_t)lane * 64 + 0];
  u64 rnz = RM[lane];
  for (int W = 0; W < NCHUNK; ++W) {
    int c0 = W << 6;
    u64 s = __shfl(supp, W);
    u64 v = __shfl(valid, W);
    // prefetch next chunk's diagonal block + rowmask (hides under resolve)
    u64 dnext = 0ull, rnext = 0ull;
    if (W + 1 < NCHUNK) {
      int row = c0 + 64 + lane;
      if (row < NC) {
        dnext = M[(size_t)row * 64 + (W + 1)];
        rnext = RM[row];
      }
    }
    // greedy resolve: iterate ONLY over suppressor rows (scalar readlane chain)
    u64 pending = v & ~s;
    u64 kw = 0ull;
    u64 suppressors = __ballot((dch & pending) != 0ull) & pending;
    while (pending) {
      u64 sp = pending & suppressors;
      if (!sp) { kw |= pending; break; }
      int q = __builtin_ctzll(sp);
      u64 below = pending & ((1ull << q) - 1ull);  // non-suppressors: keep all
      kw |= below | (1ull << q);
      u64 supq = readlane_u64(dch, q);
      pending &= ~supq;
      pending &= ~below;
      pending &= ~(1ull << q);
    }
    // cross-chunk apply: only kept rows with a nonzero word beyond W
    u64 kwload = __ballot(((rnz >> W) >> 1) != 0ull) & kw;
    u64 kk = kwload;
    while (kk) {
      int q0 = __builtin_ctzll(kk);
      kk &= kk - 1ull;
      u64 m0 = (lane > W) ? M[(size_t)(c0 + q0) * 64 + lane] : 0ull;
      if (kk) {  // 2-way pipelined second load
        int q1 = __builtin_ctzll(kk);
        kk &= kk - 1ull;
        u64 m1 = (lane > W) ? M[(size_t)(c0 + q1) * 64 + lane] : 0ull;
        m0 |= m1;
      }
      supp |= m0;
    }
    if (lane == W) keep = kw;
    dch = dnext;
    rnz = rnext;
  }
  // rank = exclusive prefix of popcounts across lanes
  int pc = __popcll(keep);
  int incl = pc;
  for (int d = 1; d < 64; d <<= 1) {
    int t = __shfl_up(incl, d);
    if (lane >= d) incl += t;
  }
  int r = incl - pc;
  u64 kk = keep;
  while (kk) {
    int bit = __builtin_ctzll(kk);
    kk &= kk - 1ull;
    if (r < POSTN) {
      int p = lane * 64 + bit;
      float4 bx = sbox[(size_t)b * NCPAD + p];
      size_t ob = ((size_t)b * POSTN + (size_t)r) * 4;
      out[ob + 0] = bx.x;
      out[ob + 1] = bx.y;
      out[ob + 2] = bx.z;
      out[ob + 3] = bx.w;
      out[(size_t)NB * POSTN * 4 + (size_t)b * POSTN + (size_t)r] =
          score[(size_t)b * NCPAD + p];
    }
    ++r;
  }
}

extern "C" void kernel_launch(void* const* d_in, const int* in_sizes, int n_in,
                              void* d_out, int out_size, void* d_ws, size_t ws_size,
                              hipStream_t stream) {
  // setup_inputs dict order: cls0, reg0, cls1, reg1, cls2, reg2, cls3, reg3, anchors
  const float* cls0 = (const float*)d_in[0];
  const float* reg0 = (const float*)d_in[1];
  const float* cls1 = (const float*)d_in[2];
  const float* reg1 = (const float*)d_in[3];
  const float* cls2 = (const float*)d_in[4];
  const float* reg2 = (const float*)d_in[5];
  const float* cls3 = (const float*)d_in[6];
  const float* reg3 = (const float*)d_in[7];
  const float* anchors = (const float*)d_in[8];
  float* out = (float*)d_out;

  char* ws = (char*)d_ws;
  size_t off = 0;
  auto take = [&](size_t bytes) -> void* {
    off = (off + 255) & ~(size_t)255;
    void* p = ws + off;
    off += bytes;
    return p;
  };
  u64* mask      = (u64*)take((size_t)NB * NC * 64 * 8);   // 32.8 MB
  // keybuf (10.2 MB) and tiebuf (2 MB) alias the mask region: they are
  // dead before k_mask writes it (stream-ordered).
  u32* keybuf    = (u32*)mask;
  u32* tiebuf    = (u32*)((char*)mask + (20u << 20));
  u64* rowmask   = (u64*)take((size_t)NB * NCPAD * 8);     // 512 KB
  u64* cand_key  = (u64*)take((size_t)NB * NCPAD * 8);
  float4* sbox   = (float4*)take((size_t)NB * NCPAD * 16);
  float4* boffA  = (float4*)take((size_t)NB * NCPAD * 16);
  float* area    = (float*)take((size_t)NB * NCPAD * 4);
  float* score   = (float*)take((size_t)NB * NCPAD * 4);
  u64* validmask = (u64*)take((size_t)NB * 64 * 8);
  u32* hist1     = (u32*)take((size_t)64 * 2048 * 4);
  u32* hist2     = (u32*)take((size_t)64 * 2048 * 4);
  u32* hist3     = (u32*)take((size_t)64 * 2048 * 4);
  u64* kth       = (u64*)take((size_t)64 * 8);
  u32* counters  = (u32*)take((size_t)64 * 4);
  u32* tiecnt    = (u32*)take((size_t)64 * 4);
  u32* resolvedf = (u32*)take((size_t)64 * 4);
  u32* state_known = (u32*)take((size_t)64 * 4);
  u32* state_kneed = (u32*)take((size_t)64 * 4);
  (void)ws_size; (void)in_sizes; (void)n_in; (void)out_size;

  k_zero<<<512, 256, 0, stream>>>(out, counters, cand_key, hist1, hist2, hist3,
                                  tiecnt, resolvedf, state_known, state_kneed,
                                  rowmask);
  k_keys<<<192, 1024, 0, stream>>>(cls0, cls1, cls2, cls3, keybuf, hist1);
  k_pick<<<64, 1024, 0, stream>>>(hist1, state_known, state_kneed, resolvedf,
                                  kth, 2048, 21, 0);
  k_hist<<<192, 1024, 0, stream>>>(keybuf, state_known, hist2, 10, 0xFFE00000u,
                                   0x7FFu);
  k_pick<<<64, 1024, 0, stream>>>(hist2, state_known, state_kneed, resolvedf,
                                  kth, 2048, 10, 0);
  k_hist<<<192, 1024, 0, stream>>>(keybuf, state_known, hist3, 0, 0xFFFFFC00u,
                                   0x3FFu);
  k_pick<<<64, 1024, 0, stream>>>(hist3, state_known, state_kneed, resolvedf,
                                  kth, 1024, 0, 1);
  k_tie<<<192, 1024, 0, stream>>>(keybuf, state_known, resolvedf, tiecnt,
                                  tiebuf);
  k_tiepick<<<64, 1024, 0, stream>>>(tiecnt, tiebuf, state_known, state_kneed,
                                     resolvedf, kth);
  k_gather<<<192, 1024, 0, stream>>>(keybuf, kth, reg0, reg1, reg2, reg3,
                                     anchors, counters, cand_key);
  k_sort<<<NB, 1024, 0, stream>>>(cand_key);
  k_decode<<<NB * 4, 1024, 0, stream>>>(cand_key, reg0, reg1, reg2, reg3,
                                        anchors, sbox, boffA, area, score,
                                        validmask);
  k_mask<<<NB * 250, 256, 0, stream>>>(boffA, area, mask, rowmask);
  k_nms<<<NB, 64, 0, stream>>>(mask, rowmask, validmask, sbox, score, out);
}

// Round 7
// 330.162 us; speedup vs baseline: 4.6250x; 1.5700x over previous
//
#include <hip/hip_runtime.h>
#include <cstdint>
#include <cstddef>

typedef uint32_t u32;
typedef uint64_t u64;

#define NB 16
#define POSTN 1000
#define PREN 1000
#define LSEG 1024     // per-level segment (1000 candidates + 24 pad)
#define LCH 16        // chunks of 64 per level
#define TIECAP 8192

__constant__ int c_N[4]    = {120000, 30000, 7500, 1875};
__constant__ int c_OFF[4]  = {0, 120000, 150000, 157500};
__constant__ int c_HW[4]   = {40000, 10000, 2500, 625};
__constant__ int c_W[4]    = {200, 100, 50, 25};
__constant__ int c_BASE[4] = {0, 1024, 2048, 3072};
__constant__ int c_KOFF[4] = {0, 1920000, 2400000, 2520000};

__device__ __forceinline__ u32 ord_bits(float f) {
  u32 u = __float_as_uint(f);
  return (u & 0x80000000u) ? ~u : (u | 0x80000000u);
}
__device__ __forceinline__ float inv_ord(u32 o) {
  u32 bits = (o & 0x80000000u) ? (o ^ 0x80000000u) : ~o;
  return __uint_as_float(bits);
}
__device__ __forceinline__ u64 readlane_u64(u64 v, int l) {
  u32 lo = (u32)__builtin_amdgcn_readlane((int)(u32)v, l);
  u32 hi = (u32)__builtin_amdgcn_readlane((int)(u32)(v >> 32), l);
  return (((u64)hi) << 32) | (u64)lo;
}

// 192-block slice map: 8 blocks/task lvl0, 2/task lvl1, 1/task lvl2+3
__device__ __forceinline__ void slice_map(int bid, int& lvl, int& b, int& e0,
                                          int& nsl) {
  if (bid < 128)      { lvl = 0; b = bid >> 3; e0 = (bid & 7) * 15000; nsl = 15000; }
  else if (bid < 160) { lvl = 1; int t = bid - 128; b = t >> 1; e0 = (t & 1) * 15000; nsl = 15000; }
  else if (bid < 176) { lvl = 2; b = bid - 160; e0 = 0; nsl = 7500; }
  else                { lvl = 3; b = bid - 176; e0 = 0; nsl = 1875; }
}

struct DecBox { float x1, y1, x2, y2; int lvl; bool valid; };

__device__ DecBox decode_box(u32 gid, int b,
    const float* __restrict__ reg0, const float* __restrict__ reg1,
    const float* __restrict__ reg2, const float* __restrict__ reg3,
    const float* __restrict__ anchors) {
  int lvl = (gid < 120000u) ? 0 : (gid < 150000u) ? 1 : (gid < 157500u) ? 2 : 3;
  int local = (int)gid - c_OFF[lvl];
  int a = local % 3;
  int cell = local / 3;
  int w = c_W[lvl];
  int hw = c_HW[lvl];
  int y = cell / w;
  int x = cell - y * w;
  const float* reg = (lvl == 0) ? reg0 : (lvl == 1) ? reg1 : (lvl == 2) ? reg2 : reg3;
  size_t base = ((size_t)(b * 12 + a * 4) * (size_t)w + (size_t)y) * (size_t)w + (size_t)x;
  const float CLIPV = 4.135166556742356f; // log(1000/16) as f32
  float dx = reg[base];
  float dy = reg[base + (size_t)hw];
  float dwv = fminf(reg[base + 2 * (size_t)hw], CLIPV);
  float dhv = fminf(reg[base + 3 * (size_t)hw], CLIPV);
  float a0 = anchors[(size_t)gid * 4 + 0];
  float a1 = anchors[(size_t)gid * 4 + 1];
  float a2 = anchors[(size_t)gid * 4 + 2];
  float a3 = anchors[(size_t)gid * 4 + 3];
  float wa = __fsub_rn(a2, a0);
  float ha = __fsub_rn(a3, a1);
  float cxa = __fadd_rn(a0, __fmul_rn(0.5f, wa));
  float cya = __fadd_rn(a1, __fmul_rn(0.5f, ha));
  float pcx = __fadd_rn(__fmul_rn(dx, wa), cxa);
  float pcy = __fadd_rn(__fmul_rn(dy, ha), cya);
  float pw = __fmul_rn(expf(dwv), wa);
  float ph = __fmul_rn(expf(dhv), ha);
  float x1 = __fsub_rn(pcx, __fmul_rn(0.5f, pw));
  float y1 = __fsub_rn(pcy, __fmul_rn(0.5f, ph));
  float x2 = __fadd_rn(pcx, __fmul_rn(0.5f, pw));
  float y2 = __fadd_rn(pcy, __fmul_rn(0.5f, ph));
  x1 = fminf(fmaxf(x1, 0.0f), 800.0f);
  y1 = fminf(fmaxf(y1, 0.0f), 800.0f);
  x2 = fminf(fmaxf(x2, 0.0f), 800.0f);
  y2 = fminf(fmaxf(y2, 0.0f), 800.0f);
  DecBox r;
  r.x1 = x1; r.y1 = y1; r.x2 = x2; r.y2 = y2; r.lvl = lvl;
  r.valid = (__fsub_rn(x2, x1) >= 1.0f) && (__fsub_rn(y2, y1) >= 1.0f);
  return r;
}

// ---------------- K0: zero state ----------------------------------------------
__global__ void k_zero(float* __restrict__ out, u32* __restrict__ counters,
                       u64* __restrict__ cand_key, u32* __restrict__ hist1,
                       u32* __restrict__ hist2, u32* __restrict__ hist3,
                       u32* __restrict__ tiecnt, u32* __restrict__ resolvedf,
                       u32* __restrict__ state_known,
                       u32* __restrict__ state_kneed) {
  int i = blockIdx.x * blockDim.x + threadIdx.x;
  if (i < NB * POSTN * 5) out[i] = 0.0f;
  if (i < NB * 4096) cand_key[i] = 0ull;
  if (i < 64 * 2048) { hist1[i] = 0u; hist2[i] = 0u; hist3[i] = 0u; }
  if (i < 64) {
    counters[i] = 0u; tiecnt[i] = 0u; resolvedf[i] = 0u;
    state_known[i] = 0u; state_kneed[i] = (u32)PREN;
  }
}

// ---------------- K1: ord keys + pass-1 histogram (full chip) -----------------
__global__ __launch_bounds__(1024) void k_keys(
    const float* __restrict__ cls0, const float* __restrict__ cls1,
    const float* __restrict__ cls2, const float* __restrict__ cls3,
    u32* __restrict__ keybuf, u32* __restrict__ hist1) {
  int lvl, b, e0, nsl;
  slice_map(blockIdx.x, lvl, b, e0, nsl);
  const float* cls = (lvl == 0) ? cls0 : (lvl == 1) ? cls1 : (lvl == 2) ? cls2 : cls3;
  int n = c_N[lvl];
  const float* cp = cls + (size_t)b * n;
  u32* kb = keybuf + c_KOFF[lvl] + b * n;
  int tid = threadIdx.x;
  __shared__ u32 h[2048];
  for (int t = tid; t < 2048; t += 1024) h[t] = 0u;
  __syncthreads();
  for (int e = e0 + tid; e < e0 + nsl; e += 1024) {
    u32 o = ord_bits(cp[e]);
    kb[e] = o;
    atomicAdd(&h[o >> 21], 1u);
  }
  __syncthreads();
  int task = lvl * 16 + b;
  for (int t = tid; t < 2048; t += 1024) {
    u32 v = h[t];
    if (v) atomicAdd(&hist1[task * 2048 + t], v);
  }
}

// ---------------- K2/K3: filtered histogram passes -----------------------------
__global__ __launch_bounds__(1024) void k_hist(
    const u32* __restrict__ keybuf, const u32* __restrict__ state_known,
    u32* __restrict__ hist, int shift, u32 fmask, u32 dmask) {
  int lvl, b, e0, nsl;
  slice_map(blockIdx.x, lvl, b, e0, nsl);
  int task = lvl * 16 + b;
  u32 known = state_known[task];
  const u32* kb = keybuf + c_KOFF[lvl] + b * c_N[lvl];
  int tid = threadIdx.x;
  __shared__ u32 h[2048];
  for (int t = tid; t <= (int)dmask; t += 1024) h[t] = 0u;
  __syncthreads();
  for (int e = e0 + tid; e < e0 + nsl; e += 1024) {
    u32 o = kb[e];
    if ((o & fmask) == known) atomicAdd(&h[(o >> shift) & dmask], 1u);
  }
  __syncthreads();
  for (int t = tid; t <= (int)dmask; t += 1024) {
    u32 v = h[t];
    if (v) atomicAdd(&hist[task * 2048 + t], v);
  }
}

// ---------------- K pick: suffix-scan histogram, choose digit ------------------
__global__ __launch_bounds__(1024) void k_pick(
    const u32* __restrict__ hist, u32* __restrict__ state_known,
    u32* __restrict__ state_kneed, u32* __restrict__ resolvedf,
    u64* __restrict__ kth, int nb, int shift, int final_pass) {
  int task = blockIdx.x;
  int tid = threadIdx.x;
  __shared__ u32 A[2048], Bb[2048];
  __shared__ int sh_t;
  __shared__ u32 sh_above;
  u32 kneed = state_kneed[task];
  for (int t = tid; t < nb; t += 1024) A[t] = hist[task * 2048 + t];
  __syncthreads();
  u32* cur = A;
  u32* nxt = Bb;
  for (int off2 = 1; off2 < nb; off2 <<= 1) {
    for (int t = tid; t < nb; t += 1024)
      nxt[t] = cur[t] + ((t + off2 < nb) ? cur[t + off2] : 0u);
    __syncthreads();
    u32* tmp = cur; cur = nxt; nxt = tmp;
  }
  // cur[t] = count of elements with digit >= t
  for (int t = tid; t < nb; t += 1024) {
    u32 s = cur[t];
    u32 above = (t + 1 < nb) ? cur[t + 1] : 0u;
    if (s >= kneed && above < kneed) { sh_t = t; sh_above = above; }
  }
  __syncthreads();
  if (tid == 0) {
    u32 known = state_known[task] | ((u32)sh_t << shift);
    u32 kneed2 = kneed - sh_above;
    state_known[task] = known;
    state_kneed[task] = kneed2;
    if (final_pass) {
      u32 c = cur[sh_t] - sh_above;   // count equal to kth value
      if (kneed2 == c) {
        resolvedf[task] = 1u;
        kth[task] = ((u64)known) << 32;   // take all value-equals
      } else {
        resolvedf[task] = 0u;             // gid tie-break needed
      }
    }
  }
}

// ---------------- K tie: collect gids of value-equal elements ------------------
__global__ __launch_bounds__(1024) void k_tie(
    const u32* __restrict__ keybuf, const u32* __restrict__ state_known,
    const u32* __restrict__ resolvedf, u32* __restrict__ tiecnt,
    u32* __restrict__ tiebuf) {
  int lvl, b, e0, nsl;
  slice_map(blockIdx.x, lvl, b, e0, nsl);
  int task = lvl * 16 + b;
  if (resolvedf[task]) return;
  u32 pval = state_known[task];
  const u32* kb = keybuf + c_KOFF[lvl] + b * c_N[lvl];
  int hw = c_HW[lvl], off = c_OFF[lvl];
  for (int e = e0 + threadIdx.x; e < e0 + nsl; e += 1024) {
    if (kb[e] == pval) {
      int a = e / hw;
      int cell = e - a * hw;
      u32 gid = (u32)(off + cell * 3 + a);
      u32 idx = atomicAdd(&tiecnt[task], 1u);
      if (idx < (u32)TIECAP) tiebuf[task * TIECAP + idx] = gid;
    }
  }
}

// ---------------- K tiepick: kneed-th smallest gid among equals ----------------
__global__ __launch_bounds__(1024) void k_tiepick(
    const u32* __restrict__ tiecnt, const u32* __restrict__ tiebuf,
    const u32* __restrict__ state_known, const u32* __restrict__ state_kneed,
    const u32* __restrict__ resolvedf, u64* __restrict__ kth) {
  int task = blockIdx.x;
  if (resolvedf[task]) return;
  int tid = threadIdx.x;
  __shared__ u32 G[TIECAP];
  __shared__ u32 h[256];
  __shared__ u32 sh_known, sh_kneed;
  u32 c2 = min(tiecnt[task], (u32)TIECAP);
  for (u32 i = tid; i < c2; i += 1024) G[i] = tiebuf[task * TIECAP + i];
  if (tid == 0) { sh_known = 0u; sh_kneed = state_kneed[task]; }
  u32 pmask = 0u;
  __syncthreads();
  for (int pass = 2; pass >= 0; --pass) {  // gid < 2^18 < 2^24
    int shift = pass * 8;
    if (tid < 256) h[tid] = 0u;
    __syncthreads();
    u32 known = sh_known;
    for (u32 i = tid; i < c2; i += 1024) {
      u32 g = G[i];
      if ((g & pmask) == known) atomicAdd(&h[(g >> shift) & 255u], 1u);
    }
    __syncthreads();
    if (tid == 0) {
      u32 kneed = sh_kneed;
      u32 cum = 0;
      for (int t = 0; t < 256; ++t) {   // ascending: kneed-th SMALLEST gid
        u32 v = h[t];
        if (cum + v >= kneed) {
          sh_known = known | ((u32)t << shift);
          sh_kneed = kneed - cum;
          break;
        }
        cum += v;
      }
    }
    pmask |= (0xFFu << shift);
    __syncthreads();
  }
  if (tid == 0)
    kth[task] = (((u64)state_known[task]) << 32) | (u32)(~sh_known);
}

// ---------------- K gather: threshold test + slot write ------------------------
__global__ __launch_bounds__(1024) void k_gather(
    const u32* __restrict__ keybuf, const u64* __restrict__ kth,
    const float* __restrict__ reg0, const float* __restrict__ reg1,
    const float* __restrict__ reg2, const float* __restrict__ reg3,
    const float* __restrict__ anchors, u32* __restrict__ counters,
    u64* __restrict__ cand_key) {
  int lvl, b, e0, nsl;
  slice_map(blockIdx.x, lvl, b, e0, nsl);
  int task = lvl * 16 + b;
  u64 kt = kth[task];
  u32 hi = (u32)(kt >> 32);
  const u32* kb = keybuf + c_KOFF[lvl] + b * c_N[lvl];
  int hw = c_HW[lvl], off = c_OFF[lvl];
  for (int e = e0 + threadIdx.x; e < e0 + nsl; e += 1024) {
    u32 o = kb[e];
    if (o < hi) continue;
    int a = e / hw;
    int cell = e - a * hw;
    u32 gid = (u32)(off + cell * 3 + a);
    u64 key = ((u64)o << 32) | (u32)(~gid);
    if (key < kt) continue;
    DecBox bx = decode_box(gid, b, reg0, reg1, reg2, reg3, anchors);
    u64 skey = bx.valid ? key : (key & 0xFFFFFFFFull);
    u32 slot = atomicAdd(&counters[task], 1u);
    if (slot < (u32)PREN)
      cand_key[(size_t)b * 4096 + (size_t)(c_BASE[lvl] + (int)slot)] = skey;
  }
}

// ---------------- K sortl: per-(image,level) bitonic sort (desc) of 1024 -------
__global__ __launch_bounds__(512) void k_sortl(u64* __restrict__ cand_key) {
  int bl = blockIdx.x;                 // b*4 + lvl
  int tid = threadIdx.x;
  __shared__ u64 sk[LSEG];
  sk[tid] = cand_key[(size_t)bl * LSEG + tid];
  sk[tid + 512] = cand_key[(size_t)bl * LSEG + tid + 512];
  __syncthreads();
  for (u32 k = 2; k <= LSEG; k <<= 1) {
    for (u32 j = k >> 1; j > 0; j >>= 1) {
      u32 i = 2u * tid - (tid & (j - 1u));
      u32 l2 = i | j;
      u64 av = sk[i], bv = sk[l2];
      bool up = ((i & k) == 0u);
      if (up ? (av < bv) : (av > bv)) { sk[i] = bv; sk[l2] = av; }
      __syncthreads();
    }
  }
  cand_key[(size_t)bl * LSEG + tid] = sk[tid];
  cand_key[(size_t)bl * LSEG + tid + 512] = sk[tid + 512];
}

// ---------------- K decodel: payloads for sorted per-level candidates ----------
__global__ __launch_bounds__(1024) void k_decodel(
    const u64* __restrict__ cand_key,
    const float* __restrict__ reg0, const float* __restrict__ reg1,
    const float* __restrict__ reg2, const float* __restrict__ reg3,
    const float* __restrict__ anchors,
    float4* __restrict__ sbox, float4* __restrict__ boffA,
    float* __restrict__ area, float* __restrict__ score,
    u64* __restrict__ vmaskl) {
  int bl = blockIdx.x;
  int b = bl >> 2;
  int p = threadIdx.x;
  u64 key = cand_key[(size_t)bl * LSEG + p];
  float4 bx4 = make_float4(0.f, 0.f, 0.f, 0.f);
  float4 bo4 = make_float4(0.f, 0.f, 0.f, 0.f);
  float ar = 0.f, sc = 0.f;
  bool vflag = false;
  if (key != 0ull) {
    u32 gid = ~((u32)key);
    vflag = (key >> 32) != 0ull;
    DecBox bx = decode_box(gid, b, reg0, reg1, reg2, reg3, anchors);
    bx4 = make_float4(bx.x1, bx.y1, bx.x2, bx.y2);
    float offv = __fmul_rn((float)bx.lvl, 801.0f);
    bo4 = make_float4(__fadd_rn(bx.x1, offv), __fadd_rn(bx.y1, offv),
                      __fadd_rn(bx.x2, offv), __fadd_rn(bx.y2, offv));
    ar = __fmul_rn(__fsub_rn(bo4.z, bo4.x), __fsub_rn(bo4.w, bo4.y));
    if (vflag) {
      float logit = inv_ord((u32)(key >> 32));
      sc = 1.0f / (1.0f + expf(-logit));
    }
  }
  size_t gi = (size_t)bl * LSEG + p;
  sbox[gi] = bx4;
  boffA[gi] = bo4;
  area[gi] = ar;
  score[gi] = sc;
  u64 bal = __ballot(vflag ? 1 : 0);
  if ((p & 63) == 0) vmaskl[bl * LCH + (p >> 6)] = bal;
}

// ---------------- K maskl: per-level IoU bitmask (16 words/row) ----------------
#define RPB 16
__global__ __launch_bounds__(256) void k_maskl(
    const float4* __restrict__ boffA, const float* __restrict__ area,
    u64* __restrict__ maskl, u32* __restrict__ rnzl) {
  int bg = blockIdx.x;
  int bl = bg >> 6;                 // (b*4+lvl)
  int g = bg & 63;                  // row-group within level
  int row0 = g * RPB;
  int tid = threadIdx.x;
  int wave = tid >> 6;
  int lane = tid & 63;
  __shared__ float4 rb[RPB];
  __shared__ float ra[RPB];
  __shared__ u32 rnzs[RPB];
  if (tid < RPB) {
    rb[tid] = boffA[(size_t)bl * LSEG + row0 + tid];
    ra[tid] = area[(size_t)bl * LSEG + row0 + tid];
    rnzs[tid] = 0u;
  }
  __syncthreads();
  u64* M = maskl + (size_t)bl * LSEG * LCH;
  for (int chunk = 0; chunk < 4; ++chunk) {
    int wword = chunk * 4 + wave;
    int wmaxj = chunk * 256 + wave * 64 + 63;   // this wave's max column
    if (wmaxj <= row0) {
      if (lane == 0) {
#pragma unroll
        for (int rr = 0; rr < RPB; ++rr)
          M[(size_t)(row0 + rr) * LCH + wword] = 0ull;
      }
      continue;
    }
    int j = chunk * 256 + tid;
    float4 cb = boffA[(size_t)bl * LSEG + j];
    float ca = area[(size_t)bl * LSEG + j];
#pragma unroll
    for (int rr = 0; rr < RPB; ++rr) {
      int i = row0 + rr;
      if (wmaxj <= i) {
        if (lane == 0) M[(size_t)i * LCH + wword] = 0ull;
        continue;
      }
      float4 rbb = rb[rr];
      float ria = ra[rr];
      float ix1 = fmaxf(cb.x, rbb.x);
      float iy1 = fmaxf(cb.y, rbb.y);
      float ix2 = fminf(cb.z, rbb.z);
      float iy2 = fminf(cb.w, rbb.w);
      float inter = __fmul_rn(fmaxf(__fsub_rn(ix2, ix1), 0.0f),
                              fmaxf(__fsub_rn(iy2, iy1), 0.0f));
      float uni = __fsub_rn(__fadd_rn(ca, ria), inter);
      float iou = __fdiv_rn(inter, (uni > 0.0f) ? uni : 1.0f);
      bool pred = (j > i) && (iou > 0.7f);
      u64 bal = __ballot(pred ? 1 : 0);
      if (lane == 0) {
        M[(size_t)i * LCH + wword] = bal;
        if (bal) atomicOr(&rnzs[rr], 1u << wword);
      }
    }
  }
  __syncthreads();
  if (tid < RPB) rnzl[(size_t)bl * LSEG + row0 + tid] = rnzs[tid];
}

// ---------------- K nmsl: per-(image,level) greedy NMS + kept compaction -------
__global__ __launch_bounds__(64) void k_nmsl(
    const u64* __restrict__ maskl, const u32* __restrict__ rnzl,
    const u64* __restrict__ vmaskl, const u64* __restrict__ cand_key,
    u64* __restrict__ keptkeys, u32* __restrict__ keptpos,
    u32* __restrict__ keptcnt) {
  int bl = blockIdx.x;
  int lane = threadIdx.x;
  const u64* M = maskl + (size_t)bl * LSEG * LCH;
  const u32* RZ = rnzl + (size_t)bl * LSEG;
  u64 supp = 0ull;   // lane w<16 holds suppression word w
  u64 keep = 0ull;   // lane w<16 holds keep word w
  u64 vword = (lane < LCH) ? vmaskl[bl * LCH + lane] : 0ull;
  u64 dch = M[(size_t)lane * LCH + 0];
  u32 rnz = RZ[lane];
  for (int W = 0; W < LCH; ++W) {
    int c0 = W << 6;
    u64 s = __shfl(supp, W);
    u64 v = __shfl(vword, W);
    u64 dnext = 0ull; u32 rnext = 0u;
    if (W + 1 < LCH) {
      int row = c0 + 64 + lane;
      dnext = M[(size_t)row * LCH + (W + 1)];
      rnext = RZ[row];
    }
    // greedy resolve: scalar readlane over suppressor rows only
    u64 pending = v & ~s;
    u64 kw = 0ull;
    u64 suppressors = __ballot((dch & pending) != 0ull) & pending;
    while (pending) {
      u64 sp = pending & suppressors;
      if (!sp) { kw |= pending; break; }
      int q = __builtin_ctzll(sp);
      u64 below = pending & ((1ull << q) - 1ull);
      kw |= below | (1ull << q);
      u64 supq = readlane_u64(dch, q);
      pending &= ~supq;
      pending &= ~below;
      pending &= ~(1ull << q);
    }
    // sparse apply: only kept rows with a nonzero word beyond W
    u64 kwload = __ballot(((rnz >> W) >> 1) != 0u) & kw;
    u64 kk = kwload;
    bool ld = (lane > W) && (lane < LCH);
    while (kk) {
      int q0 = __builtin_ctzll(kk);
      kk &= kk - 1ull;
      u64 m0 = ld ? M[(size_t)(c0 + q0) * LCH + lane] : 0ull;
      if (kk) {
        int q1 = __builtin_ctzll(kk);
        kk &= kk - 1ull;
        u64 m1 = ld ? M[(size_t)(c0 + q1) * LCH + lane] : 0ull;
        m0 |= m1;
      }
      supp |= m0;
    }
    if (lane == W) keep = kw;
    dch = dnext;
    rnz = rnext;
  }
  // compact kept: prefix popcount across lanes
  int pc = __popcll(keep);
  int incl = pc;
  for (int d = 1; d < 64; d <<= 1) {
    int t = __shfl_up(incl, d);
    if (lane >= d) incl += t;
  }
  int r = incl - pc;
  u64 kk = keep;
  while (kk) {
    int bit = __builtin_ctzll(kk);
    kk &= kk - 1ull;
    int p = lane * 64 + bit;
    keptkeys[(size_t)bl * LSEG + r] = cand_key[(size_t)bl * LSEG + p];
    keptpos[(size_t)bl * LSEG + r] = (u32)p;
    ++r;
  }
  if (lane == 63) keptcnt[bl] = (u32)incl;
}

// ---------------- K out: global rank via cross-level binary search -------------
__global__ __launch_bounds__(1024) void k_out(
    const u64* __restrict__ keptkeys, const u32* __restrict__ keptpos,
    const u32* __restrict__ keptcnt, const float4* __restrict__ sbox,
    const float* __restrict__ score, float* __restrict__ out) {
  int bl = blockIdx.x;
  int b = bl >> 2;
  int l = bl & 3;
  int r = threadIdx.x;
  u32 cnt = keptcnt[bl];
  if (r >= (int)cnt) return;
  u64 K = keptkeys[(size_t)bl * LSEG + r];
  int rank = r;
#pragma unroll
  for (int dl = 0; dl < 4; ++dl) {
    if (dl == l) continue;
    int obl = (b << 2) | dl;
    const u64* arr = keptkeys + (size_t)obl * LSEG;
    int lo = 0, hi = (int)keptcnt[obl];
    while (lo < hi) {
      int mid = (lo + hi) >> 1;
      if (arr[mid] > K) lo = mid + 1; else hi = mid;
    }
    rank += lo;
  }
  if (rank < POSTN) {
    u32 p = keptpos[(size_t)bl * LSEG + r];
    float4 bx = sbox[(size_t)bl * LSEG + p];
    size_t ob = ((size_t)b * POSTN + (size_t)rank) * 4;
    out[ob + 0] = bx.x;
    out[ob + 1] = bx.y;
    out[ob + 2] = bx.z;
    out[ob + 3] = bx.w;
    out[(size_t)NB * POSTN * 4 + (size_t)b * POSTN + (size_t)rank] =
        score[(size_t)bl * LSEG + p];
  }
}

extern "C" void kernel_launch(void* const* d_in, const int* in_sizes, int n_in,
                              void* d_out, int out_size, void* d_ws, size_t ws_size,
                              hipStream_t stream) {
  // setup_inputs dict order: cls0, reg0, cls1, reg1, cls2, reg2, cls3, reg3, anchors
  const float* cls0 = (const float*)d_in[0];
  const float* reg0 = (const float*)d_in[1];
  const float* cls1 = (const float*)d_in[2];
  const float* reg1 = (const float*)d_in[3];
  const float* cls2 = (const float*)d_in[4];
  const float* reg2 = (const float*)d_in[5];
  const float* cls3 = (const float*)d_in[6];
  const float* reg3 = (const float*)d_in[7];
  const float* anchors = (const float*)d_in[8];
  float* out = (float*)d_out;

  char* ws = (char*)d_ws;
  size_t off = 0;
  auto take = [&](size_t bytes) -> void* {
    off = (off + 255) & ~(size_t)255;
    void* p = ws + off;
    off += bytes;
    return p;
  };
  u32* keybuf    = (u32*)take((size_t)2550000 * 4);          // 10.2 MB
  u32* tiebuf    = (u32*)take((size_t)64 * TIECAP * 4);      // 2 MB
  u64* maskl     = (u64*)take((size_t)64 * LSEG * LCH * 8);  // 8.4 MB
  u32* rnzl      = (u32*)take((size_t)64 * LSEG * 4);        // 256 KB
  u64* cand_key  = (u64*)take((size_t)NB * 4096 * 8);        // 512 KB
  float4* sbox   = (float4*)take((size_t)64 * LSEG * 16);    // 1 MB
  float4* boffA  = (float4*)take((size_t)64 * LSEG * 16);    // 1 MB
  float* area    = (float*)take((size_t)64 * LSEG * 4);
  float* score   = (float*)take((size_t)64 * LSEG * 4);
  u64* vmaskl    = (u64*)take((size_t)64 * LCH * 8);
  u64* keptkeys  = (u64*)take((size_t)64 * LSEG * 8);        // 512 KB
  u32* keptpos   = (u32*)take((size_t)64 * LSEG * 4);        // 256 KB
  u32* keptcnt   = (u32*)take((size_t)64 * 4);
  u32* hist1     = (u32*)take((size_t)64 * 2048 * 4);
  u32* hist2     = (u32*)take((size_t)64 * 2048 * 4);
  u32* hist3     = (u32*)take((size_t)64 * 2048 * 4);
  u64* kth       = (u64*)take((size_t)64 * 8);
  u32* counters  = (u32*)take((size_t)64 * 4);
  u32* tiecnt    = (u32*)take((size_t)64 * 4);
  u32* resolvedf = (u32*)take((size_t)64 * 4);
  u32* state_known = (u32*)take((size_t)64 * 4);
  u32* state_kneed = (u32*)take((size_t)64 * 4);
  (void)ws_size; (void)in_sizes; (void)n_in; (void)out_size;

  k_zero<<<512, 256, 0, stream>>>(out, counters, cand_key, hist1, hist2, hist3,
                                  tiecnt, resolvedf, state_known, state_kneed);
  k_keys<<<192, 1024, 0, stream>>>(cls0, cls1, cls2, cls3, keybuf, hist1);
  k_pick<<<64, 1024, 0, stream>>>(hist1, state_known, state_kneed, resolvedf,
                                  kth, 2048, 21, 0);
  k_hist<<<192, 1024, 0, stream>>>(keybuf, state_known, hist2, 10, 0xFFE00000u,
                                   0x7FFu);
  k_pick<<<64, 1024, 0, stream>>>(hist2, state_known, state_kneed, resolvedf,
                                  kth, 2048, 10, 0);
  k_hist<<<192, 1024, 0, stream>>>(keybuf, state_known, hist3, 0, 0xFFFFFC00u,
                                   0x3FFu);
  k_pick<<<64, 1024, 0, stream>>>(hist3, state_known, state_kneed, resolvedf,
                                  kth, 1024, 0, 1);
  k_tie<<<192, 1024, 0, stream>>>(keybuf, state_known, resolvedf, tiecnt,
                                  tiebuf);
  k_tiepick<<<64, 1024, 0, stream>>>(tiecnt, tiebuf, state_known, state_kneed,
                                     resolvedf, kth);
  k_gather<<<192, 1024, 0, stream>>>(keybuf, kth, reg0, reg1, reg2, reg3,
                                     anchors, counters, cand_key);
  k_sortl<<<64, 512, 0, stream>>>(cand_key);
  k_decodel<<<64, 1024, 0, stream>>>(cand_key, reg0, reg1, reg2, reg3,
                                     anchors, sbox, boffA, area, score,
                                     vmaskl);
  k_maskl<<<64 * 64, 256, 0, stream>>>(boffA, area, maskl, rnzl);
  k_nmsl<<<64, 64, 0, stream>>>(maskl, rnzl, vmaskl, cand_key, keptkeys,
                                keptpos, keptcnt);
  k_out<<<64, 1024, 0, stream>>>(keptkeys, keptpos, keptcnt, sbox, score, out);
}

// Round 8
// 185.277 us; speedup vs baseline: 8.2417x; 1.7820x over previous
//
#include <hip/hip_runtime.h>
#include <cstdint>
#include <cstddef>

typedef uint32_t u32;
typedef uint64_t u64;

#define NB 16
#define POSTN 1000
#define PREN 1000
#define LSEG 1024     // per-level segment (1000 candidates + 24 pad)
#define LCH 16        // chunks of 64 per level
#define SIDECAP 4096  // per-task boundary-bucket buffer
#define BSIDE 2048    // per-block LDS side list

__constant__ int c_N[4]    = {120000, 30000, 7500, 1875};
__constant__ int c_OFF[4]  = {0, 120000, 150000, 157500};
__constant__ int c_HW[4]   = {40000, 10000, 2500, 625};
__constant__ int c_W[4]    = {200, 100, 50, 25};
__constant__ int c_BASE[4] = {0, 1024, 2048, 3072};

__device__ __forceinline__ u32 ord_bits(float f) {
  u32 u = __float_as_uint(f);
  return (u & 0x80000000u) ? ~u : (u | 0x80000000u);
}
__device__ __forceinline__ float inv_ord(u32 o) {
  u32 bits = (o & 0x80000000u) ? (o ^ 0x80000000u) : ~o;
  return __uint_as_float(bits);
}
__device__ __forceinline__ u64 readlane_u64(u64 v, int l) {
  u32 lo = (u32)__builtin_amdgcn_readlane((int)(u32)v, l);
  u32 hi = (u32)__builtin_amdgcn_readlane((int)(u32)(v >> 32), l);
  return (((u64)hi) << 32) | (u64)lo;
}

// 192-block slice map: 8 blocks/task lvl0, 2/task lvl1, 1/task lvl2+3
__device__ __forceinline__ void slice_map(int bid, int& lvl, int& b, int& e0,
                                          int& nsl) {
  if (bid < 128)      { lvl = 0; b = bid >> 3; e0 = (bid & 7) * 15000; nsl = 15000; }
  else if (bid < 160) { lvl = 1; int t = bid - 128; b = t >> 1; e0 = (t & 1) * 15000; nsl = 15000; }
  else if (bid < 176) { lvl = 2; b = bid - 160; e0 = 0; nsl = 7500; }
  else                { lvl = 3; b = bid - 176; e0 = 0; nsl = 1875; }
}

struct DecBox { float x1, y1, x2, y2; int lvl; bool valid; };

__device__ DecBox decode_box(u32 gid, int b,
    const float* __restrict__ reg0, const float* __restrict__ reg1,
    const float* __restrict__ reg2, const float* __restrict__ reg3,
    const float* __restrict__ anchors) {
  int lvl = (gid < 120000u) ? 0 : (gid < 150000u) ? 1 : (gid < 157500u) ? 2 : 3;
  int local = (int)gid - c_OFF[lvl];
  int a = local % 3;
  int cell = local / 3;
  int w = c_W[lvl];
  int hw = c_HW[lvl];
  int y = cell / w;
  int x = cell - y * w;
  const float* reg = (lvl == 0) ? reg0 : (lvl == 1) ? reg1 : (lvl == 2) ? reg2 : reg3;
  size_t base = ((size_t)(b * 12 + a * 4) * (size_t)w + (size_t)y) * (size_t)w + (size_t)x;
  const float CLIPV = 4.135166556742356f; // log(1000/16) as f32
  float dx = reg[base];
  float dy = reg[base + (size_t)hw];
  float dwv = fminf(reg[base + 2 * (size_t)hw], CLIPV);
  float dhv = fminf(reg[base + 3 * (size_t)hw], CLIPV);
  float a0 = anchors[(size_t)gid * 4 + 0];
  float a1 = anchors[(size_t)gid * 4 + 1];
  float a2 = anchors[(size_t)gid * 4 + 2];
  float a3 = anchors[(size_t)gid * 4 + 3];
  float wa = __fsub_rn(a2, a0);
  float ha = __fsub_rn(a3, a1);
  float cxa = __fadd_rn(a0, __fmul_rn(0.5f, wa));
  float cya = __fadd_rn(a1, __fmul_rn(0.5f, ha));
  float pcx = __fadd_rn(__fmul_rn(dx, wa), cxa);
  float pcy = __fadd_rn(__fmul_rn(dy, ha), cya);
  float pw = __fmul_rn(expf(dwv), wa);
  float ph = __fmul_rn(expf(dhv), ha);
  float x1 = __fsub_rn(pcx, __fmul_rn(0.5f, pw));
  float y1 = __fsub_rn(pcy, __fmul_rn(0.5f, ph));
  float x2 = __fadd_rn(pcx, __fmul_rn(0.5f, pw));
  float y2 = __fadd_rn(pcy, __fmul_rn(0.5f, ph));
  x1 = fminf(fmaxf(x1, 0.0f), 800.0f);
  y1 = fminf(fmaxf(y1, 0.0f), 800.0f);
  x2 = fminf(fmaxf(x2, 0.0f), 800.0f);
  y2 = fminf(fmaxf(y2, 0.0f), 800.0f);
  DecBox r;
  r.x1 = x1; r.y1 = y1; r.x2 = x2; r.y2 = y2; r.lvl = lvl;
  r.valid = (__fsub_rn(x2, x1) >= 1.0f) && (__fsub_rn(y2, y1) >= 1.0f);
  return r;
}

// ---------------- K0: zero state ----------------------------------------------
__global__ void k_zero(float* __restrict__ out, u32* __restrict__ counters,
                       u32* __restrict__ sidecnt, u64* __restrict__ cand_key,
                       u32* __restrict__ hist1, u32* __restrict__ state_known,
                       u32* __restrict__ state_kneed) {
  int i = blockIdx.x * blockDim.x + threadIdx.x;
  if (i < NB * POSTN * 5) out[i] = 0.0f;
  if (i < NB * 4096) cand_key[i] = 0ull;
  if (i < 64 * 2048) hist1[i] = 0u;
  if (i < 64 * 16) { counters[i] = 0u; sidecnt[i] = 0u; }
  if (i < 64) { state_known[i] = 0u; state_kneed[i] = (u32)PREN; }
}

// ---------------- K1: top-11-bit histogram straight from cls -------------------
__global__ __launch_bounds__(1024) void k_hist1(
    const float* __restrict__ cls0, const float* __restrict__ cls1,
    const float* __restrict__ cls2, const float* __restrict__ cls3,
    u32* __restrict__ hist1) {
  int lvl, b, e0, nsl;
  slice_map(blockIdx.x, lvl, b, e0, nsl);
  const float* cls = (lvl == 0) ? cls0 : (lvl == 1) ? cls1 : (lvl == 2) ? cls2 : cls3;
  const float* cp = cls + (size_t)b * c_N[lvl];
  int tid = threadIdx.x;
  __shared__ u32 h[2048];
  for (int t = tid; t < 2048; t += 1024) h[t] = 0u;
  __syncthreads();
  for (int e = e0 + tid; e < e0 + nsl; e += 1024)
    atomicAdd(&h[ord_bits(cp[e]) >> 21], 1u);
  __syncthreads();
  int task = lvl * 16 + b;
  for (int t = tid; t < 2048; t += 1024) {
    u32 v = h[t];
    if (v) atomicAdd(&hist1[task * 2048 + t], v);
  }
}

// ---------------- K2: pick boundary bucket (suffix scan) -----------------------
__global__ __launch_bounds__(1024) void k_pick1(
    const u32* __restrict__ hist1, u32* __restrict__ state_known,
    u32* __restrict__ state_kneed) {
  int task = blockIdx.x;
  int tid = threadIdx.x;
  __shared__ u32 A[2048], Bb[2048];
  __shared__ int sh_t;
  __shared__ u32 sh_above;
  u32 kneed = (u32)PREN;
  for (int t = tid; t < 2048; t += 1024) A[t] = hist1[task * 2048 + t];
  __syncthreads();
  u32* cur = A;
  u32* nxt = Bb;
  for (int off2 = 1; off2 < 2048; off2 <<= 1) {
    for (int t = tid; t < 2048; t += 1024)
      nxt[t] = cur[t] + ((t + off2 < 2048) ? cur[t + off2] : 0u);
    __syncthreads();
    u32* tmp = cur; cur = nxt; nxt = tmp;
  }
  for (int t = tid; t < 2048; t += 1024) {
    u32 s = cur[t];
    u32 above = (t + 1 < 2048) ? cur[t + 1] : 0u;
    if (s >= kneed && above < kneed) { sh_t = t; sh_above = above; }
  }
  __syncthreads();
  if (tid == 0) {
    state_known[task] = (u32)sh_t << 21;
    state_kneed[task] = kneed - sh_above;   // how many to take from boundary
  }
}

// ---------------- K3: collect — block-local staging, 1 atomic per block --------
__global__ __launch_bounds__(1024) void k_collect(
    const float* __restrict__ cls0, const float* __restrict__ cls1,
    const float* __restrict__ cls2, const float* __restrict__ cls3,
    const u32* __restrict__ state_known,
    const float* __restrict__ reg0, const float* __restrict__ reg1,
    const float* __restrict__ reg2, const float* __restrict__ reg3,
    const float* __restrict__ anchors, u32* __restrict__ counters,
    u32* __restrict__ sidecnt, u64* __restrict__ sidebuf,
    u64* __restrict__ cand_key) {
  int lvl, b, e0, nsl;
  slice_map(blockIdx.x, lvl, b, e0, nsl);
  int task = lvl * 16 + b;
  u32 tb = state_known[task] >> 21;
  const float* cls = (lvl == 0) ? cls0 : (lvl == 1) ? cls1 : (lvl == 2) ? cls2 : cls3;
  const float* cp = cls + (size_t)b * c_N[lvl];
  int tid = threadIdx.x;
  __shared__ u32 ldef[1024];
  __shared__ u32 lside[BSIDE];
  __shared__ u32 cdef, cside, bdef, bside;
  if (tid == 0) { cdef = 0u; cside = 0u; }
  __syncthreads();
  for (int e = e0 + tid; e < e0 + nsl; e += 1024) {
    u32 bk = ord_bits(cp[e]) >> 21;
    if (bk < tb) continue;
    if (bk > tb) {
      u32 i = atomicAdd(&cdef, 1u);
      if (i < 1024u) ldef[i] = (u32)e;
    } else {
      u32 i = atomicAdd(&cside, 1u);
      if (i < (u32)BSIDE) lside[i] = (u32)e;
    }
  }
  __syncthreads();
  if (tid == 0) bdef = atomicAdd(&counters[task * 16], min(cdef, 1024u));
  if (tid == 1) bside = atomicAdd(&sidecnt[task * 16], min(cside, (u32)BSIDE));
  __syncthreads();
  int hw = c_HW[lvl], off = c_OFF[lvl];
  u32 nd = min(cdef, 1024u);
  for (u32 i = tid; i < nd; i += 1024) {
    int e = (int)ldef[i];
    int a = e / hw;
    int cell = e - a * hw;
    u32 gid = (u32)(off + cell * 3 + a);
    u64 key = ((u64)ord_bits(cp[e]) << 32) | (u32)(~gid);
    DecBox bx = decode_box(gid, b, reg0, reg1, reg2, reg3, anchors);
    u64 skey = bx.valid ? key : (key & 0xFFFFFFFFull);
    u32 slot = bdef + i;
    if (slot < (u32)PREN)
      cand_key[(size_t)b * 4096 + c_BASE[lvl] + slot] = skey;
  }
  u32 ns = min(cside, (u32)BSIDE);
  for (u32 i = tid; i < ns; i += 1024) {
    int e = (int)lside[i];
    int a = e / hw;
    int cell = e - a * hw;
    u32 gid = (u32)(off + cell * 3 + a);
    u64 key = ((u64)ord_bits(cp[e]) << 32) | (u32)(~gid);
    u32 slot = bside + i;
    if (slot < (u32)SIDECAP) sidebuf[(size_t)task * SIDECAP + slot] = key;
  }
}

// ---------------- K4: finalize — sort boundary bucket, append kneed ------------
__global__ __launch_bounds__(1024) void k_finalize(
    const u64* __restrict__ sidebuf, const u32* __restrict__ sidecnt,
    const u32* __restrict__ counters, const u32* __restrict__ state_kneed,
    const float* __restrict__ reg0, const float* __restrict__ reg1,
    const float* __restrict__ reg2, const float* __restrict__ reg3,
    const float* __restrict__ anchors, u64* __restrict__ cand_key) {
  int task = blockIdx.x;
  int lvl = task >> 4;
  int b = task & 15;
  int tid = threadIdx.x;
  u32 nside = min(sidecnt[task * 16], (u32)SIDECAP);
  u32 kneed = state_kneed[task];
  u32 nab = counters[task * 16];
  __shared__ u64 sk[SIDECAP];
  for (int i = tid; i < SIDECAP; i += 1024)
    sk[i] = (i < (int)nside) ? sidebuf[(size_t)task * SIDECAP + i] : 0ull;
  __syncthreads();
  for (u32 k = 2; k <= SIDECAP; k <<= 1) {
    for (u32 j = k >> 1; j > 0; j >>= 1) {
      for (u32 t = tid; t < SIDECAP / 2; t += 1024) {
        u32 i = 2u * t - (t & (j - 1u));
        u32 l2 = i | j;
        u64 av = sk[i], bv = sk[l2];
        bool up = ((i & k) == 0u);
        if (up ? (av < bv) : (av > bv)) { sk[i] = bv; sk[l2] = av; }
      }
      __syncthreads();
    }
  }
  if (tid < (int)kneed) {
    u64 key = sk[tid];
    u32 gid = ~((u32)key);
    DecBox bx = decode_box(gid, b, reg0, reg1, reg2, reg3, anchors);
    u64 skey = bx.valid ? key : (key & 0xFFFFFFFFull);
    u32 slot = nab + (u32)tid;
    if (slot < (u32)PREN)
      cand_key[(size_t)b * 4096 + c_BASE[lvl] + slot] = skey;
  }
}

// ---------------- K sortl: per-(image,level) bitonic sort (desc) of 1024 -------
__global__ __launch_bounds__(512) void k_sortl(u64* __restrict__ cand_key) {
  int bl = blockIdx.x;                 // b*4 + lvl
  int tid = threadIdx.x;
  __shared__ u64 sk[LSEG];
  sk[tid] = cand_key[(size_t)bl * LSEG + tid];
  sk[tid + 512] = cand_key[(size_t)bl * LSEG + tid + 512];
  __syncthreads();
  for (u32 k = 2; k <= LSEG; k <<= 1) {
    for (u32 j = k >> 1; j > 0; j >>= 1) {
      u32 i = 2u * tid - (tid & (j - 1u));
      u32 l2 = i | j;
      u64 av = sk[i], bv = sk[l2];
      bool up = ((i & k) == 0u);
      if (up ? (av < bv) : (av > bv)) { sk[i] = bv; sk[l2] = av; }
      __syncthreads();
    }
  }
  cand_key[(size_t)bl * LSEG + tid] = sk[tid];
  cand_key[(size_t)bl * LSEG + tid + 512] = sk[tid + 512];
}

// ---------------- K decodel: payloads for sorted per-level candidates ----------
__global__ __launch_bounds__(1024) void k_decodel(
    const u64* __restrict__ cand_key,
    const float* __restrict__ reg0, const float* __restrict__ reg1,
    const float* __restrict__ reg2, const float* __restrict__ reg3,
    const float* __restrict__ anchors,
    float4* __restrict__ sbox, float4* __restrict__ boffA,
    float* __restrict__ area, float* __restrict__ score,
    u64* __restrict__ vmaskl) {
  int bl = blockIdx.x;
  int b = bl >> 2;
  int p = threadIdx.x;
  u64 key = cand_key[(size_t)bl * LSEG + p];
  float4 bx4 = make_float4(0.f, 0.f, 0.f, 0.f);
  float4 bo4 = make_float4(0.f, 0.f, 0.f, 0.f);
  float ar = 0.f, sc = 0.f;
  bool vflag = false;
  if (key != 0ull) {
    u32 gid = ~((u32)key);
    vflag = (key >> 32) != 0ull;
    DecBox bx = decode_box(gid, b, reg0, reg1, reg2, reg3, anchors);
    bx4 = make_float4(bx.x1, bx.y1, bx.x2, bx.y2);
    float offv = __fmul_rn((float)bx.lvl, 801.0f);
    bo4 = make_float4(__fadd_rn(bx.x1, offv), __fadd_rn(bx.y1, offv),
                      __fadd_rn(bx.x2, offv), __fadd_rn(bx.y2, offv));
    ar = __fmul_rn(__fsub_rn(bo4.z, bo4.x), __fsub_rn(bo4.w, bo4.y));
    if (vflag) {
      float logit = inv_ord((u32)(key >> 32));
      sc = 1.0f / (1.0f + expf(-logit));
    }
  }
  size_t gi = (size_t)bl * LSEG + p;
  sbox[gi] = bx4;
  boffA[gi] = bo4;
  area[gi] = ar;
  score[gi] = sc;
  u64 bal = __ballot(vflag ? 1 : 0);
  if ((p & 63) == 0) vmaskl[bl * LCH + (p >> 6)] = bal;
}

// ---------------- K maskl: per-level IoU bitmask (16 words/row) ----------------
#define RPB 16
__global__ __launch_bounds__(256) void k_maskl(
    const float4* __restrict__ boffA, const float* __restrict__ area,
    u64* __restrict__ maskl, u32* __restrict__ rnzl) {
  int bg = blockIdx.x;
  int bl = bg >> 6;                 // (b*4+lvl)
  int g = bg & 63;                  // row-group within level
  int row0 = g * RPB;
  int tid = threadIdx.x;
  int wave = tid >> 6;
  int lane = tid & 63;
  __shared__ float4 rb[RPB];
  __shared__ float ra[RPB];
  __shared__ u32 rnzs[RPB];
  if (tid < RPB) {
    rb[tid] = boffA[(size_t)bl * LSEG + row0 + tid];
    ra[tid] = area[(size_t)bl * LSEG + row0 + tid];
    rnzs[tid] = 0u;
  }
  __syncthreads();
  u64* M = maskl + (size_t)bl * LSEG * LCH;
  for (int chunk = 0; chunk < 4; ++chunk) {
    int wword = chunk * 4 + wave;
    int wmaxj = chunk * 256 + wave * 64 + 63;   // this wave's max column
    if (wmaxj <= row0) {
      if (lane == 0) {
#pragma unroll
        for (int rr = 0; rr < RPB; ++rr)
          M[(size_t)(row0 + rr) * LCH + wword] = 0ull;
      }
      continue;
    }
    int j = chunk * 256 + tid;
    float4 cb = boffA[(size_t)bl * LSEG + j];
    float ca = area[(size_t)bl * LSEG + j];
#pragma unroll
    for (int rr = 0; rr < RPB; ++rr) {
      int i = row0 + rr;
      if (wmaxj <= i) {
        if (lane == 0) M[(size_t)i * LCH + wword] = 0ull;
        continue;
      }
      float4 rbb = rb[rr];
      float ria = ra[rr];
      float ix1 = fmaxf(cb.x, rbb.x);
      float iy1 = fmaxf(cb.y, rbb.y);
      float ix2 = fminf(cb.z, rbb.z);
      float iy2 = fminf(cb.w, rbb.w);
      float inter = __fmul_rn(fmaxf(__fsub_rn(ix2, ix1), 0.0f),
                              fmaxf(__fsub_rn(iy2, iy1), 0.0f));
      float uni = __fsub_rn(__fadd_rn(ca, ria), inter);
      float iou = __fdiv_rn(inter, (uni > 0.0f) ? uni : 1.0f);
      bool pred = (j > i) && (iou > 0.7f);
      u64 bal = __ballot(pred ? 1 : 0);
      if (lane == 0) {
        M[(size_t)i * LCH + wword] = bal;
        if (bal) atomicOr(&rnzs[rr], 1u << wword);
      }
    }
  }
  __syncthreads();
  if (tid < RPB) rnzl[(size_t)bl * LSEG + row0 + tid] = rnzs[tid];
}

// ---------------- K nmsl: per-(image,level) greedy NMS + kept compaction -------
__global__ __launch_bounds__(64) void k_nmsl(
    const u64* __restrict__ maskl, const u32* __restrict__ rnzl,
    const u64* __restrict__ vmaskl, const u64* __restrict__ cand_key,
    u64* __restrict__ keptkeys, u32* __restrict__ keptpos,
    u32* __restrict__ keptcnt) {
  int bl = blockIdx.x;
  int lane = threadIdx.x;
  const u64* M = maskl + (size_t)bl * LSEG * LCH;
  const u32* RZ = rnzl + (size_t)bl * LSEG;
  u64 supp = 0ull;   // lane w<16 holds suppression word w
  u64 keep = 0ull;   // lane w<16 holds keep word w
  u64 vword = (lane < LCH) ? vmaskl[bl * LCH + lane] : 0ull;
  u64 dch = M[(size_t)lane * LCH + 0];
  u32 rnz = RZ[lane];
  for (int W = 0; W < LCH; ++W) {
    int c0 = W << 6;
    u64 s = __shfl(supp, W);
    u64 v = __shfl(vword, W);
    u64 dnext = 0ull; u32 rnext = 0u;
    if (W + 1 < LCH) {
      int row = c0 + 64 + lane;
      dnext = M[(size_t)row * LCH + (W + 1)];
      rnext = RZ[row];
    }
    // greedy resolve: scalar readlane over suppressor rows only
    u64 pending = v & ~s;
    u64 kw = 0ull;
    u64 suppressors = __ballot((dch & pending) != 0ull) & pending;
    while (pending) {
      u64 sp = pending & suppressors;
      if (!sp) { kw |= pending; break; }
      int q = __builtin_ctzll(sp);
      u64 below = pending & ((1ull << q) - 1ull);
      kw |= below | (1ull << q);
      u64 supq = readlane_u64(dch, q);
      pending &= ~supq;
      pending &= ~below;
      pending &= ~(1ull << q);
    }
    // sparse apply: only kept rows with a nonzero word beyond W
    u64 kwload = __ballot(((rnz >> W) >> 1) != 0u) & kw;
    u64 kk = kwload;
    bool ld = (lane > W) && (lane < LCH);
    while (kk) {
      int q0 = __builtin_ctzll(kk);
      kk &= kk - 1ull;
      u64 m0 = ld ? M[(size_t)(c0 + q0) * LCH + lane] : 0ull;
      if (kk) {
        int q1 = __builtin_ctzll(kk);
        kk &= kk - 1ull;
        u64 m1 = ld ? M[(size_t)(c0 + q1) * LCH + lane] : 0ull;
        m0 |= m1;
      }
      supp |= m0;
    }
    if (lane == W) keep = kw;
    dch = dnext;
    rnz = rnext;
  }
  // compact kept: prefix popcount across lanes
  int pc = __popcll(keep);
  int incl = pc;
  for (int d = 1; d < 64; d <<= 1) {
    int t = __shfl_up(incl, d);
    if (lane >= d) incl += t;
  }
  int r = incl - pc;
  u64 kk = keep;
  while (kk) {
    int bit = __builtin_ctzll(kk);
    kk &= kk - 1ull;
    int p = lane * 64 + bit;
    keptkeys[(size_t)bl * LSEG + r] = cand_key[(size_t)bl * LSEG + p];
    keptpos[(size_t)bl * LSEG + r] = (u32)p;
    ++r;
  }
  if (lane == 63) keptcnt[bl] = (u32)incl;
}

// ---------------- K out: global rank via cross-level binary search -------------
__global__ __launch_bounds__(1024) void k_out(
    const u64* __restrict__ keptkeys, const u32* __restrict__ keptpos,
    const u32* __restrict__ keptcnt, const float4* __restrict__ sbox,
    const float* __restrict__ score, float* __restrict__ out) {
  int bl = blockIdx.x;
  int b = bl >> 2;
  int l = bl & 3;
  int r = threadIdx.x;
  u32 cnt = keptcnt[bl];
  if (r >= (int)cnt) return;
  u64 K = keptkeys[(size_t)bl * LSEG + r];
  int rank = r;
#pragma unroll
  for (int dl = 0; dl < 4; ++dl) {
    if (dl == l) continue;
    int obl = (b << 2) | dl;
    const u64* arr = keptkeys + (size_t)obl * LSEG;
    int lo = 0, hi = (int)keptcnt[obl];
    while (lo < hi) {
      int mid = (lo + hi) >> 1;
      if (arr[mid] > K) lo = mid + 1; else hi = mid;
    }
    rank += lo;
  }
  if (rank < POSTN) {
    u32 p = keptpos[(size_t)bl * LSEG + r];
    float4 bx = sbox[(size_t)bl * LSEG + p];
    size_t ob = ((size_t)b * POSTN + (size_t)rank) * 4;
    out[ob + 0] = bx.x;
    out[ob + 1] = bx.y;
    out[ob + 2] = bx.z;
    out[ob + 3] = bx.w;
    out[(size_t)NB * POSTN * 4 + (size_t)b * POSTN + (size_t)rank] =
        score[(size_t)bl * LSEG + p];
  }
}

extern "C" void kernel_launch(void* const* d_in, const int* in_sizes, int n_in,
                              void* d_out, int out_size, void* d_ws, size_t ws_size,
                              hipStream_t stream) {
  // setup_inputs dict order: cls0, reg0, cls1, reg1, cls2, reg2, cls3, reg3, anchors
  const float* cls0 = (const float*)d_in[0];
  const float* reg0 = (const float*)d_in[1];
  const float* cls1 = (const float*)d_in[2];
  const float* reg1 = (const float*)d_in[3];
  const float* cls2 = (const float*)d_in[4];
  const float* reg2 = (const float*)d_in[5];
  const float* cls3 = (const float*)d_in[6];
  const float* reg3 = (const float*)d_in[7];
  const float* anchors = (const float*)d_in[8];
  float* out = (float*)d_out;

  char* ws = (char*)d_ws;
  size_t off = 0;
  auto take = [&](size_t bytes) -> void* {
    off = (off + 255) & ~(size_t)255;
    void* p = ws + off;
    off += bytes;
    return p;
  };
  u64* maskl     = (u64*)take((size_t)64 * LSEG * LCH * 8);  // 8.4 MB
  u64* sidebuf   = (u64*)take((size_t)64 * SIDECAP * 8);     // 2 MB
  u32* rnzl      = (u32*)take((size_t)64 * LSEG * 4);        // 256 KB
  u64* cand_key  = (u64*)take((size_t)NB * 4096 * 8);        // 512 KB
  float4* sbox   = (float4*)take((size_t)64 * LSEG * 16);    // 1 MB
  float4* boffA  = (float4*)take((size_t)64 * LSEG * 16);    // 1 MB
  float* area    = (float*)take((size_t)64 * LSEG * 4);
  float* score   = (float*)take((size_t)64 * LSEG * 4);
  u64* vmaskl    = (u64*)take((size_t)64 * LCH * 8);
  u64* keptkeys  = (u64*)take((size_t)64 * LSEG * 8);        // 512 KB
  u32* keptpos   = (u32*)take((size_t)64 * LSEG * 4);        // 256 KB
  u32* keptcnt   = (u32*)take((size_t)64 * 4);
  u32* hist1     = (u32*)take((size_t)64 * 2048 * 4);
  u32* counters  = (u32*)take((size_t)64 * 16 * 4);          // 64B-padded
  u32* sidecnt   = (u32*)take((size_t)64 * 16 * 4);          // 64B-padded
  u32* state_known = (u32*)take((size_t)64 * 4);
  u32* state_kneed = (u32*)take((size_t)64 * 4);
  (void)ws_size; (void)in_sizes; (void)n_in; (void)out_size;

  k_zero<<<512, 256, 0, stream>>>(out, counters, sidecnt, cand_key, hist1,
                                  state_known, state_kneed);
  k_hist1<<<192, 1024, 0, stream>>>(cls0, cls1, cls2, cls3, hist1);
  k_pick1<<<64, 1024, 0, stream>>>(hist1, state_known, state_kneed);
  k_collect<<<192, 1024, 0, stream>>>(cls0, cls1, cls2, cls3, state_known,
                                      reg0, reg1, reg2, reg3, anchors,
                                      counters, sidecnt, sidebuf, cand_key);
  k_finalize<<<64, 1024, 0, stream>>>(sidebuf, sidecnt, counters, state_kneed,
                                      reg0, reg1, reg2, reg3, anchors,
                                      cand_key);
  k_sortl<<<64, 512, 0, stream>>>(cand_key);
  k_decodel<<<64, 1024, 0, stream>>>(cand_key, reg0, reg1, reg2, reg3,
                                     anchors, sbox, boffA, area, score,
                                     vmaskl);
  k_maskl<<<64 * 64, 256, 0, stream>>>(boffA, area, maskl, rnzl);
  k_nmsl<<<64, 64, 0, stream>>>(maskl, rnzl, vmaskl, cand_key, keptkeys,
                                keptpos, keptcnt);
  k_out<<<64, 1024, 0, stream>>>(keptkeys, keptpos, keptcnt, sbox, score, out);
}

// Round 9
// 180.741 us; speedup vs baseline: 8.4485x; 1.0251x over previous
//
#include <hip/hip_runtime.h>
#include <cstdint>
#include <cstddef>

typedef uint32_t u32;
typedef uint64_t u64;

#define NB 16
#define POSTN 1000
#define PREN 1000
#define LSEG 1024     // per-level segment (1000 candidates + 24 pad)
#define LCH 16        // chunks of 64 per level
#define SIDECAP 4096  // per-task boundary-bucket buffer
#define BSIDE 2048    // per-block LDS side list

__constant__ int c_N[4]    = {120000, 30000, 7500, 1875};
__constant__ int c_OFF[4]  = {0, 120000, 150000, 157500};
__constant__ int c_HW[4]   = {40000, 10000, 2500, 625};
__constant__ int c_W[4]    = {200, 100, 50, 25};
__constant__ int c_BASE[4] = {0, 1024, 2048, 3072};

__device__ __forceinline__ u32 ord_bits(float f) {
  u32 u = __float_as_uint(f);
  return (u & 0x80000000u) ? ~u : (u | 0x80000000u);
}
__device__ __forceinline__ float inv_ord(u32 o) {
  u32 bits = (o & 0x80000000u) ? (o ^ 0x80000000u) : ~o;
  return __uint_as_float(bits);
}
__device__ __forceinline__ u64 readlane_u64(u64 v, int l) {
  u32 lo = (u32)__builtin_amdgcn_readlane((int)(u32)v, l);
  u32 hi = (u32)__builtin_amdgcn_readlane((int)(u32)(v >> 32), l);
  return (((u64)hi) << 32) | (u64)lo;
}

// 192-block slice map: 8 blocks/task lvl0, 2/task lvl1, 1/task lvl2+3
__device__ __forceinline__ void slice_map(int bid, int& lvl, int& b, int& e0,
                                          int& nsl) {
  if (bid < 128)      { lvl = 0; b = bid >> 3; e0 = (bid & 7) * 15000; nsl = 15000; }
  else if (bid < 160) { lvl = 1; int t = bid - 128; b = t >> 1; e0 = (t & 1) * 15000; nsl = 15000; }
  else if (bid < 176) { lvl = 2; b = bid - 160; e0 = 0; nsl = 7500; }
  else                { lvl = 3; b = bid - 176; e0 = 0; nsl = 1875; }
}

struct DecBox { float x1, y1, x2, y2; int lvl; bool valid; };

__device__ DecBox decode_box(u32 gid, int b,
    const float* __restrict__ reg0, const float* __restrict__ reg1,
    const float* __restrict__ reg2, const float* __restrict__ reg3,
    const float* __restrict__ anchors) {
  int lvl = (gid < 120000u) ? 0 : (gid < 150000u) ? 1 : (gid < 157500u) ? 2 : 3;
  int local = (int)gid - c_OFF[lvl];
  int a = local % 3;
  int cell = local / 3;
  int w = c_W[lvl];
  int hw = c_HW[lvl];
  int y = cell / w;
  int x = cell - y * w;
  const float* reg = (lvl == 0) ? reg0 : (lvl == 1) ? reg1 : (lvl == 2) ? reg2 : reg3;
  size_t base = ((size_t)(b * 12 + a * 4) * (size_t)w + (size_t)y) * (size_t)w + (size_t)x;
  const float CLIPV = 4.135166556742356f; // log(1000/16) as f32
  float dx = reg[base];
  float dy = reg[base + (size_t)hw];
  float dwv = fminf(reg[base + 2 * (size_t)hw], CLIPV);
  float dhv = fminf(reg[base + 3 * (size_t)hw], CLIPV);
  float a0 = anchors[(size_t)gid * 4 + 0];
  float a1 = anchors[(size_t)gid * 4 + 1];
  float a2 = anchors[(size_t)gid * 4 + 2];
  float a3 = anchors[(size_t)gid * 4 + 3];
  float wa = __fsub_rn(a2, a0);
  float ha = __fsub_rn(a3, a1);
  float cxa = __fadd_rn(a0, __fmul_rn(0.5f, wa));
  float cya = __fadd_rn(a1, __fmul_rn(0.5f, ha));
  float pcx = __fadd_rn(__fmul_rn(dx, wa), cxa);
  float pcy = __fadd_rn(__fmul_rn(dy, ha), cya);
  float pw = __fmul_rn(expf(dwv), wa);
  float ph = __fmul_rn(expf(dhv), ha);
  float x1 = __fsub_rn(pcx, __fmul_rn(0.5f, pw));
  float y1 = __fsub_rn(pcy, __fmul_rn(0.5f, ph));
  float x2 = __fadd_rn(pcx, __fmul_rn(0.5f, pw));
  float y2 = __fadd_rn(pcy, __fmul_rn(0.5f, ph));
  x1 = fminf(fmaxf(x1, 0.0f), 800.0f);
  y1 = fminf(fmaxf(y1, 0.0f), 800.0f);
  x2 = fminf(fmaxf(x2, 0.0f), 800.0f);
  y2 = fminf(fmaxf(y2, 0.0f), 800.0f);
  DecBox r;
  r.x1 = x1; r.y1 = y1; r.x2 = x2; r.y2 = y2; r.lvl = lvl;
  r.valid = (__fsub_rn(x2, x1) >= 1.0f) && (__fsub_rn(y2, y1) >= 1.0f);
  return r;
}

// ---------------- K0: zero state ----------------------------------------------
__global__ void k_zero(float* __restrict__ out, u32* __restrict__ counters,
                       u32* __restrict__ sidecnt, u64* __restrict__ cand_key,
                       u32* __restrict__ hist1, u32* __restrict__ state_known,
                       u32* __restrict__ state_kneed) {
  int i = blockIdx.x * blockDim.x + threadIdx.x;
  if (i < NB * POSTN * 5) out[i] = 0.0f;
  if (i < NB * 4096) cand_key[i] = 0ull;
  if (i < 64 * 2048) hist1[i] = 0u;
  if (i < 64 * 16) { counters[i] = 0u; sidecnt[i] = 0u; }
  if (i < 64) { state_known[i] = 0u; state_kneed[i] = (u32)PREN; }
}

// ---------------- K1: top-11-bit histogram straight from cls -------------------
__global__ __launch_bounds__(1024) void k_hist1(
    const float* __restrict__ cls0, const float* __restrict__ cls1,
    const float* __restrict__ cls2, const float* __restrict__ cls3,
    u32* __restrict__ hist1) {
  int lvl, b, e0, nsl;
  slice_map(blockIdx.x, lvl, b, e0, nsl);
  const float* cls = (lvl == 0) ? cls0 : (lvl == 1) ? cls1 : (lvl == 2) ? cls2 : cls3;
  const float* cp = cls + (size_t)b * c_N[lvl];
  int tid = threadIdx.x;
  __shared__ u32 h[2048];
  for (int t = tid; t < 2048; t += 1024) h[t] = 0u;
  __syncthreads();
  for (int e = e0 + tid; e < e0 + nsl; e += 1024)
    atomicAdd(&h[ord_bits(cp[e]) >> 21], 1u);
  __syncthreads();
  int task = lvl * 16 + b;
  for (int t = tid; t < 2048; t += 1024) {
    u32 v = h[t];
    if (v) atomicAdd(&hist1[task * 2048 + t], v);
  }
}

// ---------------- K2: pick boundary bucket (suffix scan) -----------------------
__global__ __launch_bounds__(1024) void k_pick1(
    const u32* __restrict__ hist1, u32* __restrict__ state_known,
    u32* __restrict__ state_kneed) {
  int task = blockIdx.x;
  int tid = threadIdx.x;
  __shared__ u32 A[2048], Bb[2048];
  __shared__ int sh_t;
  __shared__ u32 sh_above;
  u32 kneed = (u32)PREN;
  for (int t = tid; t < 2048; t += 1024) A[t] = hist1[task * 2048 + t];
  __syncthreads();
  u32* cur = A;
  u32* nxt = Bb;
  for (int off2 = 1; off2 < 2048; off2 <<= 1) {
    for (int t = tid; t < 2048; t += 1024)
      nxt[t] = cur[t] + ((t + off2 < 2048) ? cur[t + off2] : 0u);
    __syncthreads();
    u32* tmp = cur; cur = nxt; nxt = tmp;
  }
  for (int t = tid; t < 2048; t += 1024) {
    u32 s = cur[t];
    u32 above = (t + 1 < 2048) ? cur[t + 1] : 0u;
    if (s >= kneed && above < kneed) { sh_t = t; sh_above = above; }
  }
  __syncthreads();
  if (tid == 0) {
    state_known[task] = (u32)sh_t << 21;
    state_kneed[task] = kneed - sh_above;   // how many to take from boundary
  }
}

// ---------------- K3: collect — block-local staging, 1 atomic per block --------
__global__ __launch_bounds__(1024) void k_collect(
    const float* __restrict__ cls0, const float* __restrict__ cls1,
    const float* __restrict__ cls2, const float* __restrict__ cls3,
    const u32* __restrict__ state_known,
    const float* __restrict__ reg0, const float* __restrict__ reg1,
    const float* __restrict__ reg2, const float* __restrict__ reg3,
    const float* __restrict__ anchors, u32* __restrict__ counters,
    u32* __restrict__ sidecnt, u64* __restrict__ sidebuf,
    u64* __restrict__ cand_key) {
  int lvl, b, e0, nsl;
  slice_map(blockIdx.x, lvl, b, e0, nsl);
  int task = lvl * 16 + b;
  u32 tb = state_known[task] >> 21;
  const float* cls = (lvl == 0) ? cls0 : (lvl == 1) ? cls1 : (lvl == 2) ? cls2 : cls3;
  const float* cp = cls + (size_t)b * c_N[lvl];
  int tid = threadIdx.x;
  __shared__ u32 ldef[1024];
  __shared__ u32 lside[BSIDE];
  __shared__ u32 cdef, cside, bdef, bside;
  if (tid == 0) { cdef = 0u; cside = 0u; }
  __syncthreads();
  for (int e = e0 + tid; e < e0 + nsl; e += 1024) {
    u32 bk = ord_bits(cp[e]) >> 21;
    if (bk < tb) continue;
    if (bk > tb) {
      u32 i = atomicAdd(&cdef, 1u);
      if (i < 1024u) ldef[i] = (u32)e;
    } else {
      u32 i = atomicAdd(&cside, 1u);
      if (i < (u32)BSIDE) lside[i] = (u32)e;
    }
  }
  __syncthreads();
  if (tid == 0) bdef = atomicAdd(&counters[task * 16], min(cdef, 1024u));
  if (tid == 1) bside = atomicAdd(&sidecnt[task * 16], min(cside, (u32)BSIDE));
  __syncthreads();
  int hw = c_HW[lvl], off = c_OFF[lvl];
  u32 nd = min(cdef, 1024u);
  for (u32 i = tid; i < nd; i += 1024) {
    int e = (int)ldef[i];
    int a = e / hw;
    int cell = e - a * hw;
    u32 gid = (u32)(off + cell * 3 + a);
    u64 key = ((u64)ord_bits(cp[e]) << 32) | (u32)(~gid);
    DecBox bx = decode_box(gid, b, reg0, reg1, reg2, reg3, anchors);
    u64 skey = bx.valid ? key : (key & 0xFFFFFFFFull);
    u32 slot = bdef + i;
    if (slot < (u32)PREN)
      cand_key[(size_t)b * 4096 + c_BASE[lvl] + slot] = skey;
  }
  u32 ns = min(cside, (u32)BSIDE);
  for (u32 i = tid; i < ns; i += 1024) {
    int e = (int)lside[i];
    int a = e / hw;
    int cell = e - a * hw;
    u32 gid = (u32)(off + cell * 3 + a);
    u64 key = ((u64)ord_bits(cp[e]) << 32) | (u32)(~gid);
    u32 slot = bside + i;
    if (slot < (u32)SIDECAP) sidebuf[(size_t)task * SIDECAP + slot] = key;
  }
}

// ---------------- K4: finalize — sort boundary bucket (np2), append kneed ------
__global__ __launch_bounds__(1024) void k_finalize(
    const u64* __restrict__ sidebuf, const u32* __restrict__ sidecnt,
    const u32* __restrict__ counters, const u32* __restrict__ state_kneed,
    const float* __restrict__ reg0, const float* __restrict__ reg1,
    const float* __restrict__ reg2, const float* __restrict__ reg3,
    const float* __restrict__ anchors, u64* __restrict__ cand_key) {
  int task = blockIdx.x;
  int lvl = task >> 4;
  int b = task & 15;
  int tid = threadIdx.x;
  u32 nside = min(sidecnt[task * 16], (u32)SIDECAP);
  u32 kneed = state_kneed[task];
  u32 nab = counters[task * 16];
  u32 np2 = 64;
  while (np2 < nside) np2 <<= 1;   // next pow2 >= nside (uniform)
  __shared__ u64 sk[SIDECAP];
  for (u32 i = tid; i < np2; i += 1024)
    sk[i] = (i < nside) ? sidebuf[(size_t)task * SIDECAP + i] : 0ull;
  __syncthreads();
  for (u32 k = 2; k <= np2; k <<= 1) {
    for (u32 j = k >> 1; j > 0; j >>= 1) {
      for (u32 t = tid; t < np2 / 2; t += 1024) {
        u32 i = 2u * t - (t & (j - 1u));
        u32 l2 = i | j;
        u64 av = sk[i], bv = sk[l2];
        bool up = ((i & k) == 0u);
        if (up ? (av < bv) : (av > bv)) { sk[i] = bv; sk[l2] = av; }
      }
      __syncthreads();
    }
  }
  if (tid < (int)kneed) {
    u64 key = sk[tid];
    u32 gid = ~((u32)key);
    DecBox bx = decode_box(gid, b, reg0, reg1, reg2, reg3, anchors);
    u64 skey = bx.valid ? key : (key & 0xFFFFFFFFull);
    u32 slot = nab + (u32)tid;
    if (slot < (u32)PREN)
      cand_key[(size_t)b * 4096 + c_BASE[lvl] + slot] = skey;
  }
}

// ---------------- K sortdec: fused per-(image,level) sort + decode -------------
__global__ __launch_bounds__(1024) void k_sortdec(
    u64* __restrict__ cand_key,
    const float* __restrict__ reg0, const float* __restrict__ reg1,
    const float* __restrict__ reg2, const float* __restrict__ reg3,
    const float* __restrict__ anchors,
    float4* __restrict__ sbox, float4* __restrict__ boffA,
    float* __restrict__ area, float* __restrict__ score,
    u64* __restrict__ vmaskl) {
  int bl = blockIdx.x;                 // b*4 + lvl
  int b = bl >> 2;
  int tid = threadIdx.x;
  __shared__ u64 sk[LSEG];
  sk[tid] = cand_key[(size_t)bl * LSEG + tid];
  __syncthreads();
  for (u32 k = 2; k <= LSEG; k <<= 1) {
    for (u32 j = k >> 1; j > 0; j >>= 1) {
      if (tid < LSEG / 2) {
        u32 t = (u32)tid;
        u32 i = 2u * t - (t & (j - 1u));
        u32 l2 = i | j;
        u64 av = sk[i], bv = sk[l2];
        bool up = ((i & k) == 0u);
        if (up ? (av < bv) : (av > bv)) { sk[i] = bv; sk[l2] = av; }
      }
      __syncthreads();
    }
  }
  // write back sorted keys (k_nmsl reads them for kept compaction)
  u64 key = sk[tid];
  cand_key[(size_t)bl * LSEG + tid] = key;
  // decode payloads
  float4 bx4 = make_float4(0.f, 0.f, 0.f, 0.f);
  float4 bo4 = make_float4(0.f, 0.f, 0.f, 0.f);
  float ar = 0.f, sc = 0.f;
  bool vflag = false;
  if (key != 0ull) {
    u32 gid = ~((u32)key);
    vflag = (key >> 32) != 0ull;
    DecBox bx = decode_box(gid, b, reg0, reg1, reg2, reg3, anchors);
    bx4 = make_float4(bx.x1, bx.y1, bx.x2, bx.y2);
    float offv = __fmul_rn((float)bx.lvl, 801.0f);
    bo4 = make_float4(__fadd_rn(bx.x1, offv), __fadd_rn(bx.y1, offv),
                      __fadd_rn(bx.x2, offv), __fadd_rn(bx.y2, offv));
    ar = __fmul_rn(__fsub_rn(bo4.z, bo4.x), __fsub_rn(bo4.w, bo4.y));
    if (vflag) {
      float logit = inv_ord((u32)(key >> 32));
      sc = 1.0f / (1.0f + expf(-logit));
    }
  }
  size_t gi = (size_t)bl * LSEG + tid;
  sbox[gi] = bx4;
  boffA[gi] = bo4;
  area[gi] = ar;
  score[gi] = sc;
  u64 bal = __ballot(vflag ? 1 : 0);
  if ((tid & 63) == 0) vmaskl[bl * LCH + (tid >> 6)] = bal;
}

// ---------------- K maskl: sparse IoU bitmask — exact div-free test ------------
// RN(inter/uni) > 0.7f  <=>  inter/uni >= B, B = 0.7f + 2^-25 (tie rounds up).
// B*(double)uni is exact (25x24 bits <= 53); comparison is bit-equivalent.
#define RPB 16
__global__ __launch_bounds__(256) void k_maskl(
    const float4* __restrict__ boffA, const float* __restrict__ area,
    u64* __restrict__ maskl, u32* __restrict__ rnzl) {
  const double Bd = 0x1.6666661p-1;   // 0.7000000178813934326171875
  int bg = blockIdx.x;
  int bl = bg >> 6;                 // (b*4+lvl)
  int g = bg & 63;                  // row-group within level
  int row0 = g * RPB;
  int tid = threadIdx.x;
  int wave = tid >> 6;
  int lane = tid & 63;
  __shared__ float4 rb[RPB];
  __shared__ float ra[RPB];
  __shared__ u32 rnzs[RPB];
  if (tid < RPB) {
    rb[tid] = boffA[(size_t)bl * LSEG + row0 + tid];
    ra[tid] = area[(size_t)bl * LSEG + row0 + tid];
    rnzs[tid] = 0u;
  }
  __syncthreads();
  u64* M = maskl + (size_t)bl * LSEG * LCH;
  for (int chunk = 0; chunk < 4; ++chunk) {
    int wword = chunk * 4 + wave;
    int wmaxj = chunk * 256 + wave * 64 + 63;   // this wave's max column
    if (wmaxj <= row0) continue;                // below diagonal: nothing
    int j = chunk * 256 + tid;
    float4 cb = boffA[(size_t)bl * LSEG + j];
    float ca = area[(size_t)bl * LSEG + j];
#pragma unroll
    for (int rr = 0; rr < RPB; ++rr) {
      int i = row0 + rr;
      if (wmaxj <= i) continue;
      float4 rbb = rb[rr];
      float ria = ra[rr];
      float ix1 = fmaxf(cb.x, rbb.x);
      float iy1 = fmaxf(cb.y, rbb.y);
      float ix2 = fminf(cb.z, rbb.z);
      float iy2 = fminf(cb.w, rbb.w);
      float inter = __fmul_rn(fmaxf(__fsub_rn(ix2, ix1), 0.0f),
                              fmaxf(__fsub_rn(iy2, iy1), 0.0f));
      float uni = __fsub_rn(__fadd_rn(ca, ria), inter);
      bool pred = (j > i) && (inter > 0.0f) &&
                  ((double)inter >= Bd * (double)uni);
      u64 bal = __ballot(pred ? 1 : 0);
      if (lane == 0 && bal) {           // write ONLY nonzero words
        M[(size_t)i * LCH + wword] = bal;
        atomicOr(&rnzs[rr], 1u << wword);
      }
    }
  }
  __syncthreads();
  if (tid < RPB) rnzl[(size_t)bl * LSEG + row0 + tid] = rnzs[tid];
}

// ---------------- K nmsl: greedy NMS — all mask reads gated by rnz -------------
__global__ __launch_bounds__(64) void k_nmsl(
    const u64* __restrict__ maskl, const u32* __restrict__ rnzl,
    const u64* __restrict__ vmaskl, const u64* __restrict__ cand_key,
    u64* __restrict__ keptkeys, u32* __restrict__ keptpos,
    u32* __restrict__ keptcnt) {
  int bl = blockIdx.x;
  int lane = threadIdx.x;
  const u64* M = maskl + (size_t)bl * LSEG * LCH;
  const u32* RZ = rnzl + (size_t)bl * LSEG;
  u64 supp = 0ull;   // lane w<16 holds suppression word w
  u64 keep = 0ull;   // lane w<16 holds keep word w
  u64 vword = (lane < LCH) ? vmaskl[bl * LCH + lane] : 0ull;
  u32 rnz = RZ[lane];
  u64 dch = (rnz & 1u) ? M[(size_t)lane * LCH + 0] : 0ull;
  for (int W = 0; W < LCH; ++W) {
    int c0 = W << 6;
    u64 s = __shfl(supp, W);
    u64 v = __shfl(vword, W);
    u64 dnext = 0ull; u32 rnext = 0u;
    if (W + 1 < LCH) {
      int row = c0 + 64 + lane;
      rnext = RZ[row];
      dnext = ((rnext >> (W + 1)) & 1u) ? M[(size_t)row * LCH + (W + 1)]
                                        : 0ull;
    }
    // greedy resolve: scalar readlane over suppressor rows only
    u64 pending = v & ~s;
    u64 kw = 0ull;
    u64 suppressors = __ballot((dch & pending) != 0ull) & pending;
    while (pending) {
      u64 sp = pending & suppressors;
      if (!sp) { kw |= pending; break; }
      int q = __builtin_ctzll(sp);
      u64 below = pending & ((1ull << q) - 1ull);
      kw |= below | (1ull << q);
      u64 supq = readlane_u64(dch, q);
      pending &= ~supq;
      pending &= ~below;
      pending &= ~(1ull << q);
    }
    // sparse apply: kept rows with a nonzero word beyond W; per-lane rnz gate
    u64 kwload = __ballot(((rnz >> W) >> 1) != 0u) & kw;
    u64 kk = kwload;
    bool ld = (lane > W) && (lane < LCH);
    while (kk) {
      int q0 = __builtin_ctzll(kk);
      kk &= kk - 1ull;
      u32 rq0 = (u32)__builtin_amdgcn_readlane((int)rnz, q0);
      u64 m0 = (ld && ((rq0 >> lane) & 1u))
                   ? M[(size_t)(c0 + q0) * LCH + lane] : 0ull;
      if (kk) {
        int q1 = __builtin_ctzll(kk);
        kk &= kk - 1ull;
        u32 rq1 = (u32)__builtin_amdgcn_readlane((int)rnz, q1);
        u64 m1 = (ld && ((rq1 >> lane) & 1u))
                     ? M[(size_t)(c0 + q1) * LCH + lane] : 0ull;
        m0 |= m1;
      }
      supp |= m0;
    }
    if (lane == W) keep = kw;
    dch = dnext;
    rnz = rnext;
  }
  // compact kept: prefix popcount across lanes
  int pc = __popcll(keep);
  int incl = pc;
  for (int d = 1; d < 64; d <<= 1) {
    int t = __shfl_up(incl, d);
    if (lane >= d) incl += t;
  }
  int r = incl - pc;
  u64 kk = keep;
  while (kk) {
    int bit = __builtin_ctzll(kk);
    kk &= kk - 1ull;
    int p = lane * 64 + bit;
    keptkeys[(size_t)bl * LSEG + r] = cand_key[(size_t)bl * LSEG + p];
    keptpos[(size_t)bl * LSEG + r] = (u32)p;
    ++r;
  }
  if (lane == 63) keptcnt[bl] = (u32)incl;
}

// ---------------- K out: global rank via cross-level binary search -------------
__global__ __launch_bounds__(1024) void k_out(
    const u64* __restrict__ keptkeys, const u32* __restrict__ keptpos,
    const u32* __restrict__ keptcnt, const float4* __restrict__ sbox,
    const float* __restrict__ score, float* __restrict__ out) {
  int bl = blockIdx.x;
  int b = bl >> 2;
  int l = bl & 3;
  int r = threadIdx.x;
  u32 cnt = keptcnt[bl];
  if (r >= (int)cnt) return;
  u64 K = keptkeys[(size_t)bl * LSEG + r];
  int rank = r;
#pragma unroll
  for (int dl = 0; dl < 4; ++dl) {
    if (dl == l) continue;
    int obl = (b << 2) | dl;
    const u64* arr = keptkeys + (size_t)obl * LSEG;
    int lo = 0, hi = (int)keptcnt[obl];
    while (lo < hi) {
      int mid = (lo + hi) >> 1;
      if (arr[mid] > K) lo = mid + 1; else hi = mid;
    }
    rank += lo;
  }
  if (rank < POSTN) {
    u32 p = keptpos[(size_t)bl * LSEG + r];
    float4 bx = sbox[(size_t)bl * LSEG + p];
    size_t ob = ((size_t)b * POSTN + (size_t)rank) * 4;
    out[ob + 0] = bx.x;
    out[ob + 1] = bx.y;
    out[ob + 2] = bx.z;
    out[ob + 3] = bx.w;
    out[(size_t)NB * POSTN * 4 + (size_t)b * POSTN + (size_t)rank] =
        score[(size_t)bl * LSEG + p];
  }
}

extern "C" void kernel_launch(void* const* d_in, const int* in_sizes, int n_in,
                              void* d_out, int out_size, void* d_ws, size_t ws_size,
                              hipStream_t stream) {
  // setup_inputs dict order: cls0, reg0, cls1, reg1, cls2, reg2, cls3, reg3, anchors
  const float* cls0 = (const float*)d_in[0];
  const float* reg0 = (const float*)d_in[1];
  const float* cls1 = (const float*)d_in[2];
  const float* reg1 = (const float*)d_in[3];
  const float* cls2 = (const float*)d_in[4];
  const float* reg2 = (const float*)d_in[5];
  const float* cls3 = (const float*)d_in[6];
  const float* reg3 = (const float*)d_in[7];
  const float* anchors = (const float*)d_in[8];
  float* out = (float*)d_out;

  char* ws = (char*)d_ws;
  size_t off = 0;
  auto take = [&](size_t bytes) -> void* {
    off = (off + 255) & ~(size_t)255;
    void* p = ws + off;
    off += bytes;
    return p;
  };
  u64* maskl     = (u64*)take((size_t)64 * LSEG * LCH * 8);  // 8.4 MB (sparse)
  u64* sidebuf   = (u64*)take((size_t)64 * SIDECAP * 8);     // 2 MB
  u32* rnzl      = (u32*)take((size_t)64 * LSEG * 4);        // 256 KB
  u64* cand_key  = (u64*)take((size_t)NB * 4096 * 8);        // 512 KB
  float4* sbox   = (float4*)take((size_t)64 * LSEG * 16);    // 1 MB
  float4* boffA  = (float4*)take((size_t)64 * LSEG * 16);    // 1 MB
  float* area    = (float*)take((size_t)64 * LSEG * 4);
  float* score   = (float*)take((size_t)64 * LSEG * 4);
  u64* vmaskl    = (u64*)take((size_t)64 * LCH * 8);
  u64* keptkeys  = (u64*)take((size_t)64 * LSEG * 8);        // 512 KB
  u32* keptpos   = (u32*)take((size_t)64 * LSEG * 4);        // 256 KB
  u32* keptcnt   = (u32*)take((size_t)64 * 4);
  u32* hist1     = (u32*)take((size_t)64 * 2048 * 4);
  u32* counters  = (u32*)take((size_t)64 * 16 * 4);          // 64B-padded
  u32* sidecnt   = (u32*)take((size_t)64 * 16 * 4);          // 64B-padded
  u32* state_known = (u32*)take((size_t)64 * 4);
  u32* state_kneed = (u32*)take((size_t)64 * 4);
  (void)ws_size; (void)in_sizes; (void)n_in; (void)out_size;

  k_zero<<<512, 256, 0, stream>>>(out, counters, sidecnt, cand_key, hist1,
                                  state_known, state_kneed);
  k_hist1<<<192, 1024, 0, stream>>>(cls0, cls1, cls2, cls3, hist1);
  k_pick1<<<64, 1024, 0, stream>>>(hist1, state_known, state_kneed);
  k_collect<<<192, 1024, 0, stream>>>(cls0, cls1, cls2, cls3, state_known,
                                      reg0, reg1, reg2, reg3, anchors,
                                      counters, sidecnt, sidebuf, cand_key);
  k_finalize<<<64, 1024, 0, stream>>>(sidebuf, sidecnt, counters, state_kneed,
                                      reg0, reg1, reg2, reg3, anchors,
                                      cand_key);
  k_sortdec<<<64, 1024, 0, stream>>>(cand_key, reg0, reg1, reg2, reg3,
                                     anchors, sbox, boffA, area, score,
                                     vmaskl);
  k_maskl<<<64 * 64, 256, 0, stream>>>(boffA, area, maskl, rnzl);
  k_nmsl<<<64, 64, 0, stream>>>(maskl, rnzl, vmaskl, cand_key, keptkeys,
                                keptpos, keptcnt);
  k_out<<<64, 1024, 0, stream>>>(keptkeys, keptpos, keptcnt, sbox, score, out);
}

// Round 10
// 176.915 us; speedup vs baseline: 8.6312x; 1.0216x over previous
//
#include <hip/hip_runtime.h>
#include <cstdint>
#include <cstddef>

typedef uint32_t u32;
typedef uint64_t u64;

#define NB 16
#define POSTN 1000
#define PREN 1000
#define LSEG 1024     // per-level segment (1000 candidates + 24 pad)
#define LCH 16        // chunks of 64 per level
#define SIDECAP 4096  // per-task boundary-bucket buffer
#define BSIDE 2048    // per-block LDS side list

__constant__ int c_N[4]    = {120000, 30000, 7500, 1875};
__constant__ int c_OFF[4]  = {0, 120000, 150000, 157500};
__constant__ int c_HW[4]   = {40000, 10000, 2500, 625};
__constant__ int c_W[4]    = {200, 100, 50, 25};
__constant__ int c_BASE[4] = {0, 1024, 2048, 3072};

__device__ __forceinline__ u32 ord_bits(float f) {
  u32 u = __float_as_uint(f);
  return (u & 0x80000000u) ? ~u : (u | 0x80000000u);
}
__device__ __forceinline__ float inv_ord(u32 o) {
  u32 bits = (o & 0x80000000u) ? (o ^ 0x80000000u) : ~o;
  return __uint_as_float(bits);
}
__device__ __forceinline__ u64 readlane_u64(u64 v, int l) {
  u32 lo = (u32)__builtin_amdgcn_readlane((int)(u32)v, l);
  u32 hi = (u32)__builtin_amdgcn_readlane((int)(u32)(v >> 32), l);
  return (((u64)hi) << 32) | (u64)lo;
}

// 192-block slice map: 8 blocks/task lvl0, 2/task lvl1, 1/task lvl2+3
__device__ __forceinline__ void slice_map(int bid, int& lvl, int& b, int& e0,
                                          int& nsl) {
  if (bid < 128)      { lvl = 0; b = bid >> 3; e0 = (bid & 7) * 15000; nsl = 15000; }
  else if (bid < 160) { lvl = 1; int t = bid - 128; b = t >> 1; e0 = (t & 1) * 15000; nsl = 15000; }
  else if (bid < 176) { lvl = 2; b = bid - 160; e0 = 0; nsl = 7500; }
  else                { lvl = 3; b = bid - 176; e0 = 0; nsl = 1875; }
}

struct DecBox { float x1, y1, x2, y2; int lvl; bool valid; };

__device__ DecBox decode_box(u32 gid, int b,
    const float* __restrict__ reg0, const float* __restrict__ reg1,
    const float* __restrict__ reg2, const float* __restrict__ reg3,
    const float* __restrict__ anchors) {
  int lvl = (gid < 120000u) ? 0 : (gid < 150000u) ? 1 : (gid < 157500u) ? 2 : 3;
  int local = (int)gid - c_OFF[lvl];
  int a = local % 3;
  int cell = local / 3;
  int w = c_W[lvl];
  int hw = c_HW[lvl];
  int y = cell / w;
  int x = cell - y * w;
  const float* reg = (lvl == 0) ? reg0 : (lvl == 1) ? reg1 : (lvl == 2) ? reg2 : reg3;
  size_t base = ((size_t)(b * 12 + a * 4) * (size_t)w + (size_t)y) * (size_t)w + (size_t)x;
  const float CLIPV = 4.135166556742356f; // log(1000/16) as f32
  float dx = reg[base];
  float dy = reg[base + (size_t)hw];
  float dwv = fminf(reg[base + 2 * (size_t)hw], CLIPV);
  float dhv = fminf(reg[base + 3 * (size_t)hw], CLIPV);
  float a0 = anchors[(size_t)gid * 4 + 0];
  float a1 = anchors[(size_t)gid * 4 + 1];
  float a2 = anchors[(size_t)gid * 4 + 2];
  float a3 = anchors[(size_t)gid * 4 + 3];
  float wa = __fsub_rn(a2, a0);
  float ha = __fsub_rn(a3, a1);
  float cxa = __fadd_rn(a0, __fmul_rn(0.5f, wa));
  float cya = __fadd_rn(a1, __fmul_rn(0.5f, ha));
  float pcx = __fadd_rn(__fmul_rn(dx, wa), cxa);
  float pcy = __fadd_rn(__fmul_rn(dy, ha), cya);
  float pw = __fmul_rn(expf(dwv), wa);
  float ph = __fmul_rn(expf(dhv), ha);
  float x1 = __fsub_rn(pcx, __fmul_rn(0.5f, pw));
  float y1 = __fsub_rn(pcy, __fmul_rn(0.5f, ph));
  float x2 = __fadd_rn(pcx, __fmul_rn(0.5f, pw));
  float y2 = __fadd_rn(pcy, __fmul_rn(0.5f, ph));
  x1 = fminf(fmaxf(x1, 0.0f), 800.0f);
  y1 = fminf(fmaxf(y1, 0.0f), 800.0f);
  x2 = fminf(fmaxf(x2, 0.0f), 800.0f);
  y2 = fminf(fmaxf(y2, 0.0f), 800.0f);
  DecBox r;
  r.x1 = x1; r.y1 = y1; r.x2 = x2; r.y2 = y2; r.lvl = lvl;
  r.valid = (__fsub_rn(x2, x1) >= 1.0f) && (__fsub_rn(y2, y1) >= 1.0f);
  return r;
}

// ---------------- K0: zero state ----------------------------------------------
__global__ void k_zero(float* __restrict__ out, u32* __restrict__ counters,
                       u32* __restrict__ sidecnt, u64* __restrict__ cand_key,
                       u32* __restrict__ hist1, u32* __restrict__ state_known,
                       u32* __restrict__ state_kneed) {
  int i = blockIdx.x * blockDim.x + threadIdx.x;
  if (i < NB * POSTN * 5) out[i] = 0.0f;
  if (i < NB * 4096) cand_key[i] = 0ull;
  if (i < 64 * 2048) hist1[i] = 0u;
  if (i < 64 * 16) { counters[i] = 0u; sidecnt[i] = 0u; }
  if (i < 64) { state_known[i] = 0u; state_kneed[i] = (u32)PREN; }
}

// ---------------- K1: top-11-bit histogram straight from cls -------------------
__global__ __launch_bounds__(1024) void k_hist1(
    const float* __restrict__ cls0, const float* __restrict__ cls1,
    const float* __restrict__ cls2, const float* __restrict__ cls3,
    u32* __restrict__ hist1) {
  int lvl, b, e0, nsl;
  slice_map(blockIdx.x, lvl, b, e0, nsl);
  const float* cls = (lvl == 0) ? cls0 : (lvl == 1) ? cls1 : (lvl == 2) ? cls2 : cls3;
  const float* cp = cls + (size_t)b * c_N[lvl];
  int tid = threadIdx.x;
  __shared__ u32 h[2048];
  for (int t = tid; t < 2048; t += 1024) h[t] = 0u;
  __syncthreads();
  for (int e = e0 + tid; e < e0 + nsl; e += 1024)
    atomicAdd(&h[ord_bits(cp[e]) >> 21], 1u);
  __syncthreads();
  int task = lvl * 16 + b;
  for (int t = tid; t < 2048; t += 1024) {
    u32 v = h[t];
    if (v) atomicAdd(&hist1[task * 2048 + t], v);
  }
}

// ---------------- K2: pick boundary bucket (suffix scan) -----------------------
__global__ __launch_bounds__(1024) void k_pick1(
    const u32* __restrict__ hist1, u32* __restrict__ state_known,
    u32* __restrict__ state_kneed) {
  int task = blockIdx.x;
  int tid = threadIdx.x;
  __shared__ u32 A[2048], Bb[2048];
  __shared__ int sh_t;
  __shared__ u32 sh_above;
  u32 kneed = (u32)PREN;
  for (int t = tid; t < 2048; t += 1024) A[t] = hist1[task * 2048 + t];
  __syncthreads();
  u32* cur = A;
  u32* nxt = Bb;
  for (int off2 = 1; off2 < 2048; off2 <<= 1) {
    for (int t = tid; t < 2048; t += 1024)
      nxt[t] = cur[t] + ((t + off2 < 2048) ? cur[t + off2] : 0u);
    __syncthreads();
    u32* tmp = cur; cur = nxt; nxt = tmp;
  }
  for (int t = tid; t < 2048; t += 1024) {
    u32 s = cur[t];
    u32 above = (t + 1 < 2048) ? cur[t + 1] : 0u;
    if (s >= kneed && above < kneed) { sh_t = t; sh_above = above; }
  }
  __syncthreads();
  if (tid == 0) {
    state_known[task] = (u32)sh_t << 21;
    state_kneed[task] = kneed - sh_above;   // how many to take from boundary
  }
}

// ---------------- K3: collect — block-local staging, 1 atomic per block --------
__global__ __launch_bounds__(1024) void k_collect(
    const float* __restrict__ cls0, const float* __restrict__ cls1,
    const float* __restrict__ cls2, const float* __restrict__ cls3,
    const u32* __restrict__ state_known,
    const float* __restrict__ reg0, const float* __restrict__ reg1,
    const float* __restrict__ reg2, const float* __restrict__ reg3,
    const float* __restrict__ anchors, u32* __restrict__ counters,
    u32* __restrict__ sidecnt, u64* __restrict__ sidebuf,
    u64* __restrict__ cand_key) {
  int lvl, b, e0, nsl;
  slice_map(blockIdx.x, lvl, b, e0, nsl);
  int task = lvl * 16 + b;
  u32 tb = state_known[task] >> 21;
  const float* cls = (lvl == 0) ? cls0 : (lvl == 1) ? cls1 : (lvl == 2) ? cls2 : cls3;
  const float* cp = cls + (size_t)b * c_N[lvl];
  int tid = threadIdx.x;
  __shared__ u32 ldef[1024];
  __shared__ u32 lside[BSIDE];
  __shared__ u32 cdef, cside, bdef, bside;
  if (tid == 0) { cdef = 0u; cside = 0u; }
  __syncthreads();
  for (int e = e0 + tid; e < e0 + nsl; e += 1024) {
    u32 bk = ord_bits(cp[e]) >> 21;
    if (bk < tb) continue;
    if (bk > tb) {
      u32 i = atomicAdd(&cdef, 1u);
      if (i < 1024u) ldef[i] = (u32)e;
    } else {
      u32 i = atomicAdd(&cside, 1u);
      if (i < (u32)BSIDE) lside[i] = (u32)e;
    }
  }
  __syncthreads();
  if (tid == 0) bdef = atomicAdd(&counters[task * 16], min(cdef, 1024u));
  if (tid == 1) bside = atomicAdd(&sidecnt[task * 16], min(cside, (u32)BSIDE));
  __syncthreads();
  int hw = c_HW[lvl], off = c_OFF[lvl];
  u32 nd = min(cdef, 1024u);
  for (u32 i = tid; i < nd; i += 1024) {
    int e = (int)ldef[i];
    int a = e / hw;
    int cell = e - a * hw;
    u32 gid = (u32)(off + cell * 3 + a);
    u64 key = ((u64)ord_bits(cp[e]) << 32) | (u32)(~gid);
    DecBox bx = decode_box(gid, b, reg0, reg1, reg2, reg3, anchors);
    u64 skey = bx.valid ? key : (key & 0xFFFFFFFFull);
    u32 slot = bdef + i;
    if (slot < (u32)PREN)
      cand_key[(size_t)b * 4096 + c_BASE[lvl] + slot] = skey;
  }
  u32 ns = min(cside, (u32)BSIDE);
  for (u32 i = tid; i < ns; i += 1024) {
    int e = (int)lside[i];
    int a = e / hw;
    int cell = e - a * hw;
    u32 gid = (u32)(off + cell * 3 + a);
    u64 key = ((u64)ord_bits(cp[e]) << 32) | (u32)(~gid);
    u32 slot = bside + i;
    if (slot < (u32)SIDECAP) sidebuf[(size_t)task * SIDECAP + slot] = key;
  }
}

// ---------------- K4: finalize — sort boundary bucket (np2), append kneed ------
__global__ __launch_bounds__(1024) void k_finalize(
    const u64* __restrict__ sidebuf, const u32* __restrict__ sidecnt,
    const u32* __restrict__ counters, const u32* __restrict__ state_kneed,
    const float* __restrict__ reg0, const float* __restrict__ reg1,
    const float* __restrict__ reg2, const float* __restrict__ reg3,
    const float* __restrict__ anchors, u64* __restrict__ cand_key) {
  int task = blockIdx.x;
  int lvl = task >> 4;
  int b = task & 15;
  int tid = threadIdx.x;
  u32 nside = min(sidecnt[task * 16], (u32)SIDECAP);
  u32 kneed = state_kneed[task];
  u32 nab = counters[task * 16];
  u32 np2 = 64;
  while (np2 < nside) np2 <<= 1;   // next pow2 >= nside (uniform)
  __shared__ u64 sk[SIDECAP];
  for (u32 i = tid; i < np2; i += 1024)
    sk[i] = (i < nside) ? sidebuf[(size_t)task * SIDECAP + i] : 0ull;
  __syncthreads();
  for (u32 k = 2; k <= np2; k <<= 1) {
    for (u32 j = k >> 1; j > 0; j >>= 1) {
      for (u32 t = tid; t < np2 / 2; t += 1024) {
        u32 i = 2u * t - (t & (j - 1u));
        u32 l2 = i | j;
        u64 av = sk[i], bv = sk[l2];
        bool up = ((i & k) == 0u);
        if (up ? (av < bv) : (av > bv)) { sk[i] = bv; sk[l2] = av; }
      }
      __syncthreads();
    }
  }
  if (tid < (int)kneed) {
    u64 key = sk[tid];
    u32 gid = ~((u32)key);
    DecBox bx = decode_box(gid, b, reg0, reg1, reg2, reg3, anchors);
    u64 skey = bx.valid ? key : (key & 0xFFFFFFFFull);
    u32 slot = nab + (u32)tid;
    if (slot < (u32)PREN)
      cand_key[(size_t)b * 4096 + c_BASE[lvl] + slot] = skey;
  }
}

// ---------------- K sortdec: fused per-(image,level) sort + decode -------------
__global__ __launch_bounds__(1024) void k_sortdec(
    u64* __restrict__ cand_key,
    const float* __restrict__ reg0, const float* __restrict__ reg1,
    const float* __restrict__ reg2, const float* __restrict__ reg3,
    const float* __restrict__ anchors,
    float4* __restrict__ sbox, float4* __restrict__ boffA,
    float* __restrict__ area, float* __restrict__ score,
    u64* __restrict__ vmaskl) {
  int bl = blockIdx.x;                 // b*4 + lvl
  int b = bl >> 2;
  int tid = threadIdx.x;
  __shared__ u64 sk[LSEG];
  sk[tid] = cand_key[(size_t)bl * LSEG + tid];
  __syncthreads();
  for (u32 k = 2; k <= LSEG; k <<= 1) {
    for (u32 j = k >> 1; j > 0; j >>= 1) {
      if (tid < LSEG / 2) {
        u32 t = (u32)tid;
        u32 i = 2u * t - (t & (j - 1u));
        u32 l2 = i | j;
        u64 av = sk[i], bv = sk[l2];
        bool up = ((i & k) == 0u);
        if (up ? (av < bv) : (av > bv)) { sk[i] = bv; sk[l2] = av; }
      }
      __syncthreads();
    }
  }
  // write back sorted keys (k_nmsl reads them for kept compaction)
  u64 key = sk[tid];
  cand_key[(size_t)bl * LSEG + tid] = key;
  // decode payloads
  float4 bx4 = make_float4(0.f, 0.f, 0.f, 0.f);
  float4 bo4 = make_float4(0.f, 0.f, 0.f, 0.f);
  float ar = 0.f, sc = 0.f;
  bool vflag = false;
  if (key != 0ull) {
    u32 gid = ~((u32)key);
    vflag = (key >> 32) != 0ull;
    DecBox bx = decode_box(gid, b, reg0, reg1, reg2, reg3, anchors);
    bx4 = make_float4(bx.x1, bx.y1, bx.x2, bx.y2);
    float offv = __fmul_rn((float)bx.lvl, 801.0f);
    bo4 = make_float4(__fadd_rn(bx.x1, offv), __fadd_rn(bx.y1, offv),
                      __fadd_rn(bx.x2, offv), __fadd_rn(bx.y2, offv));
    ar = __fmul_rn(__fsub_rn(bo4.z, bo4.x), __fsub_rn(bo4.w, bo4.y));
    if (vflag) {
      float logit = inv_ord((u32)(key >> 32));
      sc = 1.0f / (1.0f + expf(-logit));
    }
  }
  size_t gi = (size_t)bl * LSEG + tid;
  sbox[gi] = bx4;
  boffA[gi] = bo4;
  area[gi] = ar;
  score[gi] = sc;
  u64 bal = __ballot(vflag ? 1 : 0);
  if ((tid & 63) == 0) vmaskl[bl * LCH + (tid >> 6)] = bal;
}

// ---------------- K maskl: sparse IoU bitmask — exact div-free test ------------
// RN(inter/uni) > 0.7f  <=>  inter/uni >= B, B = 0.7f + 2^-25 (tie rounds up).
// B*(double)uni is exact (25x24 bits <= 53); comparison is bit-equivalent.
#define RPB 16
__global__ __launch_bounds__(256) void k_maskl(
    const float4* __restrict__ boffA, const float* __restrict__ area,
    u64* __restrict__ maskl, u32* __restrict__ rnzl) {
  const double Bd = 0x1.6666661p-1;   // 0.7000000178813934326171875
  int bg = blockIdx.x;
  int bl = bg >> 6;                 // (b*4+lvl)
  int g = bg & 63;                  // row-group within level
  int row0 = g * RPB;
  int tid = threadIdx.x;
  int wave = tid >> 6;
  int lane = tid & 63;
  __shared__ float4 rb[RPB];
  __shared__ float ra[RPB];
  __shared__ u32 rnzs[RPB];
  if (tid < RPB) {
    rb[tid] = boffA[(size_t)bl * LSEG + row0 + tid];
    ra[tid] = area[(size_t)bl * LSEG + row0 + tid];
    rnzs[tid] = 0u;
  }
  __syncthreads();
  u64* M = maskl + (size_t)bl * LSEG * LCH;
  for (int chunk = 0; chunk < 4; ++chunk) {
    int wword = chunk * 4 + wave;
    int wmaxj = chunk * 256 + wave * 64 + 63;   // this wave's max column
    if (wmaxj <= row0) continue;                // below diagonal: nothing
    int j = chunk * 256 + tid;
    float4 cb = boffA[(size_t)bl * LSEG + j];
    float ca = area[(size_t)bl * LSEG + j];
#pragma unroll
    for (int rr = 0; rr < RPB; ++rr) {
      int i = row0 + rr;
      if (wmaxj <= i) continue;
      float4 rbb = rb[rr];
      float ria = ra[rr];
      float ix1 = fmaxf(cb.x, rbb.x);
      float iy1 = fmaxf(cb.y, rbb.y);
      float ix2 = fminf(cb.z, rbb.z);
      float iy2 = fminf(cb.w, rbb.w);
      float inter = __fmul_rn(fmaxf(__fsub_rn(ix2, ix1), 0.0f),
                              fmaxf(__fsub_rn(iy2, iy1), 0.0f));
      float uni = __fsub_rn(__fadd_rn(ca, ria), inter);
      bool pred = (j > i) && (inter > 0.0f) &&
                  ((double)inter >= Bd * (double)uni);
      u64 bal = __ballot(pred ? 1 : 0);
      if (lane == 0 && bal) {           // write ONLY nonzero words
        M[(size_t)i * LCH + wword] = bal;
        atomicOr(&rnzs[rr], 1u << wword);
      }
    }
  }
  __syncthreads();
  if (tid < RPB) rnzl[(size_t)bl * LSEG + row0 + tid] = rnzs[tid];
}

// ---------------- K nmsl: greedy NMS — all loads hoisted to parallel prologue --
__global__ __launch_bounds__(64) void k_nmsl(
    const u64* __restrict__ maskl, const u32* __restrict__ rnzl,
    const u64* __restrict__ vmaskl, const u64* __restrict__ cand_key,
    u64* __restrict__ keptkeys, u32* __restrict__ keptpos,
    u32* __restrict__ keptcnt) {
  int bl = blockIdx.x;
  int lane = threadIdx.x;
  const u64* M = maskl + (size_t)bl * LSEG * LCH;
  const u32* RZ = rnzl + (size_t)bl * LSEG;
  // prologue: ALL rnz + diagonal loads issued in parallel (2 memory rounds)
  u32 rz[LCH];
#pragma unroll
  for (int c = 0; c < LCH; ++c) rz[c] = RZ[c * 64 + lane];
  u64 dch[LCH];
#pragma unroll
  for (int c = 0; c < LCH; ++c)
    dch[c] = ((rz[c] >> c) & 1u) ? M[(size_t)(c * 64 + lane) * LCH + c] : 0ull;
  u64 vword = (lane < LCH) ? vmaskl[bl * LCH + lane] : 0ull;
  u64 supp = 0ull;   // lane w<16 holds suppression word w
  u64 keep = 0ull;   // lane w<16 holds keep word w
#pragma unroll
  for (int W = 0; W < LCH; ++W) {
    int c0 = W << 6;
    u64 s = __shfl(supp, W);
    u64 v = __shfl(vword, W);
    // greedy resolve: scalar readlane over suppressor rows only (register ops)
    u64 pending = v & ~s;
    u64 kw = 0ull;
    u64 suppressors = __ballot((dch[W] & pending) != 0ull) & pending;
    while (pending) {
      u64 sp = pending & suppressors;
      if (!sp) { kw |= pending; break; }
      int q = __builtin_ctzll(sp);
      u64 below = pending & ((1ull << q) - 1ull);
      kw |= below | (1ull << q);
      u64 supq = readlane_u64(dch[W], q);
      pending &= ~supq;
      pending &= ~below;
      pending &= ~(1ull << q);
    }
    // sparse apply: kept rows with a nonzero word beyond W; per-lane rnz gate
    u64 kwload = __ballot(((rz[W] >> W) >> 1) != 0u) & kw;
    u64 kk = kwload;
    bool ld = (lane > W) && (lane < LCH);
    while (kk) {
      int q0 = __builtin_ctzll(kk);
      kk &= kk - 1ull;
      u32 rq0 = (u32)__builtin_amdgcn_readlane((int)rz[W], q0);
      u64 m0 = (ld && ((rq0 >> lane) & 1u))
                   ? M[(size_t)(c0 + q0) * LCH + lane] : 0ull;
      if (kk) {
        int q1 = __builtin_ctzll(kk);
        kk &= kk - 1ull;
        u32 rq1 = (u32)__builtin_amdgcn_readlane((int)rz[W], q1);
        u64 m1 = (ld && ((rq1 >> lane) & 1u))
                     ? M[(size_t)(c0 + q1) * LCH + lane] : 0ull;
        m0 |= m1;
      }
      supp |= m0;
    }
    if (lane == W) keep = kw;
  }
  // compact kept: prefix popcount across lanes
  int pc = __popcll(keep);
  int incl = pc;
  for (int d = 1; d < 64; d <<= 1) {
    int t = __shfl_up(incl, d);
    if (lane >= d) incl += t;
  }
  int r = incl - pc;
  u64 kk = keep;
  while (kk) {
    int bit = __builtin_ctzll(kk);
    kk &= kk - 1ull;
    int p = lane * 64 + bit;
    keptkeys[(size_t)bl * LSEG + r] = cand_key[(size_t)bl * LSEG + p];
    keptpos[(size_t)bl * LSEG + r] = (u32)p;
    ++r;
  }
  if (lane == 63) keptcnt[bl] = (u32)incl;
}

// ---------------- K out: global rank via cross-level binary search -------------
__global__ __launch_bounds__(1024) void k_out(
    const u64* __restrict__ keptkeys, const u32* __restrict__ keptpos,
    const u32* __restrict__ keptcnt, const float4* __restrict__ sbox,
    const float* __restrict__ score, float* __restrict__ out) {
  int bl = blockIdx.x;
  int b = bl >> 2;
  int l = bl & 3;
  int r = threadIdx.x;
  u32 cnt = keptcnt[bl];
  if (r >= (int)cnt) return;
  u64 K = keptkeys[(size_t)bl * LSEG + r];
  int rank = r;
#pragma unroll
  for (int dl = 0; dl < 4; ++dl) {
    if (dl == l) continue;
    int obl = (b << 2) | dl;
    const u64* arr = keptkeys + (size_t)obl * LSEG;
    int lo = 0, hi = (int)keptcnt[obl];
    while (lo < hi) {
      int mid = (lo + hi) >> 1;
      if (arr[mid] > K) lo = mid + 1; else hi = mid;
    }
    rank += lo;
  }
  if (rank < POSTN) {
    u32 p = keptpos[(size_t)bl * LSEG + r];
    float4 bx = sbox[(size_t)bl * LSEG + p];
    size_t ob = ((size_t)b * POSTN + (size_t)rank) * 4;
    out[ob + 0] = bx.x;
    out[ob + 1] = bx.y;
    out[ob + 2] = bx.z;
    out[ob + 3] = bx.w;
    out[(size_t)NB * POSTN * 4 + (size_t)b * POSTN + (size_t)rank] =
        score[(size_t)bl * LSEG + p];
  }
}

extern "C" void kernel_launch(void* const* d_in, const int* in_sizes, int n_in,
                              void* d_out, int out_size, void* d_ws, size_t ws_size,
                              hipStream_t stream) {
  // setup_inputs dict order: cls0, reg0, cls1, reg1, cls2, reg2, cls3, reg3, anchors
  const float* cls0 = (const float*)d_in[0];
  const float* reg0 = (const float*)d_in[1];
  const float* cls1 = (const float*)d_in[2];
  const float* reg1 = (const float*)d_in[3];
  const float* cls2 = (const float*)d_in[4];
  const float* reg2 = (const float*)d_in[5];
  const float* cls3 = (const float*)d_in[6];
  const float* reg3 = (const float*)d_in[7];
  const float* anchors = (const float*)d_in[8];
  float* out = (float*)d_out;

  char* ws = (char*)d_ws;
  size_t off = 0;
  auto take = [&](size_t bytes) -> void* {
    off = (off + 255) & ~(size_t)255;
    void* p = ws + off;
    off += bytes;
    return p;
  };
  u64* maskl     = (u64*)take((size_t)64 * LSEG * LCH * 8);  // 8.4 MB (sparse)
  u64* sidebuf   = (u64*)take((size_t)64 * SIDECAP * 8);     // 2 MB
  u32* rnzl      = (u32*)take((size_t)64 * LSEG * 4);        // 256 KB
  u64* cand_key  = (u64*)take((size_t)NB * 4096 * 8);        // 512 KB
  float4* sbox   = (float4*)take((size_t)64 * LSEG * 16);    // 1 MB
  float4* boffA  = (float4*)take((size_t)64 * LSEG * 16);    // 1 MB
  float* area    = (float*)take((size_t)64 * LSEG * 4);
  float* score   = (float*)take((size_t)64 * LSEG * 4);
  u64* vmaskl    = (u64*)take((size_t)64 * LCH * 8);
  u64* keptkeys  = (u64*)take((size_t)64 * LSEG * 8);        // 512 KB
  u32* keptpos   = (u32*)take((size_t)64 * LSEG * 4);        // 256 KB
  u32* keptcnt   = (u32*)take((size_t)64 * 4);
  u32* hist1     = (u32*)take((size_t)64 * 2048 * 4);
  u32* counters  = (u32*)take((size_t)64 * 16 * 4);          // 64B-padded
  u32* sidecnt   = (u32*)take((size_t)64 * 16 * 4);          // 64B-padded
  u32* state_known = (u32*)take((size_t)64 * 4);
  u32* state_kneed = (u32*)take((size_t)64 * 4);
  (void)ws_size; (void)in_sizes; (void)n_in; (void)out_size;

  k_zero<<<512, 256, 0, stream>>>(out, counters, sidecnt, cand_key, hist1,
                                  state_known, state_kneed);
  k_hist1<<<192, 1024, 0, stream>>>(cls0, cls1, cls2, cls3, hist1);
  k_pick1<<<64, 1024, 0, stream>>>(hist1, state_known, state_kneed);
  k_collect<<<192, 1024, 0, stream>>>(cls0, cls1, cls2, cls3, state_known,
                                      reg0, reg1, reg2, reg3, anchors,
                                      counters, sidecnt, sidebuf, cand_key);
  k_finalize<<<64, 1024, 0, stream>>>(sidebuf, sidecnt, counters, state_kneed,
                                      reg0, reg1, reg2, reg3, anchors,
                                      cand_key);
  k_sortdec<<<64, 1024, 0, stream>>>(cand_key, reg0, reg1, reg2, reg3,
                                     anchors, sbox, boffA, area, score,
                                     vmaskl);
  k_maskl<<<64 * 64, 256, 0, stream>>>(boffA, area, maskl, rnzl);
  k_nmsl<<<64, 64, 0, stream>>>(maskl, rnzl, vmaskl, cand_key, keptkeys,
                                keptpos, keptcnt);
  k_out<<<64, 1024, 0, stream>>>(keptkeys, keptpos, keptcnt, sbox, score, out);
}

// Round 11
// 168.804 us; speedup vs baseline: 9.0459x; 1.0480x over previous
//
#include <hip/hip_runtime.h>
#include <cstdint>
#include <cstddef>

typedef uint32_t u32;
typedef uint64_t u64;

#define NB 16
#define POSTN 1000
#define PREN 1000
#define LSEG 1024     // per-level segment (1000 candidates + 24 pad)
#define LCH 16        // chunks of 64 per level
#define SIDECAP 4096  // per-task boundary-bucket buffer
#define BSIDE 2048    // per-block LDS side list
#define TRIPCAP (LSEG * LCH)  // per-task triplet capacity = full matrix

__constant__ int c_N[4]    = {120000, 30000, 7500, 1875};
__constant__ int c_OFF[4]  = {0, 120000, 150000, 157500};
__constant__ int c_HW[4]   = {40000, 10000, 2500, 625};
__constant__ int c_W[4]    = {200, 100, 50, 25};
__constant__ int c_BASE[4] = {0, 1024, 2048, 3072};

__device__ __forceinline__ u32 ord_bits(float f) {
  u32 u = __float_as_uint(f);
  return (u & 0x80000000u) ? ~u : (u | 0x80000000u);
}
__device__ __forceinline__ float inv_ord(u32 o) {
  u32 bits = (o & 0x80000000u) ? (o ^ 0x80000000u) : ~o;
  return __uint_as_float(bits);
}
__device__ __forceinline__ u64 readlane_u64(u64 v, int l) {
  u32 lo = (u32)__builtin_amdgcn_readlane((int)(u32)v, l);
  u32 hi = (u32)__builtin_amdgcn_readlane((int)(u32)(v >> 32), l);
  return (((u64)hi) << 32) | (u64)lo;
}

// 192-block slice map: 8 blocks/task lvl0, 2/task lvl1, 1/task lvl2+3
__device__ __forceinline__ void slice_map(int bid, int& lvl, int& b, int& e0,
                                          int& nsl) {
  if (bid < 128)      { lvl = 0; b = bid >> 3; e0 = (bid & 7) * 15000; nsl = 15000; }
  else if (bid < 160) { lvl = 1; int t = bid - 128; b = t >> 1; e0 = (t & 1) * 15000; nsl = 15000; }
  else if (bid < 176) { lvl = 2; b = bid - 160; e0 = 0; nsl = 7500; }
  else                { lvl = 3; b = bid - 176; e0 = 0; nsl = 1875; }
}

struct DecBox { float x1, y1, x2, y2; int lvl; bool valid; };

__device__ DecBox decode_box(u32 gid, int b,
    const float* __restrict__ reg0, const float* __restrict__ reg1,
    const float* __restrict__ reg2, const float* __restrict__ reg3,
    const float* __restrict__ anchors) {
  int lvl = (gid < 120000u) ? 0 : (gid < 150000u) ? 1 : (gid < 157500u) ? 2 : 3;
  int local = (int)gid - c_OFF[lvl];
  int a = local % 3;
  int cell = local / 3;
  int w = c_W[lvl];
  int hw = c_HW[lvl];
  int y = cell / w;
  int x = cell - y * w;
  const float* reg = (lvl == 0) ? reg0 : (lvl == 1) ? reg1 : (lvl == 2) ? reg2 : reg3;
  size_t base = ((size_t)(b * 12 + a * 4) * (size_t)w + (size_t)y) * (size_t)w + (size_t)x;
  const float CLIPV = 4.135166556742356f; // log(1000/16) as f32
  float dx = reg[base];
  float dy = reg[base + (size_t)hw];
  float dwv = fminf(reg[base + 2 * (size_t)hw], CLIPV);
  float dhv = fminf(reg[base + 3 * (size_t)hw], CLIPV);
  float a0 = anchors[(size_t)gid * 4 + 0];
  float a1 = anchors[(size_t)gid * 4 + 1];
  float a2 = anchors[(size_t)gid * 4 + 2];
  float a3 = anchors[(size_t)gid * 4 + 3];
  float wa = __fsub_rn(a2, a0);
  float ha = __fsub_rn(a3, a1);
  float cxa = __fadd_rn(a0, __fmul_rn(0.5f, wa));
  float cya = __fadd_rn(a1, __fmul_rn(0.5f, ha));
  float pcx = __fadd_rn(__fmul_rn(dx, wa), cxa);
  float pcy = __fadd_rn(__fmul_rn(dy, ha), cya);
  float pw = __fmul_rn(expf(dwv), wa);
  float ph = __fmul_rn(expf(dhv), ha);
  float x1 = __fsub_rn(pcx, __fmul_rn(0.5f, pw));
  float y1 = __fsub_rn(pcy, __fmul_rn(0.5f, ph));
  float x2 = __fadd_rn(pcx, __fmul_rn(0.5f, pw));
  float y2 = __fadd_rn(pcy, __fmul_rn(0.5f, ph));
  x1 = fminf(fmaxf(x1, 0.0f), 800.0f);
  y1 = fminf(fmaxf(y1, 0.0f), 800.0f);
  x2 = fminf(fmaxf(x2, 0.0f), 800.0f);
  y2 = fminf(fmaxf(y2, 0.0f), 800.0f);
  DecBox r;
  r.x1 = x1; r.y1 = y1; r.x2 = x2; r.y2 = y2; r.lvl = lvl;
  r.valid = (__fsub_rn(x2, x1) >= 1.0f) && (__fsub_rn(y2, y1) >= 1.0f);
  return r;
}

// ---------------- K0: zero state ----------------------------------------------
__global__ void k_zero(float* __restrict__ out, u32* __restrict__ counters,
                       u32* __restrict__ sidecnt, u32* __restrict__ tripcnt,
                       u64* __restrict__ cand_key,
                       u32* __restrict__ hist1, u32* __restrict__ state_known,
                       u32* __restrict__ state_kneed) {
  int i = blockIdx.x * blockDim.x + threadIdx.x;
  if (i < NB * POSTN * 5) out[i] = 0.0f;
  if (i < NB * 4096) cand_key[i] = 0ull;
  if (i < 64 * 2048) hist1[i] = 0u;
  if (i < 64 * 16) { counters[i] = 0u; sidecnt[i] = 0u; tripcnt[i] = 0u; }
  if (i < 64) { state_known[i] = 0u; state_kneed[i] = (u32)PREN; }
}

// ---------------- K1: top-11-bit histogram straight from cls -------------------
__global__ __launch_bounds__(1024) void k_hist1(
    const float* __restrict__ cls0, const float* __restrict__ cls1,
    const float* __restrict__ cls2, const float* __restrict__ cls3,
    u32* __restrict__ hist1) {
  int lvl, b, e0, nsl;
  slice_map(blockIdx.x, lvl, b, e0, nsl);
  const float* cls = (lvl == 0) ? cls0 : (lvl == 1) ? cls1 : (lvl == 2) ? cls2 : cls3;
  const float* cp = cls + (size_t)b * c_N[lvl];
  int tid = threadIdx.x;
  __shared__ u32 h[2048];
  for (int t = tid; t < 2048; t += 1024) h[t] = 0u;
  __syncthreads();
  for (int e = e0 + tid; e < e0 + nsl; e += 1024)
    atomicAdd(&h[ord_bits(cp[e]) >> 21], 1u);
  __syncthreads();
  int task = lvl * 16 + b;
  for (int t = tid; t < 2048; t += 1024) {
    u32 v = h[t];
    if (v) atomicAdd(&hist1[task * 2048 + t], v);
  }
}

// ---------------- K2: pick boundary bucket (suffix scan) -----------------------
__global__ __launch_bounds__(1024) void k_pick1(
    const u32* __restrict__ hist1, u32* __restrict__ state_known,
    u32* __restrict__ state_kneed) {
  int task = blockIdx.x;
  int tid = threadIdx.x;
  __shared__ u32 A[2048], Bb[2048];
  __shared__ int sh_t;
  __shared__ u32 sh_above;
  u32 kneed = (u32)PREN;
  for (int t = tid; t < 2048; t += 1024) A[t] = hist1[task * 2048 + t];
  __syncthreads();
  u32* cur = A;
  u32* nxt = Bb;
  for (int off2 = 1; off2 < 2048; off2 <<= 1) {
    for (int t = tid; t < 2048; t += 1024)
      nxt[t] = cur[t] + ((t + off2 < 2048) ? cur[t + off2] : 0u);
    __syncthreads();
    u32* tmp = cur; cur = nxt; nxt = tmp;
  }
  for (int t = tid; t < 2048; t += 1024) {
    u32 s = cur[t];
    u32 above = (t + 1 < 2048) ? cur[t + 1] : 0u;
    if (s >= kneed && above < kneed) { sh_t = t; sh_above = above; }
  }
  __syncthreads();
  if (tid == 0) {
    state_known[task] = (u32)sh_t << 21;
    state_kneed[task] = kneed - sh_above;   // how many to take from boundary
  }
}

// ---------------- K3: collect — block-local staging, 1 atomic per block --------
__global__ __launch_bounds__(1024) void k_collect(
    const float* __restrict__ cls0, const float* __restrict__ cls1,
    const float* __restrict__ cls2, const float* __restrict__ cls3,
    const u32* __restrict__ state_known,
    const float* __restrict__ reg0, const float* __restrict__ reg1,
    const float* __restrict__ reg2, const float* __restrict__ reg3,
    const float* __restrict__ anchors, u32* __restrict__ counters,
    u32* __restrict__ sidecnt, u64* __restrict__ sidebuf,
    u64* __restrict__ cand_key) {
  int lvl, b, e0, nsl;
  slice_map(blockIdx.x, lvl, b, e0, nsl);
  int task = lvl * 16 + b;
  u32 tb = state_known[task] >> 21;
  const float* cls = (lvl == 0) ? cls0 : (lvl == 1) ? cls1 : (lvl == 2) ? cls2 : cls3;
  const float* cp = cls + (size_t)b * c_N[lvl];
  int tid = threadIdx.x;
  __shared__ u32 ldef[1024];
  __shared__ u32 lside[BSIDE];
  __shared__ u32 cdef, cside, bdef, bside;
  if (tid == 0) { cdef = 0u; cside = 0u; }
  __syncthreads();
  for (int e = e0 + tid; e < e0 + nsl; e += 1024) {
    u32 bk = ord_bits(cp[e]) >> 21;
    if (bk < tb) continue;
    if (bk > tb) {
      u32 i = atomicAdd(&cdef, 1u);
      if (i < 1024u) ldef[i] = (u32)e;
    } else {
      u32 i = atomicAdd(&cside, 1u);
      if (i < (u32)BSIDE) lside[i] = (u32)e;
    }
  }
  __syncthreads();
  if (tid == 0) bdef = atomicAdd(&counters[task * 16], min(cdef, 1024u));
  if (tid == 1) bside = atomicAdd(&sidecnt[task * 16], min(cside, (u32)BSIDE));
  __syncthreads();
  int hw = c_HW[lvl], off = c_OFF[lvl];
  u32 nd = min(cdef, 1024u);
  for (u32 i = tid; i < nd; i += 1024) {
    int e = (int)ldef[i];
    int a = e / hw;
    int cell = e - a * hw;
    u32 gid = (u32)(off + cell * 3 + a);
    u64 key = ((u64)ord_bits(cp[e]) << 32) | (u32)(~gid);
    DecBox bx = decode_box(gid, b, reg0, reg1, reg2, reg3, anchors);
    u64 skey = bx.valid ? key : (key & 0xFFFFFFFFull);
    u32 slot = bdef + i;
    if (slot < (u32)PREN)
      cand_key[(size_t)b * 4096 + c_BASE[lvl] + slot] = skey;
  }
  u32 ns = min(cside, (u32)BSIDE);
  for (u32 i = tid; i < ns; i += 1024) {
    int e = (int)lside[i];
    int a = e / hw;
    int cell = e - a * hw;
    u32 gid = (u32)(off + cell * 3 + a);
    u64 key = ((u64)ord_bits(cp[e]) << 32) | (u32)(~gid);
    u32 slot = bside + i;
    if (slot < (u32)SIDECAP) sidebuf[(size_t)task * SIDECAP + slot] = key;
  }
}

// ---------------- K4: finalize — sort boundary bucket (np2), append kneed ------
__global__ __launch_bounds__(1024) void k_finalize(
    const u64* __restrict__ sidebuf, const u32* __restrict__ sidecnt,
    const u32* __restrict__ counters, const u32* __restrict__ state_kneed,
    const float* __restrict__ reg0, const float* __restrict__ reg1,
    const float* __restrict__ reg2, const float* __restrict__ reg3,
    const float* __restrict__ anchors, u64* __restrict__ cand_key) {
  int task = blockIdx.x;
  int lvl = task >> 4;
  int b = task & 15;
  int tid = threadIdx.x;
  u32 nside = min(sidecnt[task * 16], (u32)SIDECAP);
  u32 kneed = state_kneed[task];
  u32 nab = counters[task * 16];
  u32 np2 = 64;
  while (np2 < nside) np2 <<= 1;   // next pow2 >= nside (uniform)
  __shared__ u64 sk[SIDECAP];
  for (u32 i = tid; i < np2; i += 1024)
    sk[i] = (i < nside) ? sidebuf[(size_t)task * SIDECAP + i] : 0ull;
  __syncthreads();
  for (u32 k = 2; k <= np2; k <<= 1) {
    for (u32 j = k >> 1; j > 0; j >>= 1) {
      for (u32 t = tid; t < np2 / 2; t += 1024) {
        u32 i = 2u * t - (t & (j - 1u));
        u32 l2 = i | j;
        u64 av = sk[i], bv = sk[l2];
        bool up = ((i & k) == 0u);
        if (up ? (av < bv) : (av > bv)) { sk[i] = bv; sk[l2] = av; }
      }
      __syncthreads();
    }
  }
  if (tid < (int)kneed) {
    u64 key = sk[tid];
    u32 gid = ~((u32)key);
    DecBox bx = decode_box(gid, b, reg0, reg1, reg2, reg3, anchors);
    u64 skey = bx.valid ? key : (key & 0xFFFFFFFFull);
    u32 slot = nab + (u32)tid;
    if (slot < (u32)PREN)
      cand_key[(size_t)b * 4096 + c_BASE[lvl] + slot] = skey;
  }
}

// ---------------- K sortdec: fused per-(image,level) sort + decode -------------
__global__ __launch_bounds__(1024) void k_sortdec(
    u64* __restrict__ cand_key,
    const float* __restrict__ reg0, const float* __restrict__ reg1,
    const float* __restrict__ reg2, const float* __restrict__ reg3,
    const float* __restrict__ anchors,
    float4* __restrict__ sbox, float4* __restrict__ boffA,
    float* __restrict__ area, float* __restrict__ score,
    u64* __restrict__ vmaskl) {
  int bl = blockIdx.x;                 // b*4 + lvl
  int b = bl >> 2;
  int tid = threadIdx.x;
  __shared__ u64 sk[LSEG];
  sk[tid] = cand_key[(size_t)bl * LSEG + tid];
  __syncthreads();
  for (u32 k = 2; k <= LSEG; k <<= 1) {
    for (u32 j = k >> 1; j > 0; j >>= 1) {
      if (tid < LSEG / 2) {
        u32 t = (u32)tid;
        u32 i = 2u * t - (t & (j - 1u));
        u32 l2 = i | j;
        u64 av = sk[i], bv = sk[l2];
        bool up = ((i & k) == 0u);
        if (up ? (av < bv) : (av > bv)) { sk[i] = bv; sk[l2] = av; }
      }
      __syncthreads();
    }
  }
  // write back sorted keys (k_nmsl reads them for kept compaction)
  u64 key = sk[tid];
  cand_key[(size_t)bl * LSEG + tid] = key;
  // decode payloads
  float4 bx4 = make_float4(0.f, 0.f, 0.f, 0.f);
  float4 bo4 = make_float4(0.f, 0.f, 0.f, 0.f);
  float ar = 0.f, sc = 0.f;
  bool vflag = false;
  if (key != 0ull) {
    u32 gid = ~((u32)key);
    vflag = (key >> 32) != 0ull;
    DecBox bx = decode_box(gid, b, reg0, reg1, reg2, reg3, anchors);
    bx4 = make_float4(bx.x1, bx.y1, bx.x2, bx.y2);
    float offv = __fmul_rn((float)bx.lvl, 801.0f);
    bo4 = make_float4(__fadd_rn(bx.x1, offv), __fadd_rn(bx.y1, offv),
                      __fadd_rn(bx.x2, offv), __fadd_rn(bx.y2, offv));
    ar = __fmul_rn(__fsub_rn(bo4.z, bo4.x), __fsub_rn(bo4.w, bo4.y));
    if (vflag) {
      float logit = inv_ord((u32)(key >> 32));
      sc = 1.0f / (1.0f + expf(-logit));
    }
  }
  size_t gi = (size_t)bl * LSEG + tid;
  sbox[gi] = bx4;
  boffA[gi] = bo4;
  area[gi] = ar;
  score[gi] = sc;
  u64 bal = __ballot(vflag ? 1 : 0);
  if ((tid & 63) == 0) vmaskl[bl * LCH + (tid >> 6)] = bal;
}

// ---------------- K maskl: sparse IoU → compact triplet list -------------------
// RN(inter/uni) > 0.7f  <=>  inter/uni >= B, B = 0.7f + 2^-25 (tie rounds up).
// B*(double)uni is exact (25x24 bits <= 53); comparison is bit-equivalent.
#define RPB 16
__global__ __launch_bounds__(256) void k_maskl(
    const float4* __restrict__ boffA, const float* __restrict__ area,
    ulonglong2* __restrict__ trip, u32* __restrict__ tripcnt,
    u32* __restrict__ rnzl) {
  const double Bd = 0x1.6666661p-1;   // 0.7000000178813934326171875
  int bg = blockIdx.x;
  int bl = bg >> 6;                 // (b*4+lvl)
  int g = bg & 63;                  // row-group within level
  int row0 = g * RPB;
  int tid = threadIdx.x;
  int wave = tid >> 6;
  int lane = tid & 63;
  __shared__ float4 rb[RPB];
  __shared__ float ra[RPB];
  __shared__ u32 rnzs[RPB];
  __shared__ ulonglong2 stage[RPB * LCH];   // max 256 nonzero words per block
  __shared__ u32 scount, sbase;
  if (tid == 0) scount = 0u;
  if (tid < RPB) {
    rb[tid] = boffA[(size_t)bl * LSEG + row0 + tid];
    ra[tid] = area[(size_t)bl * LSEG + row0 + tid];
    rnzs[tid] = 0u;
  }
  __syncthreads();
  for (int chunk = 0; chunk < 4; ++chunk) {
    int wword = chunk * 4 + wave;
    int wmaxj = chunk * 256 + wave * 64 + 63;   // this wave's max column
    if (wmaxj <= row0) continue;                // below diagonal: nothing
    int j = chunk * 256 + tid;
    float4 cb = boffA[(size_t)bl * LSEG + j];
    float ca = area[(size_t)bl * LSEG + j];
#pragma unroll
    for (int rr = 0; rr < RPB; ++rr) {
      int i = row0 + rr;
      if (wmaxj <= i) continue;
      float4 rbb = rb[rr];
      float ria = ra[rr];
      float ix1 = fmaxf(cb.x, rbb.x);
      float iy1 = fmaxf(cb.y, rbb.y);
      float ix2 = fminf(cb.z, rbb.z);
      float iy2 = fminf(cb.w, rbb.w);
      float inter = __fmul_rn(fmaxf(__fsub_rn(ix2, ix1), 0.0f),
                              fmaxf(__fsub_rn(iy2, iy1), 0.0f));
      float uni = __fsub_rn(__fadd_rn(ca, ria), inter);
      bool pred = (j > i) && (inter > 0.0f) &&
                  ((double)inter >= Bd * (double)uni);
      u64 bal = __ballot(pred ? 1 : 0);
      if (lane == 0 && bal) {
        u32 sidx = atomicAdd(&scount, 1u);
        ulonglong2 e;
        e.x = bal;
        e.y = (u64)(u32)(i * LCH + wword);
        stage[sidx] = e;
        atomicOr(&rnzs[rr], 1u << wword);
      }
    }
  }
  __syncthreads();
  if (tid == 0 && scount) sbase = atomicAdd(&tripcnt[bl * 16], scount);
  if (tid < RPB) rnzl[(size_t)bl * LSEG + row0 + tid] = rnzs[tid];
  __syncthreads();
  for (u32 t = tid; t < scount; t += 256)
    trip[(size_t)bl * TRIPCAP + sbase + t] = stage[t];
}

// ---------------- K nmsl: greedy NMS — full mask matrix in LDS -----------------
__global__ __launch_bounds__(64) void k_nmsl(
    const ulonglong2* __restrict__ trip, const u32* __restrict__ tripcnt,
    const u32* __restrict__ rnzl, const u64* __restrict__ vmaskl,
    const u64* __restrict__ cand_key,
    u64* __restrict__ keptkeys, u32* __restrict__ keptpos,
    u32* __restrict__ keptcnt) {
  int bl = blockIdx.x;
  int lane = threadIdx.x;
  extern __shared__ char smem[];
  u64* lmask = (u64*)smem;                       // [LSEG*LCH] = 128 KB
  u32* rnzL  = (u32*)(smem + (size_t)LSEG * LCH * 8);  // [LSEG] = 4 KB
  // zero the matrix (16B LDS writes), copy rnzl (coalesced global)
  ulonglong2 z2; z2.x = 0ull; z2.y = 0ull;
  ulonglong2* lm2 = (ulonglong2*)lmask;
  for (int t = lane; t < LSEG * LCH / 2; t += 64) lm2[t] = z2;
  for (int t = lane; t < LSEG; t += 64) rnzL[t] = rnzl[(size_t)bl * LSEG + t];
  u64 vword = (lane < LCH) ? vmaskl[bl * LCH + lane] : 0ull;
  __syncthreads();
  // scatter triplets (unique (row,word) targets — order-independent)
  u32 tc = tripcnt[bl * 16];
  for (u32 t = lane; t < tc; t += 64) {
    ulonglong2 e = trip[(size_t)bl * TRIPCAP + t];
    lmask[(u32)e.y] = e.x;
  }
  __syncthreads();
  u64 supp = 0ull;   // lane w<16 holds suppression word w
  u64 keep = 0ull;   // lane w<16 holds keep word w
  for (int W = 0; W < LCH; ++W) {
    int c0 = W << 6;
    // independent LDS reads issue early; latency hides under the shfl chain
    u32 rzW = rnzL[c0 + lane];                      // rnz of row c0+lane
    u64 dchW = lmask[(size_t)(c0 + lane) * LCH + W];  // diagonal word
    u64 s = __shfl(supp, W);
    u64 v = __shfl(vword, W);
    // greedy resolve: scalar readlane over suppressor rows only
    u64 pending = v & ~s;
    u64 kw = 0ull;
    u64 suppressors = __ballot((dchW & pending) != 0ull) & pending;
    while (pending) {
      u64 sp = pending & suppressors;
      if (!sp) { kw |= pending; break; }
      int q = __builtin_ctzll(sp);
      u64 below = pending & ((1ull << q) - 1ull);
      kw |= below | (1ull << q);
      u64 supq = readlane_u64(dchW, q);
      pending &= ~supq & ~below & ~(1ull << q);
    }
    // sparse apply: kept rows with words beyond W; 4-deep batched LDS reads
    u64 kk = __ballot(((rzW >> W) >> 1) != 0u) & kw;
    bool ld = (lane < LCH);
    u64 acc = 0ull;
    while (kk) {
      int q0 = __builtin_ctzll(kk); kk &= kk - 1ull;
      u64 m0 = ld ? lmask[(size_t)(c0 + q0) * LCH + lane] : 0ull;
      u64 m1 = 0ull, m2 = 0ull, m3 = 0ull;
      if (kk) {
        int q1 = __builtin_ctzll(kk); kk &= kk - 1ull;
        m1 = ld ? lmask[(size_t)(c0 + q1) * LCH + lane] : 0ull;
      }
      if (kk) {
        int q2 = __builtin_ctzll(kk); kk &= kk - 1ull;
        m2 = ld ? lmask[(size_t)(c0 + q2) * LCH + lane] : 0ull;
      }
      if (kk) {
        int q3 = __builtin_ctzll(kk); kk &= kk - 1ull;
        m3 = ld ? lmask[(size_t)(c0 + q3) * LCH + lane] : 0ull;
      }
      acc |= (m0 | m1) | (m2 | m3);
    }
    supp |= acc;
    if (lane == W) keep = kw;
  }
  // compact kept: prefix popcount across lanes
  int pc = __popcll(keep);
  int incl = pc;
  for (int d = 1; d < 64; d <<= 1) {
    int t = __shfl_up(incl, d);
    if (lane >= d) incl += t;
  }
  int r = incl - pc;
  u64 kk = keep;
  while (kk) {
    int bit = __builtin_ctzll(kk);
    kk &= kk - 1ull;
    int p = lane * 64 + bit;
    keptkeys[(size_t)bl * LSEG + r] = cand_key[(size_t)bl * LSEG + p];
    keptpos[(size_t)bl * LSEG + r] = (u32)p;
    ++r;
  }
  if (lane == 63) keptcnt[bl] = (u32)incl;
}

// ---------------- K out: global rank via cross-level binary search -------------
__global__ __launch_bounds__(1024) void k_out(
    const u64* __restrict__ keptkeys, const u32* __restrict__ keptpos,
    const u32* __restrict__ keptcnt, const float4* __restrict__ sbox,
    const float* __restrict__ score, float* __restrict__ out) {
  int bl = blockIdx.x;
  int b = bl >> 2;
  int l = bl & 3;
  int r = threadIdx.x;
  u32 cnt = keptcnt[bl];
  if (r >= (int)cnt) return;
  u64 K = keptkeys[(size_t)bl * LSEG + r];
  int rank = r;
#pragma unroll
  for (int dl = 0; dl < 4; ++dl) {
    if (dl == l) continue;
    int obl = (b << 2) | dl;
    const u64* arr = keptkeys + (size_t)obl * LSEG;
    int lo = 0, hi = (int)keptcnt[obl];
    while (lo < hi) {
      int mid = (lo + hi) >> 1;
      if (arr[mid] > K) lo = mid + 1; else hi = mid;
    }
    rank += lo;
  }
  if (rank < POSTN) {
    u32 p = keptpos[(size_t)bl * LSEG + r];
    float4 bx = sbox[(size_t)bl * LSEG + p];
    size_t ob = ((size_t)b * POSTN + (size_t)rank) * 4;
    out[ob + 0] = bx.x;
    out[ob + 1] = bx.y;
    out[ob + 2] = bx.z;
    out[ob + 3] = bx.w;
    out[(size_t)NB * POSTN * 4 + (size_t)b * POSTN + (size_t)rank] =
        score[(size_t)bl * LSEG + p];
  }
}

extern "C" void kernel_launch(void* const* d_in, const int* in_sizes, int n_in,
                              void* d_out, int out_size, void* d_ws, size_t ws_size,
                              hipStream_t stream) {
  // setup_inputs dict order: cls0, reg0, cls1, reg1, cls2, reg2, cls3, reg3, anchors
  const float* cls0 = (const float*)d_in[0];
  const float* reg0 = (const float*)d_in[1];
  const float* cls1 = (const float*)d_in[2];
  const float* reg1 = (const float*)d_in[3];
  const float* cls2 = (const float*)d_in[4];
  const float* reg2 = (const float*)d_in[5];
  const float* cls3 = (const float*)d_in[6];
  const float* reg3 = (const float*)d_in[7];
  const float* anchors = (const float*)d_in[8];
  float* out = (float*)d_out;

  char* ws = (char*)d_ws;
  size_t off = 0;
  auto take = [&](size_t bytes) -> void* {
    off = (off + 255) & ~(size_t)255;
    void* p = ws + off;
    off += bytes;
    return p;
  };
  ulonglong2* trip = (ulonglong2*)take((size_t)64 * TRIPCAP * 16); // 16.8 MB
  u64* sidebuf   = (u64*)take((size_t)64 * SIDECAP * 8);     // 2 MB
  u32* rnzl      = (u32*)take((size_t)64 * LSEG * 4);        // 256 KB
  u64* cand_key  = (u64*)take((size_t)NB * 4096 * 8);        // 512 KB
  float4* sbox   = (float4*)take((size_t)64 * LSEG * 16);    // 1 MB
  float4* boffA  = (float4*)take((size_t)64 * LSEG * 16);    // 1 MB
  float* area    = (float*)take((size_t)64 * LSEG * 4);
  float* score   = (float*)take((size_t)64 * LSEG * 4);
  u64* vmaskl    = (u64*)take((size_t)64 * LCH * 8);
  u64* keptkeys  = (u64*)take((size_t)64 * LSEG * 8);        // 512 KB
  u32* keptpos   = (u32*)take((size_t)64 * LSEG * 4);        // 256 KB
  u32* keptcnt   = (u32*)take((size_t)64 * 4);
  u32* hist1     = (u32*)take((size_t)64 * 2048 * 4);
  u32* counters  = (u32*)take((size_t)64 * 16 * 4);          // 64B-padded
  u32* sidecnt   = (u32*)take((size_t)64 * 16 * 4);          // 64B-padded
  u32* tripcnt   = (u32*)take((size_t)64 * 16 * 4);          // 64B-padded
  u32* state_known = (u32*)take((size_t)64 * 4);
  u32* state_kneed = (u32*)take((size_t)64 * 4);
  (void)ws_size; (void)in_sizes; (void)n_in; (void)out_size;

  k_zero<<<512, 256, 0, stream>>>(out, counters, sidecnt, tripcnt, cand_key,
                                  hist1, state_known, state_kneed);
  k_hist1<<<192, 1024, 0, stream>>>(cls0, cls1, cls2, cls3, hist1);
  k_pick1<<<64, 1024, 0, stream>>>(hist1, state_known, state_kneed);
  k_collect<<<192, 1024, 0, stream>>>(cls0, cls1, cls2, cls3, state_known,
                                      reg0, reg1, reg2, reg3, anchors,
                                      counters, sidecnt, sidebuf, cand_key);
  k_finalize<<<64, 1024, 0, stream>>>(sidebuf, sidecnt, counters, state_kneed,
                                      reg0, reg1, reg2, reg3, anchors,
                                      cand_key);
  k_sortdec<<<64, 1024, 0, stream>>>(cand_key, reg0, reg1, reg2, reg3,
                                     anchors, sbox, boffA, area, score,
                                     vmaskl);
  k_maskl<<<64 * 64, 256, 0, stream>>>(boffA, area, trip, tripcnt, rnzl);
  // dynamic LDS: 128 KB mask matrix + 4 KB rnz copy = 135168 B (<= 160 KB/CU)
  k_nmsl<<<64, 64, 135168, stream>>>(trip, tripcnt, rnzl, vmaskl, cand_key,
                                     keptkeys, keptpos, keptcnt);
  k_out<<<64, 1024, 0, stream>>>(keptkeys, keptpos, keptcnt, sbox, score, out);
}

// Round 12
// 152.647 us; speedup vs baseline: 10.0034x; 1.1058x over previous
//
#include <hip/hip_runtime.h>
#include <cstdint>
#include <cstddef>

typedef uint32_t u32;
typedef uint64_t u64;

#define NB 16
#define POSTN 1000
#define PREN 1000
#define LSEG 1024     // per-level segment (1000 candidates + 24 pad)
#define LCH 16        // chunks of 64 per level
#define SIDECAP 4096  // per-task boundary-bucket buffer
#define BSIDE 2048    // per-block LDS side list
#define TRIPCAP (LSEG * LCH)  // per-task triplet capacity = full matrix
#define NPAIR 160     // triangular (chunk,g) pairs: 16+32+48+64

__constant__ int c_N[4]    = {120000, 30000, 7500, 1875};
__constant__ int c_OFF[4]  = {0, 120000, 150000, 157500};
__constant__ int c_HW[4]   = {40000, 10000, 2500, 625};
__constant__ int c_W[4]    = {200, 100, 50, 25};
__constant__ int c_BASE[4] = {0, 1024, 2048, 3072};

__device__ __forceinline__ u32 ord_bits(float f) {
  u32 u = __float_as_uint(f);
  return (u & 0x80000000u) ? ~u : (u | 0x80000000u);
}
__device__ __forceinline__ float inv_ord(u32 o) {
  u32 bits = (o & 0x80000000u) ? (o ^ 0x80000000u) : ~o;
  return __uint_as_float(bits);
}
__device__ __forceinline__ u64 readlane_u64(u64 v, int l) {
  u32 lo = (u32)__builtin_amdgcn_readlane((int)(u32)v, l);
  u32 hi = (u32)__builtin_amdgcn_readlane((int)(u32)(v >> 32), l);
  return (((u64)hi) << 32) | (u64)lo;
}

// 192-block slice map: 8 blocks/task lvl0, 2/task lvl1, 1/task lvl2+3
__device__ __forceinline__ void slice_map(int bid, int& lvl, int& b, int& e0,
                                          int& nsl) {
  if (bid < 128)      { lvl = 0; b = bid >> 3; e0 = (bid & 7) * 15000; nsl = 15000; }
  else if (bid < 160) { lvl = 1; int t = bid - 128; b = t >> 1; e0 = (t & 1) * 15000; nsl = 15000; }
  else if (bid < 176) { lvl = 2; b = bid - 160; e0 = 0; nsl = 7500; }
  else                { lvl = 3; b = bid - 176; e0 = 0; nsl = 1875; }
}

struct DecBox { float x1, y1, x2, y2; int lvl; bool valid; };

__device__ DecBox decode_box(u32 gid, int b,
    const float* __restrict__ reg0, const float* __restrict__ reg1,
    const float* __restrict__ reg2, const float* __restrict__ reg3,
    const float* __restrict__ anchors) {
  int lvl = (gid < 120000u) ? 0 : (gid < 150000u) ? 1 : (gid < 157500u) ? 2 : 3;
  int local = (int)gid - c_OFF[lvl];
  int a = local % 3;
  int cell = local / 3;
  int w = c_W[lvl];
  int hw = c_HW[lvl];
  int y = cell / w;
  int x = cell - y * w;
  const float* reg = (lvl == 0) ? reg0 : (lvl == 1) ? reg1 : (lvl == 2) ? reg2 : reg3;
  size_t base = ((size_t)(b * 12 + a * 4) * (size_t)w + (size_t)y) * (size_t)w + (size_t)x;
  const float CLIPV = 4.135166556742356f; // log(1000/16) as f32
  float dx = reg[base];
  float dy = reg[base + (size_t)hw];
  float dwv = fminf(reg[base + 2 * (size_t)hw], CLIPV);
  float dhv = fminf(reg[base + 3 * (size_t)hw], CLIPV);
  float a0 = anchors[(size_t)gid * 4 + 0];
  float a1 = anchors[(size_t)gid * 4 + 1];
  float a2 = anchors[(size_t)gid * 4 + 2];
  float a3 = anchors[(size_t)gid * 4 + 3];
  float wa = __fsub_rn(a2, a0);
  float ha = __fsub_rn(a3, a1);
  float cxa = __fadd_rn(a0, __fmul_rn(0.5f, wa));
  float cya = __fadd_rn(a1, __fmul_rn(0.5f, ha));
  float pcx = __fadd_rn(__fmul_rn(dx, wa), cxa);
  float pcy = __fadd_rn(__fmul_rn(dy, ha), cya);
  float pw = __fmul_rn(expf(dwv), wa);
  float ph = __fmul_rn(expf(dhv), ha);
  float x1 = __fsub_rn(pcx, __fmul_rn(0.5f, pw));
  float y1 = __fsub_rn(pcy, __fmul_rn(0.5f, ph));
  float x2 = __fadd_rn(pcx, __fmul_rn(0.5f, pw));
  float y2 = __fadd_rn(pcy, __fmul_rn(0.5f, ph));
  x1 = fminf(fmaxf(x1, 0.0f), 800.0f);
  y1 = fminf(fmaxf(y1, 0.0f), 800.0f);
  x2 = fminf(fmaxf(x2, 0.0f), 800.0f);
  y2 = fminf(fmaxf(y2, 0.0f), 800.0f);
  DecBox r;
  r.x1 = x1; r.y1 = y1; r.x2 = x2; r.y2 = y2; r.lvl = lvl;
  r.valid = (__fsub_rn(x2, x1) >= 1.0f) && (__fsub_rn(y2, y1) >= 1.0f);
  return r;
}

// ---------------- K0: zero state ----------------------------------------------
__global__ void k_zero(float* __restrict__ out, u32* __restrict__ counters,
                       u32* __restrict__ sidecnt, u32* __restrict__ tripcnt,
                       u64* __restrict__ cand_key, u32* __restrict__ rnzl,
                       u32* __restrict__ hist1, u32* __restrict__ state_known,
                       u32* __restrict__ state_kneed) {
  int i = blockIdx.x * blockDim.x + threadIdx.x;
  if (i < NB * POSTN * 5) out[i] = 0.0f;
  if (i < NB * 4096) cand_key[i] = 0ull;
  if (i < 64 * LSEG) rnzl[i] = 0u;
  if (i < 64 * 2048) hist1[i] = 0u;
  if (i < 64 * 16) { counters[i] = 0u; sidecnt[i] = 0u; tripcnt[i] = 0u; }
  if (i < 64) { state_known[i] = 0u; state_kneed[i] = (u32)PREN; }
}

// ---------------- K1: top-11-bit histogram straight from cls (float4) ----------
__global__ __launch_bounds__(1024) void k_hist1(
    const float* __restrict__ cls0, const float* __restrict__ cls1,
    const float* __restrict__ cls2, const float* __restrict__ cls3,
    u32* __restrict__ hist1) {
  int lvl, b, e0, nsl;
  slice_map(blockIdx.x, lvl, b, e0, nsl);
  const float* cls = (lvl == 0) ? cls0 : (lvl == 1) ? cls1 : (lvl == 2) ? cls2 : cls3;
  const float* cp = cls + (size_t)b * c_N[lvl];
  int tid = threadIdx.x;
  __shared__ u32 h[2048];
  for (int t = tid; t < 2048; t += 1024) h[t] = 0u;
  __syncthreads();
  if (lvl != 3) {
    // base offsets are 16B-aligned for lvl 0..2 (all multiples of 4 elems)
    const float4* cp4 = (const float4*)(cp + e0);
    int n4 = nsl >> 2;
    for (int t = tid; t < n4; t += 1024) {
      float4 v = cp4[t];
      atomicAdd(&h[ord_bits(v.x) >> 21], 1u);
      atomicAdd(&h[ord_bits(v.y) >> 21], 1u);
      atomicAdd(&h[ord_bits(v.z) >> 21], 1u);
      atomicAdd(&h[ord_bits(v.w) >> 21], 1u);
    }
  } else {
    for (int e = e0 + tid; e < e0 + nsl; e += 1024)
      atomicAdd(&h[ord_bits(cp[e]) >> 21], 1u);
  }
  __syncthreads();
  int task = lvl * 16 + b;
  for (int t = tid; t < 2048; t += 1024) {
    u32 v = h[t];
    if (v) atomicAdd(&hist1[task * 2048 + t], v);
  }
}

// ---------------- K2: pick boundary bucket (suffix scan) -----------------------
__global__ __launch_bounds__(1024) void k_pick1(
    const u32* __restrict__ hist1, u32* __restrict__ state_known,
    u32* __restrict__ state_kneed) {
  int task = blockIdx.x;
  int tid = threadIdx.x;
  __shared__ u32 A[2048], Bb[2048];
  __shared__ int sh_t;
  __shared__ u32 sh_above;
  u32 kneed = (u32)PREN;
  for (int t = tid; t < 2048; t += 1024) A[t] = hist1[task * 2048 + t];
  __syncthreads();
  u32* cur = A;
  u32* nxt = Bb;
  for (int off2 = 1; off2 < 2048; off2 <<= 1) {
    for (int t = tid; t < 2048; t += 1024)
      nxt[t] = cur[t] + ((t + off2 < 2048) ? cur[t + off2] : 0u);
    __syncthreads();
    u32* tmp = cur; cur = nxt; nxt = tmp;
  }
  for (int t = tid; t < 2048; t += 1024) {
    u32 s = cur[t];
    u32 above = (t + 1 < 2048) ? cur[t + 1] : 0u;
    if (s >= kneed && above < kneed) { sh_t = t; sh_above = above; }
  }
  __syncthreads();
  if (tid == 0) {
    state_known[task] = (u32)sh_t << 21;
    state_kneed[task] = kneed - sh_above;   // how many to take from boundary
  }
}

// ---------------- K3: collect — block-local staging, 1 atomic per block --------
__global__ __launch_bounds__(1024) void k_collect(
    const float* __restrict__ cls0, const float* __restrict__ cls1,
    const float* __restrict__ cls2, const float* __restrict__ cls3,
    const u32* __restrict__ state_known,
    const float* __restrict__ reg0, const float* __restrict__ reg1,
    const float* __restrict__ reg2, const float* __restrict__ reg3,
    const float* __restrict__ anchors, u32* __restrict__ counters,
    u32* __restrict__ sidecnt, u64* __restrict__ sidebuf,
    u64* __restrict__ cand_key) {
  int lvl, b, e0, nsl;
  slice_map(blockIdx.x, lvl, b, e0, nsl);
  int task = lvl * 16 + b;
  u32 tb = state_known[task] >> 21;
  const float* cls = (lvl == 0) ? cls0 : (lvl == 1) ? cls1 : (lvl == 2) ? cls2 : cls3;
  const float* cp = cls + (size_t)b * c_N[lvl];
  int tid = threadIdx.x;
  __shared__ u32 ldef[1024];
  __shared__ u32 lside[BSIDE];
  __shared__ u32 cdef, cside, bdef, bside;
  if (tid == 0) { cdef = 0u; cside = 0u; }
  __syncthreads();
  if (lvl != 3) {
    const float4* cp4 = (const float4*)(cp + e0);
    int n4 = nsl >> 2;
    for (int t = tid; t < n4; t += 1024) {
      float4 v4 = cp4[t];
      int ebase = e0 + (t << 2);
#pragma unroll
      for (int c = 0; c < 4; ++c) {
        float f = (c == 0) ? v4.x : (c == 1) ? v4.y : (c == 2) ? v4.z : v4.w;
        u32 bk = ord_bits(f) >> 21;
        if (bk < tb) continue;
        if (bk > tb) {
          u32 i = atomicAdd(&cdef, 1u);
          if (i < 1024u) ldef[i] = (u32)(ebase + c);
        } else {
          u32 i = atomicAdd(&cside, 1u);
          if (i < (u32)BSIDE) lside[i] = (u32)(ebase + c);
        }
      }
    }
  } else {
    for (int e = e0 + tid; e < e0 + nsl; e += 1024) {
      u32 bk = ord_bits(cp[e]) >> 21;
      if (bk < tb) continue;
      if (bk > tb) {
        u32 i = atomicAdd(&cdef, 1u);
        if (i < 1024u) ldef[i] = (u32)e;
      } else {
        u32 i = atomicAdd(&cside, 1u);
        if (i < (u32)BSIDE) lside[i] = (u32)e;
      }
    }
  }
  __syncthreads();
  if (tid == 0) bdef = atomicAdd(&counters[task * 16], min(cdef, 1024u));
  if (tid == 1) bside = atomicAdd(&sidecnt[task * 16], min(cside, (u32)BSIDE));
  __syncthreads();
  int hw = c_HW[lvl], off = c_OFF[lvl];
  u32 nd = min(cdef, 1024u);
  for (u32 i = tid; i < nd; i += 1024) {
    int e = (int)ldef[i];
    int a = e / hw;
    int cell = e - a * hw;
    u32 gid = (u32)(off + cell * 3 + a);
    u64 key = ((u64)ord_bits(cp[e]) << 32) | (u32)(~gid);
    DecBox bx = decode_box(gid, b, reg0, reg1, reg2, reg3, anchors);
    u64 skey = bx.valid ? key : (key & 0xFFFFFFFFull);
    u32 slot = bdef + i;
    if (slot < (u32)PREN)
      cand_key[(size_t)b * 4096 + c_BASE[lvl] + slot] = skey;
  }
  u32 ns = min(cside, (u32)BSIDE);
  for (u32 i = tid; i < ns; i += 1024) {
    int e = (int)lside[i];
    int a = e / hw;
    int cell = e - a * hw;
    u32 gid = (u32)(off + cell * 3 + a);
    u64 key = ((u64)ord_bits(cp[e]) << 32) | (u32)(~gid);
    u32 slot = bside + i;
    if (slot < (u32)SIDECAP) sidebuf[(size_t)task * SIDECAP + slot] = key;
  }
}

// ---------------- K4: finalize — sort boundary bucket (np2), append kneed ------
__global__ __launch_bounds__(1024) void k_finalize(
    const u64* __restrict__ sidebuf, const u32* __restrict__ sidecnt,
    const u32* __restrict__ counters, const u32* __restrict__ state_kneed,
    const float* __restrict__ reg0, const float* __restrict__ reg1,
    const float* __restrict__ reg2, const float* __restrict__ reg3,
    const float* __restrict__ anchors, u64* __restrict__ cand_key) {
  int task = blockIdx.x;
  int lvl = task >> 4;
  int b = task & 15;
  int tid = threadIdx.x;
  u32 nside = min(sidecnt[task * 16], (u32)SIDECAP);
  u32 kneed = state_kneed[task];
  u32 nab = counters[task * 16];
  u32 np2 = 64;
  while (np2 < nside) np2 <<= 1;   // next pow2 >= nside (uniform)
  __shared__ u64 sk[SIDECAP];
  for (u32 i = tid; i < np2; i += 1024)
    sk[i] = (i < nside) ? sidebuf[(size_t)task * SIDECAP + i] : 0ull;
  __syncthreads();
  for (u32 k = 2; k <= np2; k <<= 1) {
    for (u32 j = k >> 1; j > 0; j >>= 1) {
      for (u32 t = tid; t < np2 / 2; t += 1024) {
        u32 i = 2u * t - (t & (j - 1u));
        u32 l2 = i | j;
        u64 av = sk[i], bv = sk[l2];
        bool up = ((i & k) == 0u);
        if (up ? (av < bv) : (av > bv)) { sk[i] = bv; sk[l2] = av; }
      }
      __syncthreads();
    }
  }
  if (tid < (int)kneed) {
    u64 key = sk[tid];
    u32 gid = ~((u32)key);
    DecBox bx = decode_box(gid, b, reg0, reg1, reg2, reg3, anchors);
    u64 skey = bx.valid ? key : (key & 0xFFFFFFFFull);
    u32 slot = nab + (u32)tid;
    if (slot < (u32)PREN)
      cand_key[(size_t)b * 4096 + c_BASE[lvl] + slot] = skey;
  }
}

// ---------------- K sortdec: fused per-(image,level) sort + decode -------------
__global__ __launch_bounds__(1024) void k_sortdec(
    u64* __restrict__ cand_key,
    const float* __restrict__ reg0, const float* __restrict__ reg1,
    const float* __restrict__ reg2, const float* __restrict__ reg3,
    const float* __restrict__ anchors,
    float4* __restrict__ sbox, float4* __restrict__ boffA,
    float* __restrict__ area, float* __restrict__ score,
    u64* __restrict__ vmaskl) {
  int bl = blockIdx.x;                 // b*4 + lvl
  int b = bl >> 2;
  int tid = threadIdx.x;
  __shared__ u64 sk[LSEG];
  sk[tid] = cand_key[(size_t)bl * LSEG + tid];
  __syncthreads();
  for (u32 k = 2; k <= LSEG; k <<= 1) {
    for (u32 j = k >> 1; j > 0; j >>= 1) {
      if (tid < LSEG / 2) {
        u32 t = (u32)tid;
        u32 i = 2u * t - (t & (j - 1u));
        u32 l2 = i | j;
        u64 av = sk[i], bv = sk[l2];
        bool up = ((i & k) == 0u);
        if (up ? (av < bv) : (av > bv)) { sk[i] = bv; sk[l2] = av; }
      }
      __syncthreads();
    }
  }
  // write back sorted keys (k_nmsl reads them for kept compaction)
  u64 key = sk[tid];
  cand_key[(size_t)bl * LSEG + tid] = key;
  // decode payloads
  float4 bx4 = make_float4(0.f, 0.f, 0.f, 0.f);
  float4 bo4 = make_float4(0.f, 0.f, 0.f, 0.f);
  float ar = 0.f, sc = 0.f;
  bool vflag = false;
  if (key != 0ull) {
    u32 gid = ~((u32)key);
    vflag = (key >> 32) != 0ull;
    DecBox bx = decode_box(gid, b, reg0, reg1, reg2, reg3, anchors);
    bx4 = make_float4(bx.x1, bx.y1, bx.x2, bx.y2);
    float offv = __fmul_rn((float)bx.lvl, 801.0f);
    bo4 = make_float4(__fadd_rn(bx.x1, offv), __fadd_rn(bx.y1, offv),
                      __fadd_rn(bx.x2, offv), __fadd_rn(bx.y2, offv));
    ar = __fmul_rn(__fsub_rn(bo4.z, bo4.x), __fsub_rn(bo4.w, bo4.y));
    if (vflag) {
      float logit = inv_ord((u32)(key >> 32));
      sc = 1.0f / (1.0f + expf(-logit));
    }
  }
  size_t gi = (size_t)bl * LSEG + tid;
  sbox[gi] = bx4;
  boffA[gi] = bo4;
  area[gi] = ar;
  score[gi] = sc;
  u64 bal = __ballot(vflag ? 1 : 0);
  if ((tid & 63) == 0) vmaskl[bl * LCH + (tid >> 6)] = bal;
}

// ---------------- K maskl: triangular-mapped IoU → compact triplet list --------
// RN(inter/uni) > 0.7f  <=>  inter/uni >= B, B = 0.7f + 2^-25 (tie rounds up).
// B*(double)uni is exact (25x24 bits <= 53); comparison is bit-equivalent.
#define RPB 16
__global__ __launch_bounds__(256) void k_maskl(
    const float4* __restrict__ boffA, const float* __restrict__ area,
    ulonglong2* __restrict__ trip, u32* __restrict__ tripcnt,
    u32* __restrict__ rnzl) {
  const double Bd = 0x1.6666661p-1;   // 0.7000000178813934326171875
  int bg = blockIdx.x;
  int bl = bg / NPAIR;
  int p = bg - bl * NPAIR;
  // triangular (chunk,g) pairs: chunk c covers row-groups g < (c+1)*16
  int chunk, g;
  if (p < 16)      { chunk = 0; g = p; }
  else if (p < 48) { chunk = 1; g = p - 16; }
  else if (p < 96) { chunk = 2; g = p - 48; }
  else             { chunk = 3; g = p - 96; }
  int row0 = g * RPB;
  int tid = threadIdx.x;
  int wave = tid >> 6;
  int lane = tid & 63;
  __shared__ float4 rb[RPB];
  __shared__ float ra[RPB];
  __shared__ ulonglong2 stage[RPB * 4];   // max 64 nonzero words per block
  __shared__ u32 scount, sbase;
  if (tid == 0) scount = 0u;
  if (tid < RPB) {
    rb[tid] = boffA[(size_t)bl * LSEG + row0 + tid];
    ra[tid] = area[(size_t)bl * LSEG + row0 + tid];
  }
  __syncthreads();
  int wword = chunk * 4 + wave;
  int wmaxj = chunk * 256 + wave * 64 + 63;   // this wave's max column
  int j = chunk * 256 + tid;
  float4 cb = boffA[(size_t)bl * LSEG + j];
  float ca = area[(size_t)bl * LSEG + j];
  if (wmaxj > row0) {
#pragma unroll
    for (int rr = 0; rr < RPB; ++rr) {
      int i = row0 + rr;
      if (wmaxj <= i) continue;
      float4 rbb = rb[rr];
      float ria = ra[rr];
      float ix1 = fmaxf(cb.x, rbb.x);
      float iy1 = fmaxf(cb.y, rbb.y);
      float ix2 = fminf(cb.z, rbb.z);
      float iy2 = fminf(cb.w, rbb.w);
      float inter = __fmul_rn(fmaxf(__fsub_rn(ix2, ix1), 0.0f),
                              fmaxf(__fsub_rn(iy2, iy1), 0.0f));
      float uni = __fsub_rn(__fadd_rn(ca, ria), inter);
      bool pred = (j > i) && (inter > 0.0f) &&
                  ((double)inter >= Bd * (double)uni);
      u64 bal = __ballot(pred ? 1 : 0);
      if (lane == 0 && bal) {
        u32 sidx = atomicAdd(&scount, 1u);
        ulonglong2 e;
        e.x = bal;
        e.y = (u64)(u32)(i * LCH + wword);
        stage[sidx] = e;
        atomicOr(&rnzl[(size_t)bl * LSEG + i], 1u << wword);
      }
    }
  }
  __syncthreads();
  if (tid == 0 && scount) sbase = atomicAdd(&tripcnt[bl * 16], scount);
  __syncthreads();
  for (u32 t = tid; t < scount; t += 256)
    trip[(size_t)bl * TRIPCAP + sbase + t] = stage[t];
}

// ---------------- K nmsl: greedy NMS — full mask matrix in LDS -----------------
__global__ __launch_bounds__(64) void k_nmsl(
    const ulonglong2* __restrict__ trip, const u32* __restrict__ tripcnt,
    const u32* __restrict__ rnzl, const u64* __restrict__ vmaskl,
    const u64* __restrict__ cand_key,
    u64* __restrict__ keptkeys, u32* __restrict__ keptpos,
    u32* __restrict__ keptcnt) {
  int bl = blockIdx.x;
  int lane = threadIdx.x;
  extern __shared__ char smem[];
  u64* lmask = (u64*)smem;                       // [LSEG*LCH] = 128 KB
  u32* rnzL  = (u32*)(smem + (size_t)LSEG * LCH * 8);  // [LSEG] = 4 KB
  // zero the matrix (16B LDS writes), copy rnzl (coalesced global)
  ulonglong2 z2; z2.x = 0ull; z2.y = 0ull;
  ulonglong2* lm2 = (ulonglong2*)lmask;
  for (int t = lane; t < LSEG * LCH / 2; t += 64) lm2[t] = z2;
  for (int t = lane; t < LSEG; t += 64) rnzL[t] = rnzl[(size_t)bl * LSEG + t];
  u64 vword = (lane < LCH) ? vmaskl[bl * LCH + lane] : 0ull;
  __syncthreads();
  // scatter triplets (unique (row,word) targets — order-independent)
  u32 tc = tripcnt[bl * 16];
  for (u32 t = lane; t < tc; t += 64) {
    ulonglong2 e = trip[(size_t)bl * TRIPCAP + t];
    lmask[(u32)e.y] = e.x;
  }
  __syncthreads();
  u64 supp = 0ull;   // lane w<16 holds suppression word w
  u64 keep = 0ull;   // lane w<16 holds keep word w
  for (int W = 0; W < LCH; ++W) {
    int c0 = W << 6;
    // independent LDS reads issue early; latency hides under the shfl chain
    u32 rzW = rnzL[c0 + lane];                      // rnz of row c0+lane
    u64 dchW = lmask[(size_t)(c0 + lane) * LCH + W];  // diagonal word
    u64 s = __shfl(supp, W);
    u64 v = __shfl(vword, W);
    // greedy resolve: scalar readlane over suppressor rows only
    u64 pending = v & ~s;
    u64 kw = 0ull;
    u64 suppressors = __ballot((dchW & pending) != 0ull) & pending;
    while (pending) {
      u64 sp = pending & suppressors;
      if (!sp) { kw |= pending; break; }
      int q = __builtin_ctzll(sp);
      u64 below = pending & ((1ull << q) - 1ull);
      kw |= below | (1ull << q);
      u64 supq = readlane_u64(dchW, q);
      pending &= ~supq & ~below & ~(1ull << q);
    }
    // sparse apply: kept rows with words beyond W; 4-deep batched LDS reads
    u64 kk = __ballot(((rzW >> W) >> 1) != 0u) & kw;
    bool ld = (lane < LCH);
    u64 acc = 0ull;
    while (kk) {
      int q0 = __builtin_ctzll(kk); kk &= kk - 1ull;
      u64 m0 = ld ? lmask[(size_t)(c0 + q0) * LCH + lane] : 0ull;
      u64 m1 = 0ull, m2 = 0ull, m3 = 0ull;
      if (kk) {
        int q1 = __builtin_ctzll(kk); kk &= kk - 1ull;
        m1 = ld ? lmask[(size_t)(c0 + q1) * LCH + lane] : 0ull;
      }
      if (kk) {
        int q2 = __builtin_ctzll(kk); kk &= kk - 1ull;
        m2 = ld ? lmask[(size_t)(c0 + q2) * LCH + lane] : 0ull;
      }
      if (kk) {
        int q3 = __builtin_ctzll(kk); kk &= kk - 1ull;
        m3 = ld ? lmask[(size_t)(c0 + q3) * LCH + lane] : 0ull;
      }
      acc |= (m0 | m1) | (m2 | m3);
    }
    supp |= acc;
    if (lane == W) keep = kw;
  }
  // compact kept: prefix popcount across lanes
  int pc = __popcll(keep);
  int incl = pc;
  for (int d = 1; d < 64; d <<= 1) {
    int t = __shfl_up(incl, d);
    if (lane >= d) incl += t;
  }
  int r = incl - pc;
  u64 kk = keep;
  while (kk) {
    int bit = __builtin_ctzll(kk);
    kk &= kk - 1ull;
    int p = lane * 64 + bit;
    keptkeys[(size_t)bl * LSEG + r] = cand_key[(size_t)bl * LSEG + p];
    keptpos[(size_t)bl * LSEG + r] = (u32)p;
    ++r;
  }
  if (lane == 63) keptcnt[bl] = (u32)incl;
}

// ---------------- K out: global rank via cross-level binary search -------------
__global__ __launch_bounds__(1024) void k_out(
    const u64* __restrict__ keptkeys, const u32* __restrict__ keptpos,
    const u32* __restrict__ keptcnt, const float4* __restrict__ sbox,
    const float* __restrict__ score, float* __restrict__ out) {
  int bl = blockIdx.x;
  int b = bl >> 2;
  int l = bl & 3;
  int r = threadIdx.x;
  u32 cnt = keptcnt[bl];
  if (r >= (int)cnt) return;
  u64 K = keptkeys[(size_t)bl * LSEG + r];
  int rank = r;
#pragma unroll
  for (int dl = 0; dl < 4; ++dl) {
    if (dl == l) continue;
    int obl = (b << 2) | dl;
    const u64* arr = keptkeys + (size_t)obl * LSEG;
    int lo = 0, hi = (int)keptcnt[obl];
    while (lo < hi) {
      int mid = (lo + hi) >> 1;
      if (arr[mid] > K) lo = mid + 1; else hi = mid;
    }
    rank += lo;
  }
  if (rank < POSTN) {
    u32 p = keptpos[(size_t)bl * LSEG + r];
    float4 bx = sbox[(size_t)bl * LSEG + p];
    size_t ob = ((size_t)b * POSTN + (size_t)rank) * 4;
    out[ob + 0] = bx.x;
    out[ob + 1] = bx.y;
    out[ob + 2] = bx.z;
    out[ob + 3] = bx.w;
    out[(size_t)NB * POSTN * 4 + (size_t)b * POSTN + (size_t)rank] =
        score[(size_t)bl * LSEG + p];
  }
}

extern "C" void kernel_launch(void* const* d_in, const int* in_sizes, int n_in,
                              void* d_out, int out_size, void* d_ws, size_t ws_size,
                              hipStream_t stream) {
  // setup_inputs dict order: cls0, reg0, cls1, reg1, cls2, reg2, cls3, reg3, anchors
  const float* cls0 = (const float*)d_in[0];
  const float* reg0 = (const float*)d_in[1];
  const float* cls1 = (const float*)d_in[2];
  const float* reg1 = (const float*)d_in[3];
  const float* cls2 = (const float*)d_in[4];
  const float* reg2 = (const float*)d_in[5];
  const float* cls3 = (const float*)d_in[6];
  const float* reg3 = (const float*)d_in[7];
  const float* anchors = (const float*)d_in[8];
  float* out = (float*)d_out;

  char* ws = (char*)d_ws;
  size_t off = 0;
  auto take = [&](size_t bytes) -> void* {
    off = (off + 255) & ~(size_t)255;
    void* p = ws + off;
    off += bytes;
    return p;
  };
  ulonglong2* trip = (ulonglong2*)take((size_t)64 * TRIPCAP * 16); // 16.8 MB
  u64* sidebuf   = (u64*)take((size_t)64 * SIDECAP * 8);     // 2 MB
  u32* rnzl      = (u32*)take((size_t)64 * LSEG * 4);        // 256 KB
  u64* cand_key  = (u64*)take((size_t)NB * 4096 * 8);        // 512 KB
  float4* sbox   = (float4*)take((size_t)64 * LSEG * 16);    // 1 MB
  float4* boffA  = (float4*)take((size_t)64 * LSEG * 16);    // 1 MB
  float* area    = (float*)take((size_t)64 * LSEG * 4);
  float* score   = (float*)take((size_t)64 * LSEG * 4);
  u64* vmaskl    = (u64*)take((size_t)64 * LCH * 8);
  u64* keptkeys  = (u64*)take((size_t)64 * LSEG * 8);        // 512 KB
  u32* keptpos   = (u32*)take((size_t)64 * LSEG * 4);        // 256 KB
  u32* keptcnt   = (u32*)take((size_t)64 * 4);
  u32* hist1     = (u32*)take((size_t)64 * 2048 * 4);
  u32* counters  = (u32*)take((size_t)64 * 16 * 4);          // 64B-padded
  u32* sidecnt   = (u32*)take((size_t)64 * 16 * 4);          // 64B-padded
  u32* tripcnt   = (u32*)take((size_t)64 * 16 * 4);          // 64B-padded
  u32* state_known = (u32*)take((size_t)64 * 4);
  u32* state_kneed = (u32*)take((size_t)64 * 4);
  (void)ws_size; (void)in_sizes; (void)n_in; (void)out_size;

  k_zero<<<512, 256, 0, stream>>>(out, counters, sidecnt, tripcnt, cand_key,
                                  rnzl, hist1, state_known, state_kneed);
  k_hist1<<<192, 1024, 0, stream>>>(cls0, cls1, cls2, cls3, hist1);
  k_pick1<<<64, 1024, 0, stream>>>(hist1, state_known, state_kneed);
  k_collect<<<192, 1024, 0, stream>>>(cls0, cls1, cls2, cls3, state_known,
                                      reg0, reg1, reg2, reg3, anchors,
                                      counters, sidecnt, sidebuf, cand_key);
  k_finalize<<<64, 1024, 0, stream>>>(sidebuf, sidecnt, counters, state_kneed,
                                      reg0, reg1, reg2, reg3, anchors,
                                      cand_key);
  k_sortdec<<<64, 1024, 0, stream>>>(cand_key, reg0, reg1, reg2, reg3,
                                     anchors, sbox, boffA, area, score,
                                     vmaskl);
  k_maskl<<<64 * NPAIR, 256, 0, stream>>>(boffA, area, trip, tripcnt, rnzl);
  // dynamic LDS: 128 KB mask matrix + 4 KB rnz copy = 135168 B (<= 160 KB/CU)
  k_nmsl<<<64, 64, 135168, stream>>>(trip, tripcnt, rnzl, vmaskl, cand_key,
                                     keptkeys, keptpos, keptcnt);
  k_out<<<64, 1024, 0, stream>>>(keptkeys, keptpos, keptcnt, sbox, score, out);
}

// Round 13
// 131.725 us; speedup vs baseline: 11.5923x; 1.1588x over previous
//
#include <hip/hip_runtime.h>
#include <cstdint>
#include <cstddef>

typedef uint32_t u32;
typedef uint64_t u64;

#define NB 16
#define POSTN 1000
#define PREN 1000
#define LSEG 1024     // per-level segment (1000 candidates + 24 pad)
#define LCH 16        // chunks of 64 per level
#define SIDECAP 4096  // per-task boundary-bucket buffer
#define BSIDE 2048    // per-block LDS side list
#define TRIPCAP (LSEG * LCH)  // per-task triplet capacity = full matrix
#define NPAIR 160     // triangular (chunk,g) pairs: 16+32+48+64
#define NBUCK 8192    // 13-bit histogram buckets
#define BSHIFT 19     // ord >> BSHIFT = bucket

__constant__ int c_N[4]    = {120000, 30000, 7500, 1875};
__constant__ int c_OFF[4]  = {0, 120000, 150000, 157500};
__constant__ int c_HW[4]   = {40000, 10000, 2500, 625};
__constant__ int c_W[4]    = {200, 100, 50, 25};
__constant__ int c_BASE[4] = {0, 1024, 2048, 3072};

__device__ __forceinline__ u32 ord_bits(float f) {
  u32 u = __float_as_uint(f);
  return (u & 0x80000000u) ? ~u : (u | 0x80000000u);
}
__device__ __forceinline__ float inv_ord(u32 o) {
  u32 bits = (o & 0x80000000u) ? (o ^ 0x80000000u) : ~o;
  return __uint_as_float(bits);
}
__device__ __forceinline__ u64 readlane_u64(u64 v, int l) {
  u32 lo = (u32)__builtin_amdgcn_readlane((int)(u32)v, l);
  u32 hi = (u32)__builtin_amdgcn_readlane((int)(u32)(v >> 32), l);
  return (((u64)hi) << 32) | (u64)lo;
}

// 192-block slice map: 8 blocks/task lvl0, 2/task lvl1, 1/task lvl2+3
__device__ __forceinline__ void slice_map(int bid, int& lvl, int& b, int& e0,
                                          int& nsl) {
  if (bid < 128)      { lvl = 0; b = bid >> 3; e0 = (bid & 7) * 15000; nsl = 15000; }
  else if (bid < 160) { lvl = 1; int t = bid - 128; b = t >> 1; e0 = (t & 1) * 15000; nsl = 15000; }
  else if (bid < 176) { lvl = 2; b = bid - 160; e0 = 0; nsl = 7500; }
  else                { lvl = 3; b = bid - 176; e0 = 0; nsl = 1875; }
}

struct DecBox { float x1, y1, x2, y2; int lvl; bool valid; };

__device__ DecBox decode_box(u32 gid, int b,
    const float* __restrict__ reg0, const float* __restrict__ reg1,
    const float* __restrict__ reg2, const float* __restrict__ reg3,
    const float* __restrict__ anchors) {
  int lvl = (gid < 120000u) ? 0 : (gid < 150000u) ? 1 : (gid < 157500u) ? 2 : 3;
  int local = (int)gid - c_OFF[lvl];
  int a = local % 3;
  int cell = local / 3;
  int w = c_W[lvl];
  int hw = c_HW[lvl];
  int y = cell / w;
  int x = cell - y * w;
  const float* reg = (lvl == 0) ? reg0 : (lvl == 1) ? reg1 : (lvl == 2) ? reg2 : reg3;
  size_t base = ((size_t)(b * 12 + a * 4) * (size_t)w + (size_t)y) * (size_t)w + (size_t)x;
  const float CLIPV = 4.135166556742356f; // log(1000/16) as f32
  float dx = reg[base];
  float dy = reg[base + (size_t)hw];
  float dwv = fminf(reg[base + 2 * (size_t)hw], CLIPV);
  float dhv = fminf(reg[base + 3 * (size_t)hw], CLIPV);
  float a0 = anchors[(size_t)gid * 4 + 0];
  float a1 = anchors[(size_t)gid * 4 + 1];
  float a2 = anchors[(size_t)gid * 4 + 2];
  float a3 = anchors[(size_t)gid * 4 + 3];
  float wa = __fsub_rn(a2, a0);
  float ha = __fsub_rn(a3, a1);
  float cxa = __fadd_rn(a0, __fmul_rn(0.5f, wa));
  float cya = __fadd_rn(a1, __fmul_rn(0.5f, ha));
  float pcx = __fadd_rn(__fmul_rn(dx, wa), cxa);
  float pcy = __fadd_rn(__fmul_rn(dy, ha), cya);
  float pw = __fmul_rn(expf(dwv), wa);
  float ph = __fmul_rn(expf(dhv), ha);
  float x1 = __fsub_rn(pcx, __fmul_rn(0.5f, pw));
  float y1 = __fsub_rn(pcy, __fmul_rn(0.5f, ph));
  float x2 = __fadd_rn(pcx, __fmul_rn(0.5f, pw));
  float y2 = __fadd_rn(pcy, __fmul_rn(0.5f, ph));
  x1 = fminf(fmaxf(x1, 0.0f), 800.0f);
  y1 = fminf(fmaxf(y1, 0.0f), 800.0f);
  x2 = fminf(fmaxf(x2, 0.0f), 800.0f);
  y2 = fminf(fmaxf(y2, 0.0f), 800.0f);
  DecBox r;
  r.x1 = x1; r.y1 = y1; r.x2 = x2; r.y2 = y2; r.lvl = lvl;
  r.valid = (__fsub_rn(x2, x1) >= 1.0f) && (__fsub_rn(y2, y1) >= 1.0f);
  return r;
}

// ---------------- K0: zero state ----------------------------------------------
__global__ void k_zero(float* __restrict__ out, u32* __restrict__ counters,
                       u32* __restrict__ sidecnt, u32* __restrict__ tripcnt,
                       u64* __restrict__ cand_key, u32* __restrict__ rnzl,
                       u32* __restrict__ hist1, u32* __restrict__ state_known,
                       u32* __restrict__ state_kneed) {
  int i = blockIdx.x * blockDim.x + threadIdx.x;
  if (i < NB * POSTN * 5) out[i] = 0.0f;
  if (i < NB * 4096) cand_key[i] = 0ull;
  if (i < 64 * LSEG) rnzl[i] = 0u;
  if (i < 64 * NBUCK) hist1[i] = 0u;
  if (i < 64 * 16) { counters[i] = 0u; sidecnt[i] = 0u; tripcnt[i] = 0u; }
  if (i < 64) { state_known[i] = 0u; state_kneed[i] = (u32)PREN; }
}

// ---------------- K1: top-13-bit histogram straight from cls (float4) ----------
__global__ __launch_bounds__(1024) void k_hist1(
    const float* __restrict__ cls0, const float* __restrict__ cls1,
    const float* __restrict__ cls2, const float* __restrict__ cls3,
    u32* __restrict__ hist1) {
  int lvl, b, e0, nsl;
  slice_map(blockIdx.x, lvl, b, e0, nsl);
  const float* cls = (lvl == 0) ? cls0 : (lvl == 1) ? cls1 : (lvl == 2) ? cls2 : cls3;
  const float* cp = cls + (size_t)b * c_N[lvl];
  int tid = threadIdx.x;
  __shared__ u32 h[NBUCK];
  for (int t = tid; t < NBUCK; t += 1024) h[t] = 0u;
  __syncthreads();
  if (lvl != 3) {
    // base offsets are 16B-aligned for lvl 0..2 (all multiples of 4 elems)
    const float4* cp4 = (const float4*)(cp + e0);
    int n4 = nsl >> 2;
    for (int t = tid; t < n4; t += 1024) {
      float4 v = cp4[t];
      atomicAdd(&h[ord_bits(v.x) >> BSHIFT], 1u);
      atomicAdd(&h[ord_bits(v.y) >> BSHIFT], 1u);
      atomicAdd(&h[ord_bits(v.z) >> BSHIFT], 1u);
      atomicAdd(&h[ord_bits(v.w) >> BSHIFT], 1u);
    }
  } else {
    for (int e = e0 + tid; e < e0 + nsl; e += 1024)
      atomicAdd(&h[ord_bits(cp[e]) >> BSHIFT], 1u);
  }
  __syncthreads();
  int task = lvl * 16 + b;
  for (int t = tid; t < NBUCK; t += 1024) {
    u32 v = h[t];
    if (v) atomicAdd(&hist1[task * NBUCK + t], v);
  }
}

// ---------------- K2: pick boundary bucket (suffix scan) -----------------------
__global__ __launch_bounds__(1024) void k_pick1(
    const u32* __restrict__ hist1, u32* __restrict__ state_known,
    u32* __restrict__ state_kneed) {
  int task = blockIdx.x;
  int tid = threadIdx.x;
  __shared__ u32 A[NBUCK], Bb[NBUCK];
  __shared__ int sh_t;
  __shared__ u32 sh_above;
  u32 kneed = (u32)PREN;
  for (int t = tid; t < NBUCK; t += 1024) A[t] = hist1[task * NBUCK + t];
  __syncthreads();
  u32* cur = A;
  u32* nxt = Bb;
  for (int off2 = 1; off2 < NBUCK; off2 <<= 1) {
    for (int t = tid; t < NBUCK; t += 1024)
      nxt[t] = cur[t] + ((t + off2 < NBUCK) ? cur[t + off2] : 0u);
    __syncthreads();
    u32* tmp = cur; cur = nxt; nxt = tmp;
  }
  for (int t = tid; t < NBUCK; t += 1024) {
    u32 s = cur[t];
    u32 above = (t + 1 < NBUCK) ? cur[t + 1] : 0u;
    if (s >= kneed && above < kneed) { sh_t = t; sh_above = above; }
  }
  __syncthreads();
  if (tid == 0) {
    state_known[task] = (u32)sh_t << BSHIFT;
    state_kneed[task] = kneed - sh_above;   // how many to take from boundary
  }
}

// ---------------- K3: collect — block-local staging, 1 atomic per block --------
__global__ __launch_bounds__(1024) void k_collect(
    const float* __restrict__ cls0, const float* __restrict__ cls1,
    const float* __restrict__ cls2, const float* __restrict__ cls3,
    const u32* __restrict__ state_known,
    const float* __restrict__ reg0, const float* __restrict__ reg1,
    const float* __restrict__ reg2, const float* __restrict__ reg3,
    const float* __restrict__ anchors, u32* __restrict__ counters,
    u32* __restrict__ sidecnt, u64* __restrict__ sidebuf,
    u64* __restrict__ cand_key) {
  int lvl, b, e0, nsl;
  slice_map(blockIdx.x, lvl, b, e0, nsl);
  int task = lvl * 16 + b;
  u32 tb = state_known[task] >> BSHIFT;
  const float* cls = (lvl == 0) ? cls0 : (lvl == 1) ? cls1 : (lvl == 2) ? cls2 : cls3;
  const float* cp = cls + (size_t)b * c_N[lvl];
  int tid = threadIdx.x;
  __shared__ u32 ldef[1024];
  __shared__ u32 lside[BSIDE];
  __shared__ u32 cdef, cside, bdef, bside;
  if (tid == 0) { cdef = 0u; cside = 0u; }
  __syncthreads();
  if (lvl != 3) {
    const float4* cp4 = (const float4*)(cp + e0);
    int n4 = nsl >> 2;
    for (int t = tid; t < n4; t += 1024) {
      float4 v4 = cp4[t];
      int ebase = e0 + (t << 2);
#pragma unroll
      for (int c = 0; c < 4; ++c) {
        float f = (c == 0) ? v4.x : (c == 1) ? v4.y : (c == 2) ? v4.z : v4.w;
        u32 bk = ord_bits(f) >> BSHIFT;
        if (bk < tb) continue;
        if (bk > tb) {
          u32 i = atomicAdd(&cdef, 1u);
          if (i < 1024u) ldef[i] = (u32)(ebase + c);
        } else {
          u32 i = atomicAdd(&cside, 1u);
          if (i < (u32)BSIDE) lside[i] = (u32)(ebase + c);
        }
      }
    }
  } else {
    for (int e = e0 + tid; e < e0 + nsl; e += 1024) {
      u32 bk = ord_bits(cp[e]) >> BSHIFT;
      if (bk < tb) continue;
      if (bk > tb) {
        u32 i = atomicAdd(&cdef, 1u);
        if (i < 1024u) ldef[i] = (u32)e;
      } else {
        u32 i = atomicAdd(&cside, 1u);
        if (i < (u32)BSIDE) lside[i] = (u32)e;
      }
    }
  }
  __syncthreads();
  if (tid == 0) bdef = atomicAdd(&counters[task * 16], min(cdef, 1024u));
  if (tid == 1) bside = atomicAdd(&sidecnt[task * 16], min(cside, (u32)BSIDE));
  __syncthreads();
  int hw = c_HW[lvl], off = c_OFF[lvl];
  u32 nd = min(cdef, 1024u);
  for (u32 i = tid; i < nd; i += 1024) {
    int e = (int)ldef[i];
    int a = e / hw;
    int cell = e - a * hw;
    u32 gid = (u32)(off + cell * 3 + a);
    u64 key = ((u64)ord_bits(cp[e]) << 32) | (u32)(~gid);
    DecBox bx = decode_box(gid, b, reg0, reg1, reg2, reg3, anchors);
    u64 skey = bx.valid ? key : (key & 0xFFFFFFFFull);
    u32 slot = bdef + i;
    if (slot < (u32)PREN)
      cand_key[(size_t)b * 4096 + c_BASE[lvl] + slot] = skey;
  }
  u32 ns = min(cside, (u32)BSIDE);
  for (u32 i = tid; i < ns; i += 1024) {
    int e = (int)lside[i];
    int a = e / hw;
    int cell = e - a * hw;
    u32 gid = (u32)(off + cell * 3 + a);
    u64 key = ((u64)ord_bits(cp[e]) << 32) | (u32)(~gid);
    u32 slot = bside + i;
    if (slot < (u32)SIDECAP) sidebuf[(size_t)task * SIDECAP + slot] = key;
  }
}

// ---------------- K4: finalize — sort boundary bucket (np2), append kneed ------
__global__ __launch_bounds__(1024) void k_finalize(
    const u64* __restrict__ sidebuf, const u32* __restrict__ sidecnt,
    const u32* __restrict__ counters, const u32* __restrict__ state_kneed,
    const float* __restrict__ reg0, const float* __restrict__ reg1,
    const float* __restrict__ reg2, const float* __restrict__ reg3,
    const float* __restrict__ anchors, u64* __restrict__ cand_key) {
  int task = blockIdx.x;
  int lvl = task >> 4;
  int b = task & 15;
  int tid = threadIdx.x;
  u32 nside = min(sidecnt[task * 16], (u32)SIDECAP);
  u32 kneed = state_kneed[task];
  u32 nab = counters[task * 16];
  u32 np2 = 64;
  while (np2 < nside) np2 <<= 1;   // next pow2 >= nside (uniform)
  __shared__ u64 sk[SIDECAP];
  for (u32 i = tid; i < np2; i += 1024)
    sk[i] = (i < nside) ? sidebuf[(size_t)task * SIDECAP + i] : 0ull;
  __syncthreads();
  for (u32 k = 2; k <= np2; k <<= 1) {
    for (u32 j = k >> 1; j > 0; j >>= 1) {
      for (u32 t = tid; t < np2 / 2; t += 1024) {
        u32 i = 2u * t - (t & (j - 1u));
        u32 l2 = i | j;
        u64 av = sk[i], bv = sk[l2];
        bool up = ((i & k) == 0u);
        if (up ? (av < bv) : (av > bv)) { sk[i] = bv; sk[l2] = av; }
      }
      __syncthreads();
    }
  }
  if (tid < (int)kneed) {
    u64 key = sk[tid];
    u32 gid = ~((u32)key);
    DecBox bx = decode_box(gid, b, reg0, reg1, reg2, reg3, anchors);
    u64 skey = bx.valid ? key : (key & 0xFFFFFFFFull);
    u32 slot = nab + (u32)tid;
    if (slot < (u32)PREN)
      cand_key[(size_t)b * 4096 + c_BASE[lvl] + slot] = skey;
  }
}

// ---------------- K sortdec: fused per-(image,level) sort + decode -------------
__global__ __launch_bounds__(1024) void k_sortdec(
    u64* __restrict__ cand_key,
    const float* __restrict__ reg0, const float* __restrict__ reg1,
    const float* __restrict__ reg2, const float* __restrict__ reg3,
    const float* __restrict__ anchors,
    float4* __restrict__ sbox, float4* __restrict__ boffA,
    float* __restrict__ area, float* __restrict__ score,
    u64* __restrict__ vmaskl) {
  int bl = blockIdx.x;                 // b*4 + lvl
  int b = bl >> 2;
  int tid = threadIdx.x;
  __shared__ u64 sk[LSEG];
  sk[tid] = cand_key[(size_t)bl * LSEG + tid];
  __syncthreads();
  for (u32 k = 2; k <= LSEG; k <<= 1) {
    for (u32 j = k >> 1; j > 0; j >>= 1) {
      if (tid < LSEG / 2) {
        u32 t = (u32)tid;
        u32 i = 2u * t - (t & (j - 1u));
        u32 l2 = i | j;
        u64 av = sk[i], bv = sk[l2];
        bool up = ((i & k) == 0u);
        if (up ? (av < bv) : (av > bv)) { sk[i] = bv; sk[l2] = av; }
      }
      __syncthreads();
    }
  }
  // write back sorted keys (k_nmsl reads them for kept compaction)
  u64 key = sk[tid];
  cand_key[(size_t)bl * LSEG + tid] = key;
  // decode payloads
  float4 bx4 = make_float4(0.f, 0.f, 0.f, 0.f);
  float4 bo4 = make_float4(0.f, 0.f, 0.f, 0.f);
  float ar = 0.f, sc = 0.f;
  bool vflag = false;
  if (key != 0ull) {
    u32 gid = ~((u32)key);
    vflag = (key >> 32) != 0ull;
    DecBox bx = decode_box(gid, b, reg0, reg1, reg2, reg3, anchors);
    bx4 = make_float4(bx.x1, bx.y1, bx.x2, bx.y2);
    float offv = __fmul_rn((float)bx.lvl, 801.0f);
    bo4 = make_float4(__fadd_rn(bx.x1, offv), __fadd_rn(bx.y1, offv),
                      __fadd_rn(bx.x2, offv), __fadd_rn(bx.y2, offv));
    ar = __fmul_rn(__fsub_rn(bo4.z, bo4.x), __fsub_rn(bo4.w, bo4.y));
    if (vflag) {
      float logit = inv_ord((u32)(key >> 32));
      sc = 1.0f / (1.0f + expf(-logit));
    }
  }
  size_t gi = (size_t)bl * LSEG + tid;
  sbox[gi] = bx4;
  boffA[gi] = bo4;
  area[gi] = ar;
  score[gi] = sc;
  u64 bal = __ballot(vflag ? 1 : 0);
  if ((tid & 63) == 0) vmaskl[bl * LCH + (tid >> 6)] = bal;
}

// ---------------- K maskl: triangular-mapped IoU → compact triplet list --------
// RN(inter/uni) > 0.7f  <=>  inter/uni >= B, B = 0.7f + 2^-25 (tie rounds up).
// B*(double)uni is exact (25x24 bits <= 53); comparison is bit-equivalent.
#define RPB 16
__global__ __launch_bounds__(256) void k_maskl(
    const float4* __restrict__ boffA, const float* __restrict__ area,
    ulonglong2* __restrict__ trip, u32* __restrict__ tripcnt,
    u32* __restrict__ rnzl) {
  const double Bd = 0x1.6666661p-1;   // 0.7000000178813934326171875
  int bg = blockIdx.x;
  int bl = bg / NPAIR;
  int p = bg - bl * NPAIR;
  // triangular (chunk,g) pairs: chunk c covers row-groups g < (c+1)*16
  int chunk, g;
  if (p < 16)      { chunk = 0; g = p; }
  else if (p < 48) { chunk = 1; g = p - 16; }
  else if (p < 96) { chunk = 2; g = p - 48; }
  else             { chunk = 3; g = p - 96; }
  int row0 = g * RPB;
  int tid = threadIdx.x;
  int wave = tid >> 6;
  int lane = tid & 63;
  __shared__ float4 rb[RPB];
  __shared__ float ra[RPB];
  __shared__ ulonglong2 stage[RPB * 4];   // max 64 nonzero words per block
  __shared__ u32 scount, sbase;
  if (tid == 0) scount = 0u;
  if (tid < RPB) {
    rb[tid] = boffA[(size_t)bl * LSEG + row0 + tid];
    ra[tid] = area[(size_t)bl * LSEG + row0 + tid];
  }
  __syncthreads();
  int wword = chunk * 4 + wave;
  int wmaxj = chunk * 256 + wave * 64 + 63;   // this wave's max column
  int j = chunk * 256 + tid;
  float4 cb = boffA[(size_t)bl * LSEG + j];
  float ca = area[(size_t)bl * LSEG + j];
  if (wmaxj > row0) {
#pragma unroll
    for (int rr = 0; rr < RPB; ++rr) {
      int i = row0 + rr;
      if (wmaxj <= i) continue;
      float4 rbb = rb[rr];
      float ria = ra[rr];
      float ix1 = fmaxf(cb.x, rbb.x);
      float iy1 = fmaxf(cb.y, rbb.y);
      float ix2 = fminf(cb.z, rbb.z);
      float iy2 = fminf(cb.w, rbb.w);
      float inter = __fmul_rn(fmaxf(__fsub_rn(ix2, ix1), 0.0f),
                              fmaxf(__fsub_rn(iy2, iy1), 0.0f));
      float uni = __fsub_rn(__fadd_rn(ca, ria), inter);
      bool pred = (j > i) && (inter > 0.0f) &&
                  ((double)inter >= Bd * (double)uni);
      u64 bal = __ballot(pred ? 1 : 0);
      if (lane == 0 && bal) {
        u32 sidx = atomicAdd(&scount, 1u);
        ulonglong2 e;
        e.x = bal;
        e.y = (u64)(u32)(i * LCH + wword);
        stage[sidx] = e;
        atomicOr(&rnzl[(size_t)bl * LSEG + i], 1u << wword);
      }
    }
  }
  __syncthreads();
  if (tid == 0 && scount) sbase = atomicAdd(&tripcnt[bl * 16], scount);
  __syncthreads();
  for (u32 t = tid; t < scount; t += 256)
    trip[(size_t)bl * TRIPCAP + sbase + t] = stage[t];
}

// ---------------- K nmsl: greedy NMS — full mask matrix in LDS -----------------
__global__ __launch_bounds__(64) void k_nmsl(
    const ulonglong2* __restrict__ trip, const u32* __restrict__ tripcnt,
    const u32* __restrict__ rnzl, const u64* __restrict__ vmaskl,
    const u64* __restrict__ cand_key,
    u64* __restrict__ keptkeys, u32* __restrict__ keptpos,
    u32* __restrict__ keptcnt) {
  int bl = blockIdx.x;
  int lane = threadIdx.x;
  extern __shared__ char smem[];
  u64* lmask = (u64*)smem;                       // [LSEG*LCH] = 128 KB
  u32* rnzL  = (u32*)(smem + (size_t)LSEG * LCH * 8);  // [LSEG] = 4 KB
  // zero the matrix (16B LDS writes), copy rnzl (coalesced global)
  ulonglong2 z2; z2.x = 0ull; z2.y = 0ull;
  ulonglong2* lm2 = (ulonglong2*)lmask;
  for (int t = lane; t < LSEG * LCH / 2; t += 64) lm2[t] = z2;
  for (int t = lane; t < LSEG; t += 64) rnzL[t] = rnzl[(size_t)bl * LSEG + t];
  u64 vword = (lane < LCH) ? vmaskl[bl * LCH + lane] : 0ull;
  __syncthreads();
  // scatter triplets (unique (row,word) targets — order-independent)
  u32 tc = tripcnt[bl * 16];
  for (u32 t = lane; t < tc; t += 64) {
    ulonglong2 e = trip[(size_t)bl * TRIPCAP + t];
    lmask[(u32)e.y] = e.x;
  }
  __syncthreads();
  u64 supp = 0ull;   // lane w<16 holds suppression word w
  u64 keep = 0ull;   // lane w<16 holds keep word w
  for (int W = 0; W < LCH; ++W) {
    int c0 = W << 6;
    // independent LDS reads issue early; latency hides under the shfl chain
    u32 rzW = rnzL[c0 + lane];                      // rnz of row c0+lane
    u64 dchW = lmask[(size_t)(c0 + lane) * LCH + W];  // diagonal word
    u64 s = __shfl(supp, W);
    u64 v = __shfl(vword, W);
    // greedy resolve: scalar readlane over suppressor rows only
    u64 pending = v & ~s;
    u64 kw = 0ull;
    u64 suppressors = __ballot((dchW & pending) != 0ull) & pending;
    while (pending) {
      u64 sp = pending & suppressors;
      if (!sp) { kw |= pending; break; }
      int q = __builtin_ctzll(sp);
      u64 below = pending & ((1ull << q) - 1ull);
      kw |= below | (1ull << q);
      u64 supq = readlane_u64(dchW, q);
      pending &= ~supq & ~below & ~(1ull << q);
    }
    // sparse apply: kept rows with words beyond W; 4-deep batched LDS reads
    u64 kk = __ballot(((rzW >> W) >> 1) != 0u) & kw;
    bool ld = (lane < LCH);
    u64 acc = 0ull;
    while (kk) {
      int q0 = __builtin_ctzll(kk); kk &= kk - 1ull;
      u64 m0 = ld ? lmask[(size_t)(c0 + q0) * LCH + lane] : 0ull;
      u64 m1 = 0ull, m2 = 0ull, m3 = 0ull;
      if (kk) {
        int q1 = __builtin_ctzll(kk); kk &= kk - 1ull;
        m1 = ld ? lmask[(size_t)(c0 + q1) * LCH + lane] : 0ull;
      }
      if (kk) {
        int q2 = __builtin_ctzll(kk); kk &= kk - 1ull;
        m2 = ld ? lmask[(size_t)(c0 + q2) * LCH + lane] : 0ull;
      }
      if (kk) {
        int q3 = __builtin_ctzll(kk); kk &= kk - 1ull;
        m3 = ld ? lmask[(size_t)(c0 + q3) * LCH + lane] : 0ull;
      }
      acc |= (m0 | m1) | (m2 | m3);
    }
    supp |= acc;
    if (lane == W) keep = kw;
  }
  // compact kept: prefix popcount across lanes
  int pc = __popcll(keep);
  int incl = pc;
  for (int d = 1; d < 64; d <<= 1) {
    int t = __shfl_up(incl, d);
    if (lane >= d) incl += t;
  }
  int r = incl - pc;
  u64 kk = keep;
  while (kk) {
    int bit = __builtin_ctzll(kk);
    kk &= kk - 1ull;
    int p = lane * 64 + bit;
    keptkeys[(size_t)bl * LSEG + r] = cand_key[(size_t)bl * LSEG + p];
    keptpos[(size_t)bl * LSEG + r] = (u32)p;
    ++r;
  }
  if (lane == 63) keptcnt[bl] = (u32)incl;
}

// ---------------- K out: global rank via cross-level binary search -------------
__global__ __launch_bounds__(1024) void k_out(
    const u64* __restrict__ keptkeys, const u32* __restrict__ keptpos,
    const u32* __restrict__ keptcnt, const float4* __restrict__ sbox,
    const float* __restrict__ score, float* __restrict__ out) {
  int bl = blockIdx.x;
  int b = bl >> 2;
  int l = bl & 3;
  int r = threadIdx.x;
  u32 cnt = keptcnt[bl];
  if (r >= (int)cnt) return;
  u64 K = keptkeys[(size_t)bl * LSEG + r];
  int rank = r;
#pragma unroll
  for (int dl = 0; dl < 4; ++dl) {
    if (dl == l) continue;
    int obl = (b << 2) | dl;
    const u64* arr = keptkeys + (size_t)obl * LSEG;
    int lo = 0, hi = (int)keptcnt[obl];
    while (lo < hi) {
      int mid = (lo + hi) >> 1;
      if (arr[mid] > K) lo = mid + 1; else hi = mid;
    }
    rank += lo;
  }
  if (rank < POSTN) {
    u32 p = keptpos[(size_t)bl * LSEG + r];
    float4 bx = sbox[(size_t)bl * LSEG + p];
    size_t ob = ((size_t)b * POSTN + (size_t)rank) * 4;
    out[ob + 0] = bx.x;
    out[ob + 1] = bx.y;
    out[ob + 2] = bx.z;
    out[ob + 3] = bx.w;
    out[(size_t)NB * POSTN * 4 + (size_t)b * POSTN + (size_t)rank] =
        score[(size_t)bl * LSEG + p];
  }
}

extern "C" void kernel_launch(void* const* d_in, const int* in_sizes, int n_in,
                              void* d_out, int out_size, void* d_ws, size_t ws_size,
                              hipStream_t stream) {
  // setup_inputs dict order: cls0, reg0, cls1, reg1, cls2, reg2, cls3, reg3, anchors
  const float* cls0 = (const float*)d_in[0];
  const float* reg0 = (const float*)d_in[1];
  const float* cls1 = (const float*)d_in[2];
  const float* reg1 = (const float*)d_in[3];
  const float* cls2 = (const float*)d_in[4];
  const float* reg2 = (const float*)d_in[5];
  const float* cls3 = (const float*)d_in[6];
  const float* reg3 = (const float*)d_in[7];
  const float* anchors = (const float*)d_in[8];
  float* out = (float*)d_out;

  char* ws = (char*)d_ws;
  size_t off = 0;
  auto take = [&](size_t bytes) -> void* {
    off = (off + 255) & ~(size_t)255;
    void* p = ws + off;
    off += bytes;
    return p;
  };
  ulonglong2* trip = (ulonglong2*)take((size_t)64 * TRIPCAP * 16); // 16.8 MB
  u64* sidebuf   = (u64*)take((size_t)64 * SIDECAP * 8);     // 2 MB
  u32* rnzl      = (u32*)take((size_t)64 * LSEG * 4);        // 256 KB
  u64* cand_key  = (u64*)take((size_t)NB * 4096 * 8);        // 512 KB
  float4* sbox   = (float4*)take((size_t)64 * LSEG * 16);    // 1 MB
  float4* boffA  = (float4*)take((size_t)64 * LSEG * 16);    // 1 MB
  float* area    = (float*)take((size_t)64 * LSEG * 4);
  float* score   = (float*)take((size_t)64 * LSEG * 4);
  u64* vmaskl    = (u64*)take((size_t)64 * LCH * 8);
  u64* keptkeys  = (u64*)take((size_t)64 * LSEG * 8);        // 512 KB
  u32* keptpos   = (u32*)take((size_t)64 * LSEG * 4);        // 256 KB
  u32* keptcnt   = (u32*)take((size_t)64 * 4);
  u32* hist1     = (u32*)take((size_t)64 * NBUCK * 4);       // 2 MB
  u32* counters  = (u32*)take((size_t)64 * 16 * 4);          // 64B-padded
  u32* sidecnt   = (u32*)take((size_t)64 * 16 * 4);          // 64B-padded
  u32* tripcnt   = (u32*)take((size_t)64 * 16 * 4);          // 64B-padded
  u32* state_known = (u32*)take((size_t)64 * 4);
  u32* state_kneed = (u32*)take((size_t)64 * 4);
  (void)ws_size; (void)in_sizes; (void)n_in; (void)out_size;

  k_zero<<<2048, 256, 0, stream>>>(out, counters, sidecnt, tripcnt, cand_key,
                                   rnzl, hist1, state_known, state_kneed);
  k_hist1<<<192, 1024, 0, stream>>>(cls0, cls1, cls2, cls3, hist1);
  k_pick1<<<64, 1024, 0, stream>>>(hist1, state_known, state_kneed);
  k_collect<<<192, 1024, 0, stream>>>(cls0, cls1, cls2, cls3, state_known,
                                      reg0, reg1, reg2, reg3, anchors,
                                      counters, sidecnt, sidebuf, cand_key);
  k_finalize<<<64, 1024, 0, stream>>>(sidebuf, sidecnt, counters, state_kneed,
                                      reg0, reg1, reg2, reg3, anchors,
                                      cand_key);
  k_sortdec<<<64, 1024, 0, stream>>>(cand_key, reg0, reg1, reg2, reg3,
                                     anchors, sbox, boffA, area, score,
                                     vmaskl);
  k_maskl<<<64 * NPAIR, 256, 0, stream>>>(boffA, area, trip, tripcnt, rnzl);
  // dynamic LDS: 128 KB mask matrix + 4 KB rnz copy = 135168 B (<= 160 KB/CU)
  k_nmsl<<<64, 64, 135168, stream>>>(trip, tripcnt, rnzl, vmaskl, cand_key,
                                     keptkeys, keptpos, keptcnt);
  k_out<<<64, 1024, 0, stream>>>(keptkeys, keptpos, keptcnt, sbox, score, out);
}

// Round 14
// 125.924 us; speedup vs baseline: 12.1263x; 1.0461x over previous
//
#include <hip/hip_runtime.h>
#include <cstdint>
#include <cstddef>

typedef uint32_t u32;
typedef uint64_t u64;

#define NB 16
#define POSTN 1000
#define PREN 1000
#define LSEG 1024     // per-level segment (1000 candidates + 24 pad)
#define LCH 16        // chunks of 64 per level
#define SIDECAP 4096  // per-task boundary-bucket buffer
#define BSIDE 2048    // per-block LDS side list
#define TRIPCAP (LSEG * LCH)  // per-task triplet capacity = full matrix
#define NPAIR 160     // triangular (chunk,g) pairs: 16+32+48+64
#define NBUCK 8192    // 13-bit histogram buckets
#define BSHIFT 19     // ord >> BSHIFT = bucket

__constant__ int c_N[4]    = {120000, 30000, 7500, 1875};
__constant__ int c_OFF[4]  = {0, 120000, 150000, 157500};
__constant__ int c_HW[4]   = {40000, 10000, 2500, 625};
__constant__ int c_W[4]    = {200, 100, 50, 25};
__constant__ int c_BASE[4] = {0, 1024, 2048, 3072};

__device__ __forceinline__ u32 ord_bits(float f) {
  u32 u = __float_as_uint(f);
  return (u & 0x80000000u) ? ~u : (u | 0x80000000u);
}
__device__ __forceinline__ float inv_ord(u32 o) {
  u32 bits = (o & 0x80000000u) ? (o ^ 0x80000000u) : ~o;
  return __uint_as_float(bits);
}
__device__ __forceinline__ u64 readlane_u64(u64 v, int l) {
  u32 lo = (u32)__builtin_amdgcn_readlane((int)(u32)v, l);
  u32 hi = (u32)__builtin_amdgcn_readlane((int)(u32)(v >> 32), l);
  return (((u64)hi) << 32) | (u64)lo;
}

// 192-block slice map: 8 blocks/task lvl0, 2/task lvl1, 1/task lvl2+3
__device__ __forceinline__ void slice_map(int bid, int& lvl, int& b, int& e0,
                                          int& nsl) {
  if (bid < 128)      { lvl = 0; b = bid >> 3; e0 = (bid & 7) * 15000; nsl = 15000; }
  else if (bid < 160) { lvl = 1; int t = bid - 128; b = t >> 1; e0 = (t & 1) * 15000; nsl = 15000; }
  else if (bid < 176) { lvl = 2; b = bid - 160; e0 = 0; nsl = 7500; }
  else                { lvl = 3; b = bid - 176; e0 = 0; nsl = 1875; }
}

struct DecBox { float x1, y1, x2, y2; int lvl; bool valid; };

__device__ DecBox decode_box(u32 gid, int b,
    const float* __restrict__ reg0, const float* __restrict__ reg1,
    const float* __restrict__ reg2, const float* __restrict__ reg3,
    const float* __restrict__ anchors) {
  int lvl = (gid < 120000u) ? 0 : (gid < 150000u) ? 1 : (gid < 157500u) ? 2 : 3;
  int local = (int)gid - c_OFF[lvl];
  int a = local % 3;
  int cell = local / 3;
  int w = c_W[lvl];
  int hw = c_HW[lvl];
  int y = cell / w;
  int x = cell - y * w;
  const float* reg = (lvl == 0) ? reg0 : (lvl == 1) ? reg1 : (lvl == 2) ? reg2 : reg3;
  size_t base = ((size_t)(b * 12 + a * 4) * (size_t)w + (size_t)y) * (size_t)w + (size_t)x;
  const float CLIPV = 4.135166556742356f; // log(1000/16) as f32
  float dx = reg[base];
  float dy = reg[base + (size_t)hw];
  float dwv = fminf(reg[base + 2 * (size_t)hw], CLIPV);
  float dhv = fminf(reg[base + 3 * (size_t)hw], CLIPV);
  float a0 = anchors[(size_t)gid * 4 + 0];
  float a1 = anchors[(size_t)gid * 4 + 1];
  float a2 = anchors[(size_t)gid * 4 + 2];
  float a3 = anchors[(size_t)gid * 4 + 3];
  float wa = __fsub_rn(a2, a0);
  float ha = __fsub_rn(a3, a1);
  float cxa = __fadd_rn(a0, __fmul_rn(0.5f, wa));
  float cya = __fadd_rn(a1, __fmul_rn(0.5f, ha));
  float pcx = __fadd_rn(__fmul_rn(dx, wa), cxa);
  float pcy = __fadd_rn(__fmul_rn(dy, ha), cya);
  float pw = __fmul_rn(expf(dwv), wa);
  float ph = __fmul_rn(expf(dhv), ha);
  float x1 = __fsub_rn(pcx, __fmul_rn(0.5f, pw));
  float y1 = __fsub_rn(pcy, __fmul_rn(0.5f, ph));
  float x2 = __fadd_rn(pcx, __fmul_rn(0.5f, pw));
  float y2 = __fadd_rn(pcy, __fmul_rn(0.5f, ph));
  x1 = fminf(fmaxf(x1, 0.0f), 800.0f);
  y1 = fminf(fmaxf(y1, 0.0f), 800.0f);
  x2 = fminf(fmaxf(x2, 0.0f), 800.0f);
  y2 = fminf(fmaxf(y2, 0.0f), 800.0f);
  DecBox r;
  r.x1 = x1; r.y1 = y1; r.x2 = x2; r.y2 = y2; r.lvl = lvl;
  r.valid = (__fsub_rn(x2, x1) >= 1.0f) && (__fsub_rn(y2, y1) >= 1.0f);
  return r;
}

// ---------------- K0: zero state ----------------------------------------------
__global__ void k_zero(float* __restrict__ out, u32* __restrict__ counters,
                       u32* __restrict__ sidecnt, u32* __restrict__ tripcnt,
                       u64* __restrict__ cand_key,
                       u32* __restrict__ hist1, u32* __restrict__ state_known,
                       u32* __restrict__ state_kneed) {
  int i = blockIdx.x * blockDim.x + threadIdx.x;
  if (i < NB * POSTN * 5) out[i] = 0.0f;
  if (i < NB * 4096) cand_key[i] = 0ull;
  if (i < 64 * NBUCK) hist1[i] = 0u;
  if (i < 64 * 16) { counters[i] = 0u; sidecnt[i] = 0u; tripcnt[i] = 0u; }
  if (i < 64) { state_known[i] = 0u; state_kneed[i] = (u32)PREN; }
}

// ---------------- K1: top-13-bit histogram straight from cls (float4) ----------
__global__ __launch_bounds__(1024) void k_hist1(
    const float* __restrict__ cls0, const float* __restrict__ cls1,
    const float* __restrict__ cls2, const float* __restrict__ cls3,
    u32* __restrict__ hist1) {
  int lvl, b, e0, nsl;
  slice_map(blockIdx.x, lvl, b, e0, nsl);
  const float* cls = (lvl == 0) ? cls0 : (lvl == 1) ? cls1 : (lvl == 2) ? cls2 : cls3;
  const float* cp = cls + (size_t)b * c_N[lvl];
  int tid = threadIdx.x;
  __shared__ u32 h[NBUCK];
  for (int t = tid; t < NBUCK; t += 1024) h[t] = 0u;
  __syncthreads();
  if (lvl != 3) {
    // base offsets are 16B-aligned for lvl 0..2 (all multiples of 4 elems)
    const float4* cp4 = (const float4*)(cp + e0);
    int n4 = nsl >> 2;
    for (int t = tid; t < n4; t += 1024) {
      float4 v = cp4[t];
      atomicAdd(&h[ord_bits(v.x) >> BSHIFT], 1u);
      atomicAdd(&h[ord_bits(v.y) >> BSHIFT], 1u);
      atomicAdd(&h[ord_bits(v.z) >> BSHIFT], 1u);
      atomicAdd(&h[ord_bits(v.w) >> BSHIFT], 1u);
    }
  } else {
    for (int e = e0 + tid; e < e0 + nsl; e += 1024)
      atomicAdd(&h[ord_bits(cp[e]) >> BSHIFT], 1u);
  }
  __syncthreads();
  int task = lvl * 16 + b;
  for (int t = tid; t < NBUCK; t += 1024) {
    u32 v = h[t];
    if (v) atomicAdd(&hist1[task * NBUCK + t], v);
  }
}

// ---------------- K2: pick boundary bucket — hierarchical O(N) suffix scan -----
__global__ __launch_bounds__(1024) void k_pick1(
    const u32* __restrict__ hist1, u32* __restrict__ state_known,
    u32* __restrict__ state_kneed) {
  int task = blockIdx.x;
  int tid = threadIdx.x;
  __shared__ u32 h[NBUCK];      // 32 KB
  __shared__ u32 spA[1024];
  __shared__ u32 spB[1024];
  __shared__ int sh_t;
  __shared__ u32 sh_above;
  u32 kneed = (u32)PREN;
  for (int t = tid; t < NBUCK; t += 1024) h[t] = hist1[task * NBUCK + t];
  __syncthreads();
  int base = tid << 3;          // 8 buckets per thread
  u32 part = 0;
#pragma unroll
  for (int j = 0; j < 8; ++j) part += h[base + j];
  spA[tid] = part;
  __syncthreads();
  // suffix scan over 1024 partials (ping-pong, 10 rounds)
  u32* cur = spA;
  u32* nxt = spB;
  for (int off = 1; off < 1024; off <<= 1) {
    u32 v = cur[tid] + ((tid + off < 1024) ? cur[tid + off] : 0u);
    nxt[tid] = v;
    __syncthreads();
    u32* tmp = cur; cur = nxt; nxt = tmp;
  }
  // cur[t] = count of elements with bucket >= 8t
  u32 suf = (tid + 1 < 1024) ? cur[tid + 1] : 0u;   // suffix at bucket 8(t+1)
#pragma unroll
  for (int j = 7; j >= 0; --j) {
    u32 s = suf + h[base + j];
    if (s >= kneed && suf < kneed) { sh_t = base + j; sh_above = suf; }
    suf = s;
  }
  __syncthreads();
  if (tid == 0) {
    state_known[task] = (u32)sh_t << BSHIFT;
    state_kneed[task] = kneed - sh_above;   // how many to take from boundary
  }
}

// ---------------- K3: collect — block-local staging, 1 atomic per block --------
__global__ __launch_bounds__(1024) void k_collect(
    const float* __restrict__ cls0, const float* __restrict__ cls1,
    const float* __restrict__ cls2, const float* __restrict__ cls3,
    const u32* __restrict__ state_known,
    const float* __restrict__ reg0, const float* __restrict__ reg1,
    const float* __restrict__ reg2, const float* __restrict__ reg3,
    const float* __restrict__ anchors, u32* __restrict__ counters,
    u32* __restrict__ sidecnt, u64* __restrict__ sidebuf,
    u64* __restrict__ cand_key) {
  int lvl, b, e0, nsl;
  slice_map(blockIdx.x, lvl, b, e0, nsl);
  int task = lvl * 16 + b;
  u32 tb = state_known[task] >> BSHIFT;
  const float* cls = (lvl == 0) ? cls0 : (lvl == 1) ? cls1 : (lvl == 2) ? cls2 : cls3;
  const float* cp = cls + (size_t)b * c_N[lvl];
  int tid = threadIdx.x;
  __shared__ u32 ldef[1024];
  __shared__ u32 lside[BSIDE];
  __shared__ u32 cdef, cside, bdef, bside;
  if (tid == 0) { cdef = 0u; cside = 0u; }
  __syncthreads();
  if (lvl != 3) {
    const float4* cp4 = (const float4*)(cp + e0);
    int n4 = nsl >> 2;
    for (int t = tid; t < n4; t += 1024) {
      float4 v4 = cp4[t];
      int ebase = e0 + (t << 2);
#pragma unroll
      for (int c = 0; c < 4; ++c) {
        float f = (c == 0) ? v4.x : (c == 1) ? v4.y : (c == 2) ? v4.z : v4.w;
        u32 bk = ord_bits(f) >> BSHIFT;
        if (bk < tb) continue;
        if (bk > tb) {
          u32 i = atomicAdd(&cdef, 1u);
          if (i < 1024u) ldef[i] = (u32)(ebase + c);
        } else {
          u32 i = atomicAdd(&cside, 1u);
          if (i < (u32)BSIDE) lside[i] = (u32)(ebase + c);
        }
      }
    }
  } else {
    for (int e = e0 + tid; e < e0 + nsl; e += 1024) {
      u32 bk = ord_bits(cp[e]) >> BSHIFT;
      if (bk < tb) continue;
      if (bk > tb) {
        u32 i = atomicAdd(&cdef, 1u);
        if (i < 1024u) ldef[i] = (u32)e;
      } else {
        u32 i = atomicAdd(&cside, 1u);
        if (i < (u32)BSIDE) lside[i] = (u32)e;
      }
    }
  }
  __syncthreads();
  if (tid == 0) bdef = atomicAdd(&counters[task * 16], min(cdef, 1024u));
  if (tid == 1) bside = atomicAdd(&sidecnt[task * 16], min(cside, (u32)BSIDE));
  __syncthreads();
  int hw = c_HW[lvl], off = c_OFF[lvl];
  u32 nd = min(cdef, 1024u);
  for (u32 i = tid; i < nd; i += 1024) {
    int e = (int)ldef[i];
    int a = e / hw;
    int cell = e - a * hw;
    u32 gid = (u32)(off + cell * 3 + a);
    u64 key = ((u64)ord_bits(cp[e]) << 32) | (u32)(~gid);
    DecBox bx = decode_box(gid, b, reg0, reg1, reg2, reg3, anchors);
    u64 skey = bx.valid ? key : (key & 0xFFFFFFFFull);
    u32 slot = bdef + i;
    if (slot < (u32)PREN)
      cand_key[(size_t)b * 4096 + c_BASE[lvl] + slot] = skey;
  }
  u32 ns = min(cside, (u32)BSIDE);
  for (u32 i = tid; i < ns; i += 1024) {
    int e = (int)lside[i];
    int a = e / hw;
    int cell = e - a * hw;
    u32 gid = (u32)(off + cell * 3 + a);
    u64 key = ((u64)ord_bits(cp[e]) << 32) | (u32)(~gid);
    u32 slot = bside + i;
    if (slot < (u32)SIDECAP) sidebuf[(size_t)task * SIDECAP + slot] = key;
  }
}

// ---------------- K sortdec: fused side-finalize + sort + decode ---------------
__global__ __launch_bounds__(1024) void k_sortdec(
    u64* __restrict__ cand_key, const u64* __restrict__ sidebuf,
    const u32* __restrict__ sidecnt, const u32* __restrict__ counters,
    const u32* __restrict__ state_kneed,
    const float* __restrict__ reg0, const float* __restrict__ reg1,
    const float* __restrict__ reg2, const float* __restrict__ reg3,
    const float* __restrict__ anchors,
    float4* __restrict__ sbox, float4* __restrict__ boffA,
    float* __restrict__ area, float* __restrict__ score,
    u64* __restrict__ vmaskl, u32* __restrict__ rnzl) {
  int bl = blockIdx.x;                 // b*4 + lvl
  int b = bl >> 2;
  int lvl = bl & 3;
  int task = lvl * 16 + b;
  int tid = threadIdx.x;
  // zero rnzl for this (b,lvl) — consumed (atomicOr) by k_maskl after us
  rnzl[(size_t)bl * LSEG + tid] = 0u;
  __shared__ u64 sside[SIDECAP];       // 32 KB
  __shared__ u64 sk[LSEG];             // 8 KB
  u32 nside = min(sidecnt[task * 16], (u32)SIDECAP);
  u32 kneed = state_kneed[task];
  u32 nab = counters[task * 16];       // nab + kneed == 1000 by construction
  u32 np2 = 64;
  while (np2 < nside) np2 <<= 1;
  for (u32 i = tid; i < np2; i += 1024)
    sside[i] = (i < nside) ? sidebuf[(size_t)task * SIDECAP + i] : 0ull;
  __syncthreads();
  // sort side keys desc (raw keys — top-k selection is pre-validity)
  for (u32 k = 2; k <= np2; k <<= 1) {
    for (u32 j = k >> 1; j > 0; j >>= 1) {
      for (u32 t = tid; t < np2 / 2; t += 1024) {
        u32 i = 2u * t - (t & (j - 1u));
        u32 l2 = i | j;
        u64 av = sside[i], bv = sside[l2];
        bool up = ((i & k) == 0u);
        if (up ? (av < bv) : (av > bv)) { sside[i] = bv; sside[l2] = av; }
      }
      __syncthreads();
    }
  }
  // validity-adjust the selected top-kneed side keys (in place, own slot only)
  if (tid < (int)kneed) {
    u64 key = sside[tid];
    u32 gid = ~((u32)key);
    DecBox bx = decode_box(gid, b, reg0, reg1, reg2, reg3, anchors);
    sside[tid] = bx.valid ? key : (key & 0xFFFFFFFFull);
  }
  u64 defk = (tid < (int)nab)
                 ? cand_key[(size_t)b * 4096 + c_BASE[lvl] + tid] : 0ull;
  __syncthreads();
  u64 kv = defk;
  if (tid >= (int)nab && tid < (int)(nab + kneed)) kv = sside[tid - nab];
  sk[tid] = kv;
  __syncthreads();
  // main 1024 bitonic sort desc
  for (u32 k = 2; k <= LSEG; k <<= 1) {
    for (u32 j = k >> 1; j > 0; j >>= 1) {
      if (tid < LSEG / 2) {
        u32 t = (u32)tid;
        u32 i = 2u * t - (t & (j - 1u));
        u32 l2 = i | j;
        u64 av = sk[i], bv = sk[l2];
        bool up = ((i & k) == 0u);
        if (up ? (av < bv) : (av > bv)) { sk[i] = bv; sk[l2] = av; }
      }
      __syncthreads();
    }
  }
  // write back sorted keys (k_nmsl reads them for kept compaction)
  u64 key = sk[tid];
  cand_key[(size_t)bl * LSEG + tid] = key;
  // decode payloads
  float4 bx4 = make_float4(0.f, 0.f, 0.f, 0.f);
  float4 bo4 = make_float4(0.f, 0.f, 0.f, 0.f);
  float ar = 0.f, sc = 0.f;
  bool vflag = false;
  if (key != 0ull) {
    u32 gid = ~((u32)key);
    vflag = (key >> 32) != 0ull;
    DecBox bx = decode_box(gid, b, reg0, reg1, reg2, reg3, anchors);
    bx4 = make_float4(bx.x1, bx.y1, bx.x2, bx.y2);
    float offv = __fmul_rn((float)bx.lvl, 801.0f);
    bo4 = make_float4(__fadd_rn(bx.x1, offv), __fadd_rn(bx.y1, offv),
                      __fadd_rn(bx.x2, offv), __fadd_rn(bx.y2, offv));
    ar = __fmul_rn(__fsub_rn(bo4.z, bo4.x), __fsub_rn(bo4.w, bo4.y));
    if (vflag) {
      float logit = inv_ord((u32)(key >> 32));
      sc = 1.0f / (1.0f + expf(-logit));
    }
  }
  size_t gi = (size_t)bl * LSEG + tid;
  sbox[gi] = bx4;
  boffA[gi] = bo4;
  area[gi] = ar;
  score[gi] = sc;
  u64 bal = __ballot(vflag ? 1 : 0);
  if ((tid & 63) == 0) vmaskl[bl * LCH + (tid >> 6)] = bal;
}

// ---------------- K maskl: triangular-mapped IoU → compact triplet list --------
// RN(inter/uni) > 0.7f  <=>  inter/uni >= B, B = 0.7f + 2^-25 (tie rounds up).
// B*(double)uni is exact (25x24 bits <= 53); comparison is bit-equivalent.
#define RPB 16
__global__ __launch_bounds__(256) void k_maskl(
    const float4* __restrict__ boffA, const float* __restrict__ area,
    ulonglong2* __restrict__ trip, u32* __restrict__ tripcnt,
    u32* __restrict__ rnzl) {
  const double Bd = 0x1.6666661p-1;   // 0.7000000178813934326171875
  int bg = blockIdx.x;
  int bl = bg / NPAIR;
  int p = bg - bl * NPAIR;
  // triangular (chunk,g) pairs: chunk c covers row-groups g < (c+1)*16
  int chunk, g;
  if (p < 16)      { chunk = 0; g = p; }
  else if (p < 48) { chunk = 1; g = p - 16; }
  else if (p < 96) { chunk = 2; g = p - 48; }
  else             { chunk = 3; g = p - 96; }
  int row0 = g * RPB;
  int tid = threadIdx.x;
  int wave = tid >> 6;
  int lane = tid & 63;
  __shared__ float4 rb[RPB];
  __shared__ float ra[RPB];
  __shared__ ulonglong2 stage[RPB * 4];   // max 64 nonzero words per block
  __shared__ u32 scount, sbase;
  if (tid == 0) scount = 0u;
  if (tid < RPB) {
    rb[tid] = boffA[(size_t)bl * LSEG + row0 + tid];
    ra[tid] = area[(size_t)bl * LSEG + row0 + tid];
  }
  __syncthreads();
  int wword = chunk * 4 + wave;
  int wmaxj = chunk * 256 + wave * 64 + 63;   // this wave's max column
  int j = chunk * 256 + tid;
  float4 cb = boffA[(size_t)bl * LSEG + j];
  float ca = area[(size_t)bl * LSEG + j];
  if (wmaxj > row0) {
#pragma unroll
    for (int rr = 0; rr < RPB; ++rr) {
      int i = row0 + rr;
      if (wmaxj <= i) continue;
      float4 rbb = rb[rr];
      float ria = ra[rr];
      float ix1 = fmaxf(cb.x, rbb.x);
      float iy1 = fmaxf(cb.y, rbb.y);
      float ix2 = fminf(cb.z, rbb.z);
      float iy2 = fminf(cb.w, rbb.w);
      float inter = __fmul_rn(fmaxf(__fsub_rn(ix2, ix1), 0.0f),
                              fmaxf(__fsub_rn(iy2, iy1), 0.0f));
      float uni = __fsub_rn(__fadd_rn(ca, ria), inter);
      bool pred = (j > i) && (inter > 0.0f) &&
                  ((double)inter >= Bd * (double)uni);
      u64 bal = __ballot(pred ? 1 : 0);
      if (lane == 0 && bal) {
        u32 sidx = atomicAdd(&scount, 1u);
        ulonglong2 e;
        e.x = bal;
        e.y = (u64)(u32)(i * LCH + wword);
        stage[sidx] = e;
        atomicOr(&rnzl[(size_t)bl * LSEG + i], 1u << wword);
      }
    }
  }
  __syncthreads();
  if (tid == 0 && scount) sbase = atomicAdd(&tripcnt[bl * 16], scount);
  __syncthreads();
  for (u32 t = tid; t < scount; t += 256)
    trip[(size_t)bl * TRIPCAP + sbase + t] = stage[t];
}

// ---------------- K nmsl: greedy NMS — full mask matrix in LDS -----------------
__global__ __launch_bounds__(64) void k_nmsl(
    const ulonglong2* __restrict__ trip, const u32* __restrict__ tripcnt,
    const u32* __restrict__ rnzl, const u64* __restrict__ vmaskl,
    const u64* __restrict__ cand_key,
    u64* __restrict__ keptkeys, u32* __restrict__ keptpos,
    u32* __restrict__ keptcnt) {
  int bl = blockIdx.x;
  int lane = threadIdx.x;
  extern __shared__ char smem[];
  u64* lmask = (u64*)smem;                       // [LSEG*LCH] = 128 KB
  u32* rnzL  = (u32*)(smem + (size_t)LSEG * LCH * 8);  // [LSEG] = 4 KB
  // zero the matrix (16B LDS writes), copy rnzl (coalesced global)
  ulonglong2 z2; z2.x = 0ull; z2.y = 0ull;
  ulonglong2* lm2 = (ulonglong2*)lmask;
  for (int t = lane; t < LSEG * LCH / 2; t += 64) lm2[t] = z2;
  for (int t = lane; t < LSEG; t += 64) rnzL[t] = rnzl[(size_t)bl * LSEG + t];
  u64 vword = (lane < LCH) ? vmaskl[bl * LCH + lane] : 0ull;
  __syncthreads();
  // scatter triplets (unique (row,word) targets — order-independent)
  u32 tc = tripcnt[bl * 16];
  for (u32 t = lane; t < tc; t += 64) {
    ulonglong2 e = trip[(size_t)bl * TRIPCAP + t];
    lmask[(u32)e.y] = e.x;
  }
  __syncthreads();
  u64 supp = 0ull;   // lane w<16 holds suppression word w
  u64 keep = 0ull;   // lane w<16 holds keep word w
  for (int W = 0; W < LCH; ++W) {
    int c0 = W << 6;
    // independent LDS reads issue early; latency hides under the shfl chain
    u32 rzW = rnzL[c0 + lane];                      // rnz of row c0+lane
    u64 dchW = lmask[(size_t)(c0 + lane) * LCH + W];  // diagonal word
    u64 s = __shfl(supp, W);
    u64 v = __shfl(vword, W);
    // greedy resolve: scalar readlane over suppressor rows only
    u64 pending = v & ~s;
    u64 kw = 0ull;
    u64 suppressors = __ballot((dchW & pending) != 0ull) & pending;
    while (pending) {
      u64 sp = pending & suppressors;
      if (!sp) { kw |= pending; break; }
      int q = __builtin_ctzll(sp);
      u64 below = pending & ((1ull << q) - 1ull);
      kw |= below | (1ull << q);
      u64 supq = readlane_u64(dchW, q);
      pending &= ~supq & ~below & ~(1ull << q);
    }
    // sparse apply: kept rows with words beyond W; 4-deep batched LDS reads
    u64 kk = __ballot(((rzW >> W) >> 1) != 0u) & kw;
    bool ld = (lane < LCH);
    u64 acc = 0ull;
    while (kk) {
      int q0 = __builtin_ctzll(kk); kk &= kk - 1ull;
      u64 m0 = ld ? lmask[(size_t)(c0 + q0) * LCH + lane] : 0ull;
      u64 m1 = 0ull, m2 = 0ull, m3 = 0ull;
      if (kk) {
        int q1 = __builtin_ctzll(kk); kk &= kk - 1ull;
        m1 = ld ? lmask[(size_t)(c0 + q1) * LCH + lane] : 0ull;
      }
      if (kk) {
        int q2 = __builtin_ctzll(kk); kk &= kk - 1ull;
        m2 = ld ? lmask[(size_t)(c0 + q2) * LCH + lane] : 0ull;
      }
      if (kk) {
        int q3 = __builtin_ctzll(kk); kk &= kk - 1ull;
        m3 = ld ? lmask[(size_t)(c0 + q3) * LCH + lane] : 0ull;
      }
      acc |= (m0 | m1) | (m2 | m3);
    }
    supp |= acc;
    if (lane == W) keep = kw;
  }
  // compact kept: prefix popcount across lanes
  int pc = __popcll(keep);
  int incl = pc;
  for (int d = 1; d < 64; d <<= 1) {
    int t = __shfl_up(incl, d);
    if (lane >= d) incl += t;
  }
  int r = incl - pc;
  u64 kk = keep;
  while (kk) {
    int bit = __builtin_ctzll(kk);
    kk &= kk - 1ull;
    int p = lane * 64 + bit;
    keptkeys[(size_t)bl * LSEG + r] = cand_key[(size_t)bl * LSEG + p];
    keptpos[(size_t)bl * LSEG + r] = (u32)p;
    ++r;
  }
  if (lane == 63) keptcnt[bl] = (u32)incl;
}

// ---------------- K out: global rank via cross-level binary search -------------
__global__ __launch_bounds__(1024) void k_out(
    const u64* __restrict__ keptkeys, const u32* __restrict__ keptpos,
    const u32* __restrict__ keptcnt, const float4* __restrict__ sbox,
    const float* __restrict__ score, float* __restrict__ out) {
  int bl = blockIdx.x;
  int b = bl >> 2;
  int l = bl & 3;
  int r = threadIdx.x;
  u32 cnt = keptcnt[bl];
  if (r >= (int)cnt) return;
  u64 K = keptkeys[(size_t)bl * LSEG + r];
  int rank = r;
#pragma unroll
  for (int dl = 0; dl < 4; ++dl) {
    if (dl == l) continue;
    int obl = (b << 2) | dl;
    const u64* arr = keptkeys + (size_t)obl * LSEG;
    int lo = 0, hi = (int)keptcnt[obl];
    while (lo < hi) {
      int mid = (lo + hi) >> 1;
      if (arr[mid] > K) lo = mid + 1; else hi = mid;
    }
    rank += lo;
  }
  if (rank < POSTN) {
    u32 p = keptpos[(size_t)bl * LSEG + r];
    float4 bx = sbox[(size_t)bl * LSEG + p];
    size_t ob = ((size_t)b * POSTN + (size_t)rank) * 4;
    out[ob + 0] = bx.x;
    out[ob + 1] = bx.y;
    out[ob + 2] = bx.z;
    out[ob + 3] = bx.w;
    out[(size_t)NB * POSTN * 4 + (size_t)b * POSTN + (size_t)rank] =
        score[(size_t)bl * LSEG + p];
  }
}

extern "C" void kernel_launch(void* const* d_in, const int* in_sizes, int n_in,
                              void* d_out, int out_size, void* d_ws, size_t ws_size,
                              hipStream_t stream) {
  // setup_inputs dict order: cls0, reg0, cls1, reg1, cls2, reg2, cls3, reg3, anchors
  const float* cls0 = (const float*)d_in[0];
  const float* reg0 = (const float*)d_in[1];
  const float* cls1 = (const float*)d_in[2];
  const float* reg1 = (const float*)d_in[3];
  const float* cls2 = (const float*)d_in[4];
  const float* reg2 = (const float*)d_in[5];
  const float* cls3 = (const float*)d_in[6];
  const float* reg3 = (const float*)d_in[7];
  const float* anchors = (const float*)d_in[8];
  float* out = (float*)d_out;

  char* ws = (char*)d_ws;
  size_t off = 0;
  auto take = [&](size_t bytes) -> void* {
    off = (off + 255) & ~(size_t)255;
    void* p = ws + off;
    off += bytes;
    return p;
  };
  ulonglong2* trip = (ulonglong2*)take((size_t)64 * TRIPCAP * 16); // 16.8 MB
  u64* sidebuf   = (u64*)take((size_t)64 * SIDECAP * 8);     // 2 MB
  u32* rnzl      = (u32*)take((size_t)64 * LSEG * 4);        // 256 KB
  u64* cand_key  = (u64*)take((size_t)NB * 4096 * 8);        // 512 KB
  float4* sbox   = (float4*)take((size_t)64 * LSEG * 16);    // 1 MB
  float4* boffA  = (float4*)take((size_t)64 * LSEG * 16);    // 1 MB
  float* area    = (float*)take((size_t)64 * LSEG * 4);
  float* score   = (float*)take((size_t)64 * LSEG * 4);
  u64* vmaskl    = (u64*)take((size_t)64 * LCH * 8);
  u64* keptkeys  = (u64*)take((size_t)64 * LSEG * 8);        // 512 KB
  u32* keptpos   = (u32*)take((size_t)64 * LSEG * 4);        // 256 KB
  u32* keptcnt   = (u32*)take((size_t)64 * 4);
  u32* hist1     = (u32*)take((size_t)64 * NBUCK * 4);       // 2 MB
  u32* counters  = (u32*)take((size_t)64 * 16 * 4);          // 64B-padded
  u32* sidecnt   = (u32*)take((size_t)64 * 16 * 4);          // 64B-padded
  u32* tripcnt   = (u32*)take((size_t)64 * 16 * 4);          // 64B-padded
  u32* state_known = (u32*)take((size_t)64 * 4);
  u32* state_kneed = (u32*)take((size_t)64 * 4);
  (void)ws_size; (void)in_sizes; (void)n_in; (void)out_size;

  k_zero<<<2048, 256, 0, stream>>>(out, counters, sidecnt, tripcnt, cand_key,
                                   hist1, state_known, state_kneed);
  k_hist1<<<192, 1024, 0, stream>>>(cls0, cls1, cls2, cls3, hist1);
  k_pick1<<<64, 1024, 0, stream>>>(hist1, state_known, state_kneed);
  k_collect<<<192, 1024, 0, stream>>>(cls0, cls1, cls2, cls3, state_known,
                                      reg0, reg1, reg2, reg3, anchors,
                                      counters, sidecnt, sidebuf, cand_key);
  k_sortdec<<<64, 1024, 0, stream>>>(cand_key, sidebuf, sidecnt, counters,
                                     state_kneed, reg0, reg1, reg2, reg3,
                                     anchors, sbox, boffA, area, score,
                                     vmaskl, rnzl);
  k_maskl<<<64 * NPAIR, 256, 0, stream>>>(boffA, area, trip, tripcnt, rnzl);
  // dynamic LDS: 128 KB mask matrix + 4 KB rnz copy = 135168 B (<= 160 KB/CU)
  k_nmsl<<<64, 64, 135168, stream>>>(trip, tripcnt, rnzl, vmaskl, cand_key,
                                     keptkeys, keptpos, keptcnt);
  k_out<<<64, 1024, 0, stream>>>(keptkeys, keptpos, keptcnt, sbox, score, out);
}